// Round 3
// baseline (2694.180 us; speedup 1.0000x reference)
//
#include <hip/hip_runtime.h>
#include <hip/hip_bf16.h>
#include <cstdint>
#include <cstddef>

typedef unsigned short u16;
typedef __attribute__((ext_vector_type(8))) short bf16x8;
typedef __attribute__((ext_vector_type(4))) float f32x4;

// ---- problem sizes ----
#define NPTS 32768      // B*H*W = 32*32*32
#define NE   1024       // codes
#define ED   256        // embedding dim (= C)
#define ZPLANE 262144   // 256*1024 floats per batch image (C*H*W)

// ---- output layout (floats) ----
#define OFF_LOSS 0
#define OFF_ZQ   1
#define OFF_PPL  8388609
#define OFF_ENC  8388610
#define OFF_IDX  41943042

// ---- ws layout (bytes) ----
#define WS_IDX   0              // int[32768]
#define WS_ZZ    131072         // float[32768]
#define WS_EE    262144         // float[1024]
#define WS_ET    266240         // float[256*1024]
#define WS_LOSSP 1314816        // double[8192]
#define NLOSSP   8192
#define WS_EH    1380352        // u16[1024*256]
#define WS_EL    1904640
#define WS_ZH    2428928        // u16[32768*256]
#define WS_ZL    19206144
#define WS_CCNT  35983360       // int[4*32768]  (per quarter)
#define WS_CANDK 36507648       // int[12*32768] (3 per quarter)
#define WS_NEED  38080512ULL    // <= 38211584 proven available

#define MARGIN 3.0e-4f

// ======================================================================
// k_prep: ||e||^2 (numpy pairwise order), eT transpose, bf16 hi/lo split
// ======================================================================
__global__ __launch_bounds__(256) void k_prep(const float* __restrict__ cb,
                                              float* __restrict__ ee,
                                              float* __restrict__ eT,
                                              u16* __restrict__ eh,
                                              u16* __restrict__ el) {
#pragma clang fp contract(off)
    int k = blockIdx.x * 256 + threadIdx.x;
    if (k >= NE) return;
    const float* row = cb + (size_t)k * ED;
    float s[2];
    for (int h = 0; h < 2; ++h) {
        const float* a = row + h * 128;
        float r[8];
        for (int j = 0; j < 8; ++j) { float v = a[j]; r[j] = v * v; }
        for (int i = 8; i < 128; i += 8)
            for (int j = 0; j < 8; ++j) { float v = a[i + j]; r[j] += v * v; }
        s[h] = ((r[0] + r[1]) + (r[2] + r[3])) + ((r[4] + r[5]) + (r[6] + r[7]));
    }
    ee[k] = s[0] + s[1];
    for (int c = 0; c < ED; ++c) {
        float f = row[c];
        eT[(size_t)c * NE + k] = f;
        __hip_bfloat16 h = __float2bfloat16(f);
        float hf = __bfloat162float(h);
        __hip_bfloat16 l = __float2bfloat16(f - hf);
        eh[(size_t)k * ED + c] = *(u16*)&h;
        el[(size_t)k * ED + c] = *(u16*)&l;
    }
}

// k_prep_old: original (small-ws fallback)
__global__ __launch_bounds__(256) void k_prep_old(const float* __restrict__ cb,
                                                  float* __restrict__ ee,
                                                  float* __restrict__ eT) {
#pragma clang fp contract(off)
    int k = blockIdx.x * 256 + threadIdx.x;
    if (k >= NE) return;
    const float* row = cb + (size_t)k * ED;
    float s[2];
    for (int h = 0; h < 2; ++h) {
        const float* a = row + h * 128;
        float r[8];
        for (int j = 0; j < 8; ++j) { float v = a[j]; r[j] = v * v; }
        for (int i = 8; i < 128; i += 8)
            for (int j = 0; j < 8; ++j) { float v = a[i + j]; r[j] += v * v; }
        s[h] = ((r[0] + r[1]) + (r[2] + r[3])) + ((r[4] + r[5]) + (r[6] + r[7]));
    }
    ee[k] = s[0] + s[1];
    for (int c = 0; c < ED; ++c) eT[(size_t)c * NE + k] = row[c];
}

// ======================================================================
// k_zz: per-point ||z||^2, numpy pairwise order (proven exact)
// ======================================================================
__global__ __launch_bounds__(256) void k_zz(const float* __restrict__ z,
                                            float* __restrict__ zz) {
#pragma clang fp contract(off)
    int n = blockIdx.x * 256 + threadIdx.x;      // 128 blocks
    int b = n >> 10, hw = n & 1023;
    const float* a0 = z + (size_t)b * ZPLANE + hw;
    float s[2];
    for (int h = 0; h < 2; ++h) {
        const float* a = a0 + (size_t)h * 128 * 1024;
        float r[8];
        for (int j = 0; j < 8; ++j) { float v = a[(size_t)j * 1024]; r[j] = v * v; }
        for (int i = 8; i < 128; i += 8)
            for (int j = 0; j < 8; ++j) { float v = a[(size_t)(i + j) * 1024]; r[j] += v * v; }
        s[h] = ((r[0] + r[1]) + (r[2] + r[3])) + ((r[4] + r[5]) + (r[6] + r[7]));
    }
    zz[n] = s[0] + s[1];
}

// ======================================================================
// k_zsplit: transpose z (b,c,hw)->point-major + bf16 hi/lo split
// ======================================================================
__global__ __launch_bounds__(256) void k_zsplit(const float* __restrict__ z,
                                                u16* __restrict__ zh,
                                                u16* __restrict__ zl) {
    __shared__ float tile[64][65];
    int t = threadIdx.x;
    int blk = blockIdx.x;              // 2048 = 32b * 4c * 16hw
    int b   = blk >> 6;
    int c0  = ((blk >> 4) & 3) * 64;
    int hw0 = (blk & 15) * 64;
    int lane = t & 63, q = t >> 6;
    for (int i = 0; i < 16; ++i) {
        int cl = i * 4 + q;
        tile[cl][lane] = z[(size_t)b * ZPLANE + (size_t)(c0 + cl) * 1024 + hw0 + lane];
    }
    __syncthreads();
    int p = t >> 2, cq = t & 3;
    size_t n = (size_t)b * 1024 + hw0 + p;
    u16 hbuf[16], lbuf[16];
#pragma unroll
    for (int k = 0; k < 16; ++k) {
        float f = tile[cq * 16 + k][p];
        __hip_bfloat16 h = __float2bfloat16(f);
        float hf = __bfloat162float(h);
        __hip_bfloat16 l = __float2bfloat16(f - hf);
        hbuf[k] = *(u16*)&h; lbuf[k] = *(u16*)&l;
    }
    u16* dh = zh + n * 256 + c0 + cq * 16;
    u16* dl = zl + n * 256 + c0 + cq * 16;
    *(bf16x8*)(dh)     = *(bf16x8*)&hbuf[0];
    *(bf16x8*)(dh + 8) = *(bf16x8*)&hbuf[8];
    *(bf16x8*)(dl)     = *(bf16x8*)&lbuf[0];
    *(bf16x8*)(dl + 8) = *(bf16x8*)&lbuf[8];
}

// ======================================================================
// k_filter: bf16x3 MFMA approx scores + margin candidate emission.
// Block: 256 thr (4 waves), 128 points x 256 codes (quarter q).
// Grid 1024: g = bid&255 (point group), q = bid>>8 (same XCD per group).
// ======================================================================
__global__ __launch_bounds__(256, 4) void k_filter(const u16* __restrict__ zh,
                                                   const u16* __restrict__ zl,
                                                   const u16* __restrict__ eh,
                                                   const u16* __restrict__ el,
                                                   const float* __restrict__ ee,
                                                   int* __restrict__ candcnt,
                                                   int* __restrict__ candk) {
    __shared__ u16  Bh[128 * 64];     // 16 KB, XOR-swizzled
    __shared__ u16  Bl[128 * 64];     // 16 KB
    __shared__ float eeL[128];
    __shared__ int  cntL[128];
    __shared__ int  ckL[128][3];

    int t = threadIdx.x;
    int lane = t & 63, w = t >> 6;
    int g = blockIdx.x & 255;
    int q = blockIdx.x >> 8;
    int n0 = g * 128;
    int kqbase = q * 256;
    int prow = w * 32 + (lane & 15);
    const u16* zh0 = zh + (size_t)(n0 + prow) * 256;
    const u16* zl0 = zl + (size_t)(n0 + prow) * 256;
    const u16* zh1 = zh0 + 16 * 256;
    const u16* zl1 = zl0 + 16 * 256;
    int koff_lane = (lane >> 4) * 8;

    if (t < 128) cntL[t] = 0;
    float runmin[2][4];
#pragma unroll
    for (int gg = 0; gg < 2; ++gg)
#pragma unroll
        for (int j = 0; j < 4; ++j) runmin[gg][j] = 3.4e38f;

    for (int nc = 0; nc < 2; ++nc) {
        int kcbase = kqbase + nc * 128;
        f32x4 acc0[8], acc1[8];
#pragma unroll
        for (int nf = 0; nf < 8; ++nf) {
            acc0[nf] = (f32x4){0.f, 0.f, 0.f, 0.f};
            acc1[nf] = (f32x4){0.f, 0.f, 0.f, 0.f};
        }
        for (int kb = 0; kb < 4; ++kb) {
            __syncthreads();
            if (kb == 0 && t < 128) eeL[t] = ee[kcbase + t];
#pragma unroll
            for (int i = 0; i < 8; ++i) {
                int f = i * 256 + t;
                int a = f >> 10, r = (f >> 3) & 127, seg = f & 7;
                const u16* src = (a ? el : eh) + (size_t)(kcbase + r) * 256 + kb * 64 + seg * 8;
                bf16x8 v = *(const bf16x8*)src;
                int bo = (r * 128 + seg * 16) ^ ((r & 7) << 4);
                *(bf16x8*)((char*)(a ? Bl : Bh) + bo) = v;
            }
            __syncthreads();
#pragma unroll
            for (int ks2 = 0; ks2 < 2; ++ks2) {
                int ko = kb * 64 + ks2 * 32 + koff_lane;
                bf16x8 ah0 = *(const bf16x8*)(zh0 + ko);
                bf16x8 al0 = *(const bf16x8*)(zl0 + ko);
                bf16x8 ah1 = *(const bf16x8*)(zh1 + ko);
                bf16x8 al1 = *(const bf16x8*)(zl1 + ko);
#pragma unroll
                for (int nf = 0; nf < 8; ++nf) {
                    int r = nf * 16 + (lane & 15);
                    int bo = (r * 128 + ks2 * 64 + (lane >> 4) * 16) ^ ((r & 7) << 4);
                    bf16x8 bh = *(const bf16x8*)((const char*)Bh + bo);
                    bf16x8 bl = *(const bf16x8*)((const char*)Bl + bo);
                    acc0[nf] = __builtin_amdgcn_mfma_f32_16x16x32_bf16(ah0, bh, acc0[nf], 0, 0, 0);
                    acc0[nf] = __builtin_amdgcn_mfma_f32_16x16x32_bf16(al0, bh, acc0[nf], 0, 0, 0);
                    acc0[nf] = __builtin_amdgcn_mfma_f32_16x16x32_bf16(ah0, bl, acc0[nf], 0, 0, 0);
                    acc1[nf] = __builtin_amdgcn_mfma_f32_16x16x32_bf16(ah1, bh, acc1[nf], 0, 0, 0);
                    acc1[nf] = __builtin_amdgcn_mfma_f32_16x16x32_bf16(al1, bh, acc1[nf], 0, 0, 0);
                    acc1[nf] = __builtin_amdgcn_mfma_f32_16x16x32_bf16(ah1, bl, acc1[nf], 0, 0, 0);
                }
            }
        }
        // epilogue: s = ee - 2*dot'; chunk-min; emission vs quarter running min
#pragma unroll
        for (int gg = 0; gg < 2; ++gg) {
#pragma unroll
            for (int nf = 0; nf < 8; ++nf) {
                float eev = eeL[nf * 16 + (lane & 15)];
                f32x4 d = gg ? acc1[nf] : acc0[nf];
                f32x4 s;
#pragma unroll
                for (int j = 0; j < 4; ++j) s[j] = fmaf(-2.f, d[j], eev);
                if (gg) acc1[nf] = s; else acc0[nf] = s;
            }
#pragma unroll
            for (int j = 0; j < 4; ++j) {
                float m = 3.4e38f;
#pragma unroll
                for (int nf = 0; nf < 8; ++nf) m = fminf(m, gg ? acc1[nf][j] : acc0[nf][j]);
                m = fminf(m, __shfl_xor(m, 1, 64));
                m = fminf(m, __shfl_xor(m, 2, 64));
                m = fminf(m, __shfl_xor(m, 4, 64));
                m = fminf(m, __shfl_xor(m, 8, 64));
                runmin[gg][j] = fminf(runmin[gg][j], m);
                float th = runmin[gg][j] + MARGIN;
                int ml = w * 32 + gg * 16 + (lane >> 4) * 4 + j;
#pragma unroll
                for (int nf = 0; nf < 8; ++nf) {
                    float sv = gg ? acc1[nf][j] : acc0[nf][j];
                    if (sv <= th) {
                        int pos = atomicAdd(&cntL[ml], 1);
                        if (pos < 3) ckL[ml][pos] = kcbase + nf * 16 + (lane & 15);
                    }
                }
            }
        }
    }
    __syncthreads();
    if (t < 128) {
        int n = n0 + t;
        candcnt[(size_t)n * 4 + q] = cntL[t];
        int* dst = candk + (size_t)n * 12 + q * 3;
        dst[0] = ckL[t][0]; dst[1] = ckL[t][1]; dst[2] = ckL[t][2];
    }
}

// ======================================================================
// k_rescore: exact fp32 d (ref arithmetic) over candidates; argmin with
// lowest-index tie-break. Full scan fallback if any quarter cnt>3.
// ======================================================================
__global__ __launch_bounds__(256) void k_rescore(const float* __restrict__ z,
                                                 const float* __restrict__ cb,
                                                 const float* __restrict__ ee,
                                                 const float* __restrict__ zz,
                                                 const int* __restrict__ candcnt,
                                                 const int* __restrict__ candk,
                                                 int* __restrict__ idx_out) {
    int t = threadIdx.x;
    int n = blockIdx.x * 256 + t;                 // 128 blocks
    int b = n >> 10, hw = n & 1023;
    const float* zp = z + (size_t)b * ZPLANE + hw;
    int c0 = candcnt[(size_t)n * 4 + 0];
    int c1 = candcnt[(size_t)n * 4 + 1];
    int c2 = candcnt[(size_t)n * 4 + 2];
    int c3 = candcnt[(size_t)n * 4 + 3];
    bool full = (c0 > 3) | (c1 > 3) | (c2 > 3) | (c3 > 3);
    float zzv = zz[n];
    float bd = 3.4e38f; int bk = 1 << 30;

    if (!full) {
        const int* cl = candk + (size_t)n * 12;
        int ks[12];
        int cq[4] = {c0, c1, c2, c3};
#pragma unroll
        for (int qq = 0; qq < 4; ++qq) {
            int k0 = cl[qq * 3];
#pragma unroll
            for (int i = 0; i < 3; ++i)
                ks[qq * 3 + i] = (i < cq[qq]) ? cl[qq * 3 + i] : k0;
        }
#pragma unroll
        for (int p = 0; p < 12; p += 4) {
            int k0 = ks[p], k1 = ks[p + 1], k2 = ks[p + 2], k3 = ks[p + 3];
            const float* e0 = cb + (size_t)k0 * ED;
            const float* e1 = cb + (size_t)k1 * ED;
            const float* e2 = cb + (size_t)k2 * ED;
            const float* e3 = cb + (size_t)k3 * ED;
            float a0 = 0.f, a1 = 0.f, a2 = 0.f, a3 = 0.f;
            for (int c = 0; c < ED; ++c) {
                float zc = zp[(size_t)c * 1024];
                a0 = fmaf(zc, e0[c], a0);
                a1 = fmaf(zc, e1[c], a1);
                a2 = fmaf(zc, e2[c], a2);
                a3 = fmaf(zc, e3[c], a3);
            }
            float d0 = (zzv + ee[k0]) - 2.f * a0;
            float d1 = (zzv + ee[k1]) - 2.f * a1;
            float d2 = (zzv + ee[k2]) - 2.f * a2;
            float d3 = (zzv + ee[k3]) - 2.f * a3;
            if (d0 < bd || (d0 == bd && k0 < bk)) { bd = d0; bk = k0; }
            if (d1 < bd || (d1 == bd && k1 < bk)) { bd = d1; bk = k1; }
            if (d2 < bd || (d2 == bd && k2 < bk)) { bd = d2; bk = k2; }
            if (d3 < bd || (d3 == bd && k3 < bk)) { bd = d3; bk = k3; }
        }
    } else {
        for (int p = 0; p < NE; p += 4) {
            int k0 = p, k1 = p + 1, k2 = p + 2, k3 = p + 3;
            const float* e0 = cb + (size_t)k0 * ED;
            const float* e1 = cb + (size_t)k1 * ED;
            const float* e2 = cb + (size_t)k2 * ED;
            const float* e3 = cb + (size_t)k3 * ED;
            float a0 = 0.f, a1 = 0.f, a2 = 0.f, a3 = 0.f;
            for (int c = 0; c < ED; ++c) {
                float zc = zp[(size_t)c * 1024];
                a0 = fmaf(zc, e0[c], a0);
                a1 = fmaf(zc, e1[c], a1);
                a2 = fmaf(zc, e2[c], a2);
                a3 = fmaf(zc, e3[c], a3);
            }
            float d0 = (zzv + ee[k0]) - 2.f * a0;
            float d1 = (zzv + ee[k1]) - 2.f * a1;
            float d2 = (zzv + ee[k2]) - 2.f * a2;
            float d3 = (zzv + ee[k3]) - 2.f * a3;
            if (d0 < bd || (d0 == bd && k0 < bk)) { bd = d0; bk = k0; }
            if (d1 < bd || (d1 == bd && k1 < bk)) { bd = d1; bk = k1; }
            if (d2 < bd || (d2 == bd && k2 < bk)) { bd = d2; bk = k2; }
            if (d3 < bd || (d3 == bd && k3 < bk)) { bd = d3; bk = k3; }
        }
    }
    idx_out[n] = bk;
}

// ======================================================================
// k_main (fallback path only): exact fp32 distances + argmin, proven.
// ======================================================================
#define TM 64
#define TK 128
#define CCH 64
__global__ __launch_bounds__(256) void k_main(const float* __restrict__ z,
                                              const float* __restrict__ eT,
                                              const float* __restrict__ ee,
                                              const float* __restrict__ zz,
                                              int* __restrict__ idx_out) {
    __shared__ float zt[CCH][TM];
    __shared__ float et[CCH][TK];
    __shared__ float redv[TM][16];
    __shared__ int   redi[TM][16];
    __shared__ float bestv[TM];
    __shared__ int   besti[TM];
    __shared__ float zzl[TM];
    int t = threadIdx.x;
    int n0 = blockIdx.x * TM;
    int b = n0 >> 10, hw0 = n0 & 1023;
    const float* zb = z + (size_t)b * ZPLANE + hw0;
    int trow = t >> 4, tcol = t & 15;
    if (t < TM) { bestv[t] = 3.4e38f; besti[t] = 0; zzl[t] = zz[n0 + t]; }
    for (int kt = 0; kt < NE / TK; ++kt) {
        int k0 = kt * TK;
        float acc[4][8];
        for (int i = 0; i < 4; ++i)
            for (int j = 0; j < 8; ++j) acc[i][j] = 0.f;
        for (int cc = 0; cc < ED / CCH; ++cc) {
            __syncthreads();
            {
                int m4 = (t & 15) * 4; int cb0 = t >> 4;
                for (int p = 0; p < 4; ++p) {
                    int cl = p * 16 + cb0;
                    float4 v = *(const float4*)(zb + (size_t)(cc * CCH + cl) * 1024 + m4);
                    *(float4*)&zt[cl][m4] = v;
                }
            }
            {
                int k4 = (t & 31) * 4; int cb0 = t >> 5;
                for (int p = 0; p < 8; ++p) {
                    int cl = p * 8 + cb0;
                    float4 v = *(const float4*)(eT + (size_t)(cc * CCH + cl) * 1024 + k0 + k4);
                    *(float4*)&et[cl][k4] = v;
                }
            }
            __syncthreads();
            for (int c = 0; c < CCH; ++c) {
                float4 zm = *(const float4*)&zt[c][trow * 4];
                float4 e0 = *(const float4*)&et[c][tcol * 8];
                float4 e1 = *(const float4*)&et[c][tcol * 8 + 4];
                float zv[4] = {zm.x, zm.y, zm.z, zm.w};
                float ev[8] = {e0.x, e0.y, e0.z, e0.w, e1.x, e1.y, e1.z, e1.w};
                for (int i = 0; i < 4; ++i)
                    for (int j = 0; j < 8; ++j)
                        acc[i][j] = fmaf(zv[i], ev[j], acc[i][j]);
            }
        }
        for (int i = 0; i < 4; ++i) {
            int m = trow * 4 + i;
            float zv = zzl[m];
            float bv = 3.4e38f; int bi = 0;
            for (int j = 0; j < 8; ++j) {
                int k = k0 + tcol * 8 + j;
                float t1 = zv + ee[k];
                float d  = t1 - 2.0f * acc[i][j];
                if (d < bv) { bv = d; bi = k; }
            }
            redv[m][tcol] = bv; redi[m][tcol] = bi;
        }
        __syncthreads();
        if (t < TM) {
            float bv = bestv[t]; int bi = besti[t];
            for (int tc = 0; tc < 16; ++tc) {
                float v = redv[t][tc]; int ix = redi[t][tc];
                if (v < bv || (v == bv && ix < bi)) { bv = v; bi = ix; }
            }
            bestv[t] = bv; besti[t] = bi;
        }
    }
    __syncthreads();
    if (t < TM) idx_out[n0 + t] = besti[t];
}

// ======================================================================
// k_out1: z_q straight-through (B,C,H,W) + loss partials
// ======================================================================
__global__ __launch_bounds__(256) void k_out1(const float* __restrict__ z,
                                              const float* __restrict__ eT,
                                              const int* __restrict__ idx,
                                              float* __restrict__ out,
                                              double* __restrict__ lossp) {
#pragma clang fp contract(off)
    int t = threadIdx.x;
    double lsum = 0.0;
    for (int it = 0; it < 4; ++it) {
        int e = (blockIdx.x * 4 + it) * 256 + t;
        int c  = (e >> 10) & 255;
        int bb = e >> 18;
        int hw = e & 1023;
        int n  = (bb << 10) + hw;
        int iv = idx[n];
        float zv = z[e];
        float zq = eT[(size_t)c * NE + iv];
        float d  = zq - zv;
        out[OFF_ZQ + (size_t)e] = zv + d;
        lsum += (double)(d * d);
    }
    for (int off = 32; off; off >>= 1) lsum += __shfl_down(lsum, off);
    __shared__ double wsum[4];
    if ((t & 63) == 0) wsum[t >> 6] = lsum;
    __syncthreads();
    if (t == 0) lossp[blockIdx.x] = (wsum[0] + wsum[1]) + (wsum[2] + wsum[3]);
}

// ======================================================================
// k_out2: one-hot encodings (float4 stores) + indices
// ======================================================================
__global__ __launch_bounds__(256) void k_out2(const int* __restrict__ idx,
                                              float* __restrict__ out) {
    int t = threadIdx.x;
    for (int it = 0; it < 16; ++it) {
        int q = (blockIdx.x * 16 + it) * 256 + t;  // grid 2048 -> 8388608 float4
        int row  = q >> 8;
        int col4 = (q & 255) * 4;
        int iv = idx[row];
        float4 v;
        v.x = (col4     == iv) ? 1.f : 0.f;
        v.y = (col4 + 1 == iv) ? 1.f : 0.f;
        v.z = (col4 + 2 == iv) ? 1.f : 0.f;
        v.w = (col4 + 3 == iv) ? 1.f : 0.f;
        *(float4*)(out + OFF_ENC + (size_t)q * 4) = v;
        if ((q & 255) == 0) out[OFF_IDX + row] = (float)iv;
    }
}

// ======================================================================
// k_final: perplexity + loss scalar, deterministic
// ======================================================================
__global__ __launch_bounds__(256) void k_final(const int* __restrict__ idx,
                                               const double* __restrict__ lossp,
                                               float* __restrict__ out) {
    __shared__ int cnt[NE];
    __shared__ double sh[4];
    int t = threadIdx.x;
    for (int k = t; k < NE; k += 256) cnt[k] = 0;
    __syncthreads();
    for (int n = t; n < NPTS; n += 256) atomicAdd(&cnt[idx[n]], 1);
    __syncthreads();
    double psum = 0.0;
    for (int k = t; k < NE; k += 256) {
        float em = (float)cnt[k] / 32768.0f;
        float term = em * logf(em + 1e-10f);
        psum += (double)term;
    }
    for (int off = 32; off; off >>= 1) psum += __shfl_down(psum, off);
    if ((t & 63) == 0) sh[t >> 6] = psum;
    __syncthreads();
    if (t == 0) {
        double tot = (sh[0] + sh[1]) + (sh[2] + sh[3]);
        out[OFF_PPL] = expf(-(float)tot);
    }
    __syncthreads();
    double ls = 0.0;
    for (int i = t; i < NLOSSP; i += 256) ls += lossp[i];
    for (int off = 32; off; off >>= 1) ls += __shfl_down(ls, off);
    __syncthreads();
    if ((t & 63) == 0) sh[t >> 6] = ls;
    __syncthreads();
    if (t == 0) {
        double m = ((sh[0] + sh[1]) + (sh[2] + sh[3])) / 8388608.0;
        float mf = (float)m;
        out[OFF_LOSS] = mf + 0.25f * mf;
    }
}

// ======================================================================
extern "C" void kernel_launch(void* const* d_in, const int* in_sizes, int n_in,
                              void* d_out, int out_size, void* d_ws, size_t ws_size,
                              hipStream_t stream) {
    const float* z  = (const float*)d_in[0];
    const float* cb = (const float*)d_in[1];
    float* out = (float*)d_out;
    char* ws = (char*)d_ws;

    int*    idx   = (int*)(ws + WS_IDX);
    float*  zz    = (float*)(ws + WS_ZZ);
    float*  ee    = (float*)(ws + WS_EE);
    float*  eT    = (float*)(ws + WS_ET);
    double* lossp = (double*)(ws + WS_LOSSP);

    if (ws_size >= WS_NEED) {
        u16* eh = (u16*)(ws + WS_EH);
        u16* el = (u16*)(ws + WS_EL);
        u16* zh = (u16*)(ws + WS_ZH);
        u16* zl = (u16*)(ws + WS_ZL);
        int* ccnt  = (int*)(ws + WS_CCNT);
        int* candk = (int*)(ws + WS_CANDK);

        k_prep   <<<4,    256, 0, stream>>>(cb, ee, eT, eh, el);
        k_zz     <<<128,  256, 0, stream>>>(z, zz);
        k_zsplit <<<2048, 256, 0, stream>>>(z, zh, zl);
        k_filter <<<1024, 256, 0, stream>>>(zh, zl, eh, el, ee, ccnt, candk);
        k_rescore<<<128,  256, 0, stream>>>(z, cb, ee, zz, ccnt, candk, idx);
    } else {
        k_prep_old<<<4,   256, 0, stream>>>(cb, ee, eT);
        k_zz      <<<128, 256, 0, stream>>>(z, zz);
        k_main    <<<512, 256, 0, stream>>>(z, eT, ee, zz, idx);
    }
    k_out1 <<<8192, 256, 0, stream>>>(z, eT, idx, out, lossp);
    k_out2 <<<2048, 256, 0, stream>>>(idx, out);
    k_final<<<1,    256, 0, stream>>>(idx, lossp, out);
}

// Round 4
// 2444.225 us; speedup vs baseline: 1.1023x; 1.1023x over previous
//
#include <hip/hip_runtime.h>
#include <hip/hip_bf16.h>
#include <cstdint>
#include <cstddef>

typedef unsigned short u16;
typedef unsigned char u8;
typedef __attribute__((ext_vector_type(8))) short bf16x8;
typedef __attribute__((ext_vector_type(4))) float f32x4;

// ---- problem sizes ----
#define NPTS 32768      // B*H*W = 32*32*32
#define NE   1024       // codes
#define ED   256        // embedding dim (= C)
#define ZPLANE 262144   // 256*1024 floats per batch image (C*H*W)

// ---- output layout (floats) ----
#define OFF_LOSS 0
#define OFF_ZQ   1
#define OFF_PPL  8388609
#define OFF_ENC  8388610
#define OFF_IDX  41943042

// ---- ws layout (bytes) ---- total exactly 38211584 (proven available)
#define WS_IDX   0              // int[32768]
#define WS_ZZ    131072         // float[32768]
#define WS_EE    262144         // float[1024]
#define WS_LOSSP 266240         // double[8192]
#define NLOSSP   8192
#define WS_ET_FB 331776         // float[256*1024] (FALLBACK ONLY, overlays EH/EL)
#define WS_EH    331776         // u16[1024*256]
#define WS_EL    856064
#define WS_ZH    1380352        // u16[32768*256]
#define WS_ZL    18157568
#define WS_CCNT  34934784       // u8[4*32768] packed counts
#define WS_CANDK 35065856       // int[12*32768]
#define WS_CANDS 36638720       // float[12*32768]
#define WS_NEED  38211584ULL

#define MARGIN 3.0e-4f

// ======================================================================
// k_prep: ||e||^2 (numpy pairwise order) + bf16 hi/lo split
// ======================================================================
__global__ __launch_bounds__(256) void k_prep(const float* __restrict__ cb,
                                              float* __restrict__ ee,
                                              u16* __restrict__ eh,
                                              u16* __restrict__ el) {
#pragma clang fp contract(off)
    int k = blockIdx.x * 256 + threadIdx.x;
    if (k >= NE) return;
    const float* row = cb + (size_t)k * ED;
    float s[2];
    for (int h = 0; h < 2; ++h) {
        const float* a = row + h * 128;
        float r[8];
        for (int j = 0; j < 8; ++j) { float v = a[j]; r[j] = v * v; }
        for (int i = 8; i < 128; i += 8)
            for (int j = 0; j < 8; ++j) { float v = a[i + j]; r[j] += v * v; }
        s[h] = ((r[0] + r[1]) + (r[2] + r[3])) + ((r[4] + r[5]) + (r[6] + r[7]));
    }
    ee[k] = s[0] + s[1];
    for (int c = 0; c < ED; ++c) {
        float f = row[c];
        __hip_bfloat16 h = __float2bfloat16(f);
        float hf = __bfloat162float(h);
        __hip_bfloat16 l = __float2bfloat16(f - hf);
        eh[(size_t)k * ED + c] = *(u16*)&h;
        el[(size_t)k * ED + c] = *(u16*)&l;
    }
}

// k_prep_old: fallback (also writes eT)
__global__ __launch_bounds__(256) void k_prep_old(const float* __restrict__ cb,
                                                  float* __restrict__ ee,
                                                  float* __restrict__ eT) {
#pragma clang fp contract(off)
    int k = blockIdx.x * 256 + threadIdx.x;
    if (k >= NE) return;
    const float* row = cb + (size_t)k * ED;
    float s[2];
    for (int h = 0; h < 2; ++h) {
        const float* a = row + h * 128;
        float r[8];
        for (int j = 0; j < 8; ++j) { float v = a[j]; r[j] = v * v; }
        for (int i = 8; i < 128; i += 8)
            for (int j = 0; j < 8; ++j) { float v = a[i + j]; r[j] += v * v; }
        s[h] = ((r[0] + r[1]) + (r[2] + r[3])) + ((r[4] + r[5]) + (r[6] + r[7]));
    }
    ee[k] = s[0] + s[1];
    for (int c = 0; c < ED; ++c) eT[(size_t)c * NE + k] = row[c];
}

// ======================================================================
// k_zz: per-point ||z||^2, numpy pairwise order (proven exact)
// ======================================================================
__global__ __launch_bounds__(256) void k_zz(const float* __restrict__ z,
                                            float* __restrict__ zz) {
#pragma clang fp contract(off)
    int n = blockIdx.x * 256 + threadIdx.x;      // 128 blocks
    int b = n >> 10, hw = n & 1023;
    const float* a0 = z + (size_t)b * ZPLANE + hw;
    float s[2];
    for (int h = 0; h < 2; ++h) {
        const float* a = a0 + (size_t)h * 128 * 1024;
        float r[8];
        for (int j = 0; j < 8; ++j) { float v = a[(size_t)j * 1024]; r[j] = v * v; }
        for (int i = 8; i < 128; i += 8)
            for (int j = 0; j < 8; ++j) { float v = a[(size_t)(i + j) * 1024]; r[j] += v * v; }
        s[h] = ((r[0] + r[1]) + (r[2] + r[3])) + ((r[4] + r[5]) + (r[6] + r[7]));
    }
    zz[n] = s[0] + s[1];
}

// ======================================================================
// k_zsplit: transpose z (b,c,hw)->point-major + bf16 hi/lo split
// ======================================================================
__global__ __launch_bounds__(256) void k_zsplit(const float* __restrict__ z,
                                                u16* __restrict__ zh,
                                                u16* __restrict__ zl) {
    __shared__ float tile[64][65];
    int t = threadIdx.x;
    int blk = blockIdx.x;              // 2048 = 32b * 4c * 16hw
    int b   = blk >> 6;
    int c0  = ((blk >> 4) & 3) * 64;
    int hw0 = (blk & 15) * 64;
    int lane = t & 63, q = t >> 6;
    for (int i = 0; i < 16; ++i) {
        int cl = i * 4 + q;
        tile[cl][lane] = z[(size_t)b * ZPLANE + (size_t)(c0 + cl) * 1024 + hw0 + lane];
    }
    __syncthreads();
    int p = t >> 2, cq = t & 3;
    size_t n = (size_t)b * 1024 + hw0 + p;
    u16 hbuf[16], lbuf[16];
#pragma unroll
    for (int k = 0; k < 16; ++k) {
        float f = tile[cq * 16 + k][p];
        __hip_bfloat16 h = __float2bfloat16(f);
        float hf = __bfloat162float(h);
        __hip_bfloat16 l = __float2bfloat16(f - hf);
        hbuf[k] = *(u16*)&h; lbuf[k] = *(u16*)&l;
    }
    u16* dh = zh + n * 256 + c0 + cq * 16;
    u16* dl = zl + n * 256 + c0 + cq * 16;
    *(bf16x8*)(dh)     = *(bf16x8*)&hbuf[0];
    *(bf16x8*)(dh + 8) = *(bf16x8*)&hbuf[8];
    *(bf16x8*)(dl)     = *(bf16x8*)&lbuf[0];
    *(bf16x8*)(dl + 8) = *(bf16x8*)&lbuf[8];
}

// ======================================================================
// k_filter: bf16x3 MFMA approx scores + margin candidate emission
// (stores score values too). 128 points x 256 codes per block.
// ======================================================================
__global__ __launch_bounds__(256, 4) void k_filter(const u16* __restrict__ zh,
                                                   const u16* __restrict__ zl,
                                                   const u16* __restrict__ eh,
                                                   const u16* __restrict__ el,
                                                   const float* __restrict__ ee,
                                                   u8* __restrict__ candcnt,
                                                   int* __restrict__ candk,
                                                   float* __restrict__ cands) {
    __shared__ u16  Bh[128 * 64];     // 16 KB, XOR-swizzled
    __shared__ u16  Bl[128 * 64];     // 16 KB
    __shared__ float eeL[128];
    __shared__ int  cntL[128];
    __shared__ int  ckL[128][3];
    __shared__ float csL[128][3];

    int t = threadIdx.x;
    int lane = t & 63, w = t >> 6;
    int g = blockIdx.x & 255;
    int q = blockIdx.x >> 8;
    int n0 = g * 128;
    int kqbase = q * 256;
    int prow = w * 32 + (lane & 15);
    const u16* zh0 = zh + (size_t)(n0 + prow) * 256;
    const u16* zl0 = zl + (size_t)(n0 + prow) * 256;
    const u16* zh1 = zh0 + 16 * 256;
    const u16* zl1 = zl0 + 16 * 256;
    int koff_lane = (lane >> 4) * 8;

    if (t < 128) cntL[t] = 0;
    float runmin[2][4];
#pragma unroll
    for (int gg = 0; gg < 2; ++gg)
#pragma unroll
        for (int j = 0; j < 4; ++j) runmin[gg][j] = 3.4e38f;

    for (int nc = 0; nc < 2; ++nc) {
        int kcbase = kqbase + nc * 128;
        f32x4 acc0[8], acc1[8];
#pragma unroll
        for (int nf = 0; nf < 8; ++nf) {
            acc0[nf] = (f32x4){0.f, 0.f, 0.f, 0.f};
            acc1[nf] = (f32x4){0.f, 0.f, 0.f, 0.f};
        }
        for (int kb = 0; kb < 4; ++kb) {
            __syncthreads();
            if (kb == 0 && t < 128) eeL[t] = ee[kcbase + t];
#pragma unroll
            for (int i = 0; i < 8; ++i) {
                int f = i * 256 + t;
                int a = f >> 10, r = (f >> 3) & 127, seg = f & 7;
                const u16* src = (a ? el : eh) + (size_t)(kcbase + r) * 256 + kb * 64 + seg * 8;
                bf16x8 v = *(const bf16x8*)src;
                int bo = (r * 128 + seg * 16) ^ ((r & 7) << 4);
                *(bf16x8*)((char*)(a ? Bl : Bh) + bo) = v;
            }
            __syncthreads();
#pragma unroll
            for (int ks2 = 0; ks2 < 2; ++ks2) {
                int ko = kb * 64 + ks2 * 32 + koff_lane;
                bf16x8 ah0 = *(const bf16x8*)(zh0 + ko);
                bf16x8 al0 = *(const bf16x8*)(zl0 + ko);
                bf16x8 ah1 = *(const bf16x8*)(zh1 + ko);
                bf16x8 al1 = *(const bf16x8*)(zl1 + ko);
#pragma unroll
                for (int nf = 0; nf < 8; ++nf) {
                    int r = nf * 16 + (lane & 15);
                    int bo = (r * 128 + ks2 * 64 + (lane >> 4) * 16) ^ ((r & 7) << 4);
                    bf16x8 bh = *(const bf16x8*)((const char*)Bh + bo);
                    bf16x8 bl = *(const bf16x8*)((const char*)Bl + bo);
                    acc0[nf] = __builtin_amdgcn_mfma_f32_16x16x32_bf16(ah0, bh, acc0[nf], 0, 0, 0);
                    acc0[nf] = __builtin_amdgcn_mfma_f32_16x16x32_bf16(al0, bh, acc0[nf], 0, 0, 0);
                    acc0[nf] = __builtin_amdgcn_mfma_f32_16x16x32_bf16(ah0, bl, acc0[nf], 0, 0, 0);
                    acc1[nf] = __builtin_amdgcn_mfma_f32_16x16x32_bf16(ah1, bh, acc1[nf], 0, 0, 0);
                    acc1[nf] = __builtin_amdgcn_mfma_f32_16x16x32_bf16(al1, bh, acc1[nf], 0, 0, 0);
                    acc1[nf] = __builtin_amdgcn_mfma_f32_16x16x32_bf16(ah1, bl, acc1[nf], 0, 0, 0);
                }
            }
        }
        // epilogue: s = ee - 2*dot'; chunk-min; emission vs quarter running min
#pragma unroll
        for (int gg = 0; gg < 2; ++gg) {
#pragma unroll
            for (int nf = 0; nf < 8; ++nf) {
                float eev = eeL[nf * 16 + (lane & 15)];
                f32x4 d = gg ? acc1[nf] : acc0[nf];
                f32x4 s;
#pragma unroll
                for (int j = 0; j < 4; ++j) s[j] = fmaf(-2.f, d[j], eev);
                if (gg) acc1[nf] = s; else acc0[nf] = s;
            }
#pragma unroll
            for (int j = 0; j < 4; ++j) {
                float m = 3.4e38f;
#pragma unroll
                for (int nf = 0; nf < 8; ++nf) m = fminf(m, gg ? acc1[nf][j] : acc0[nf][j]);
                m = fminf(m, __shfl_xor(m, 1, 64));
                m = fminf(m, __shfl_xor(m, 2, 64));
                m = fminf(m, __shfl_xor(m, 4, 64));
                m = fminf(m, __shfl_xor(m, 8, 64));
                runmin[gg][j] = fminf(runmin[gg][j], m);
                float th = runmin[gg][j] + MARGIN;
                int ml = w * 32 + gg * 16 + (lane >> 4) * 4 + j;
#pragma unroll
                for (int nf = 0; nf < 8; ++nf) {
                    float sv = gg ? acc1[nf][j] : acc0[nf][j];
                    if (sv <= th) {
                        int pos = atomicAdd(&cntL[ml], 1);
                        if (pos < 3) { ckL[ml][pos] = kcbase + nf * 16 + (lane & 15);
                                       csL[ml][pos] = sv; }
                    }
                }
            }
        }
    }
    __syncthreads();
    if (t < 128) {
        int n = n0 + t;
        int cnt = cntL[t];
        candcnt[(size_t)n * 4 + q] = (u8)(cnt > 255 ? 255 : cnt);
        int* dk = candk + (size_t)n * 12 + q * 3;
        float* ds = cands + (size_t)n * 12 + q * 3;
#pragma unroll
        for (int i = 0; i < 3; ++i) {
            dk[i] = (i < cnt) ? ckL[t][i] : 0;
            ds[i] = (i < cnt) ? csL[t][i] : 3.4e38f;
        }
    }
}

// ======================================================================
// k_rescore: global prune (s' <= gmin+MARGIN), then exact fp32 d over
// survivors only; lowest-index tie-break. Full scan if any quarter >3.
// ======================================================================
__global__ __launch_bounds__(128) void k_rescore(const float* __restrict__ z,
                                                 const float* __restrict__ cb,
                                                 const float* __restrict__ ee,
                                                 const float* __restrict__ zz,
                                                 const u8* __restrict__ candcnt,
                                                 const int* __restrict__ candk,
                                                 const float* __restrict__ cands,
                                                 int* __restrict__ idx_out) {
    int t = threadIdx.x;
    int n = blockIdx.x * 128 + t;                 // 256 blocks
    int b = n >> 10, hw = n & 1023;
    const float* zp = z + (size_t)b * ZPLANE + hw;
    int packed = ((const int*)candcnt)[n];
    int c0 = packed & 255, c1 = (packed >> 8) & 255,
        c2 = (packed >> 16) & 255, c3 = (packed >> 24) & 255;
    bool full = (c0 > 3) | (c1 > 3) | (c2 > 3) | (c3 > 3);
    float zzv = zz[n];
    float bd = 3.4e38f; int bk = 1 << 30;

    if (!full) {
        int ks[12]; float ss[12];
        const int*   ck = candk + (size_t)n * 12;
        const float* cs = cands + (size_t)n * 12;
#pragma unroll
        for (int p = 0; p < 3; ++p) {
            *(int4*)&ks[p * 4]   = *(const int4*)(ck + p * 4);
            *(float4*)&ss[p * 4] = *(const float4*)(cs + p * 4);
        }
        float gmin = 3.4e38f;
#pragma unroll
        for (int j = 0; j < 12; ++j) gmin = fminf(gmin, ss[j]);
        float th = gmin + MARGIN;
#pragma unroll 1
        for (int j = 0; j < 12; ++j) {
            if (ss[j] > th) continue;
            int k = ks[j];
            const float* e0 = cb + (size_t)k * ED;
            float a0 = 0.f;
            for (int c = 0; c < ED; c += 4) {
                float4 ev = *(const float4*)(e0 + c);
                a0 = fmaf(zp[(size_t)c * 1024],       ev.x, a0);
                a0 = fmaf(zp[(size_t)(c + 1) * 1024], ev.y, a0);
                a0 = fmaf(zp[(size_t)(c + 2) * 1024], ev.z, a0);
                a0 = fmaf(zp[(size_t)(c + 3) * 1024], ev.w, a0);
            }
            float d0 = (zzv + ee[k]) - 2.f * a0;
            if (d0 < bd || (d0 == bd && k < bk)) { bd = d0; bk = k; }
        }
    } else {
        for (int p = 0; p < NE; p += 4) {
            int k0 = p, k1 = p + 1, k2 = p + 2, k3 = p + 3;
            const float* e0 = cb + (size_t)k0 * ED;
            const float* e1 = cb + (size_t)k1 * ED;
            const float* e2 = cb + (size_t)k2 * ED;
            const float* e3 = cb + (size_t)k3 * ED;
            float a0 = 0.f, a1 = 0.f, a2 = 0.f, a3 = 0.f;
            for (int c = 0; c < ED; ++c) {
                float zc = zp[(size_t)c * 1024];
                a0 = fmaf(zc, e0[c], a0);
                a1 = fmaf(zc, e1[c], a1);
                a2 = fmaf(zc, e2[c], a2);
                a3 = fmaf(zc, e3[c], a3);
            }
            float d0 = (zzv + ee[k0]) - 2.f * a0;
            float d1 = (zzv + ee[k1]) - 2.f * a1;
            float d2 = (zzv + ee[k2]) - 2.f * a2;
            float d3 = (zzv + ee[k3]) - 2.f * a3;
            if (d0 < bd || (d0 == bd && k0 < bk)) { bd = d0; bk = k0; }
            if (d1 < bd || (d1 == bd && k1 < bk)) { bd = d1; bk = k1; }
            if (d2 < bd || (d2 == bd && k2 < bk)) { bd = d2; bk = k2; }
            if (d3 < bd || (d3 == bd && k3 < bk)) { bd = d3; bk = k3; }
        }
    }
    idx_out[n] = bk;
}

// ======================================================================
// k_main (fallback path only): exact fp32 distances + argmin, proven.
// ======================================================================
#define TM 64
#define TK 128
#define CCH 64
__global__ __launch_bounds__(256) void k_main(const float* __restrict__ z,
                                              const float* __restrict__ eT,
                                              const float* __restrict__ ee,
                                              const float* __restrict__ zz,
                                              int* __restrict__ idx_out) {
    __shared__ float zt[CCH][TM];
    __shared__ float et[CCH][TK];
    __shared__ float redv[TM][16];
    __shared__ int   redi[TM][16];
    __shared__ float bestv[TM];
    __shared__ int   besti[TM];
    __shared__ float zzl[TM];
    int t = threadIdx.x;
    int n0 = blockIdx.x * TM;
    int b = n0 >> 10, hw0 = n0 & 1023;
    const float* zb = z + (size_t)b * ZPLANE + hw0;
    int trow = t >> 4, tcol = t & 15;
    if (t < TM) { bestv[t] = 3.4e38f; besti[t] = 0; zzl[t] = zz[n0 + t]; }
    for (int kt = 0; kt < NE / TK; ++kt) {
        int k0 = kt * TK;
        float acc[4][8];
        for (int i = 0; i < 4; ++i)
            for (int j = 0; j < 8; ++j) acc[i][j] = 0.f;
        for (int cc = 0; cc < ED / CCH; ++cc) {
            __syncthreads();
            {
                int m4 = (t & 15) * 4; int cb0 = t >> 4;
                for (int p = 0; p < 4; ++p) {
                    int cl = p * 16 + cb0;
                    float4 v = *(const float4*)(zb + (size_t)(cc * CCH + cl) * 1024 + m4);
                    *(float4*)&zt[cl][m4] = v;
                }
            }
            {
                int k4 = (t & 31) * 4; int cb0 = t >> 5;
                for (int p = 0; p < 8; ++p) {
                    int cl = p * 8 + cb0;
                    float4 v = *(const float4*)(eT + (size_t)(cc * CCH + cl) * 1024 + k0 + k4);
                    *(float4*)&et[cl][k4] = v;
                }
            }
            __syncthreads();
            for (int c = 0; c < CCH; ++c) {
                float4 zm = *(const float4*)&zt[c][trow * 4];
                float4 e0 = *(const float4*)&et[c][tcol * 8];
                float4 e1 = *(const float4*)&et[c][tcol * 8 + 4];
                float zv[4] = {zm.x, zm.y, zm.z, zm.w};
                float ev[8] = {e0.x, e0.y, e0.z, e0.w, e1.x, e1.y, e1.z, e1.w};
                for (int i = 0; i < 4; ++i)
                    for (int j = 0; j < 8; ++j)
                        acc[i][j] = fmaf(zv[i], ev[j], acc[i][j]);
            }
        }
        for (int i = 0; i < 4; ++i) {
            int m = trow * 4 + i;
            float zv = zzl[m];
            float bv = 3.4e38f; int bi = 0;
            for (int j = 0; j < 8; ++j) {
                int k = k0 + tcol * 8 + j;
                float t1 = zv + ee[k];
                float d  = t1 - 2.0f * acc[i][j];
                if (d < bv) { bv = d; bi = k; }
            }
            redv[m][tcol] = bv; redi[m][tcol] = bi;
        }
        __syncthreads();
        if (t < TM) {
            float bv = bestv[t]; int bi = besti[t];
            for (int tc = 0; tc < 16; ++tc) {
                float v = redv[t][tc]; int ix = redi[t][tc];
                if (v < bv || (v == bv && ix < bi)) { bv = v; bi = ix; }
            }
            bestv[t] = bv; besti[t] = bi;
        }
    }
    __syncthreads();
    if (t < TM) idx_out[n0 + t] = besti[t];
}

// ======================================================================
// k_out1: z_q straight-through (B,C,H,W) + loss partials.
// use_eT: fallback reads eT[c*NE+iv]; fast path reads cb[iv*ED+c].
// ======================================================================
__global__ __launch_bounds__(256) void k_out1(const float* __restrict__ z,
                                              const float* __restrict__ ecb,
                                              const int* __restrict__ idx,
                                              float* __restrict__ out,
                                              double* __restrict__ lossp,
                                              int use_eT) {
#pragma clang fp contract(off)
    int t = threadIdx.x;
    double lsum = 0.0;
    for (int it = 0; it < 4; ++it) {
        int e = (blockIdx.x * 4 + it) * 256 + t;
        int c  = (e >> 10) & 255;
        int bb = e >> 18;
        int hw = e & 1023;
        int n  = (bb << 10) + hw;
        int iv = idx[n];
        float zv = z[e];
        float zq = use_eT ? ecb[(size_t)c * NE + iv] : ecb[(size_t)iv * ED + c];
        float d  = zq - zv;
        out[OFF_ZQ + (size_t)e] = zv + d;
        lsum += (double)(d * d);
    }
    for (int off = 32; off; off >>= 1) lsum += __shfl_down(lsum, off);
    __shared__ double wsum[4];
    if ((t & 63) == 0) wsum[t >> 6] = lsum;
    __syncthreads();
    if (t == 0) lossp[blockIdx.x] = (wsum[0] + wsum[1]) + (wsum[2] + wsum[3]);
}

// ======================================================================
// k_out2: one-hot encodings (float4 stores) + indices
// ======================================================================
__global__ __launch_bounds__(256) void k_out2(const int* __restrict__ idx,
                                              float* __restrict__ out) {
    int t = threadIdx.x;
    for (int it = 0; it < 16; ++it) {
        int q = (blockIdx.x * 16 + it) * 256 + t;  // grid 2048 -> 8388608 float4
        int row  = q >> 8;
        int col4 = (q & 255) * 4;
        int iv = idx[row];
        float4 v;
        v.x = (col4     == iv) ? 1.f : 0.f;
        v.y = (col4 + 1 == iv) ? 1.f : 0.f;
        v.z = (col4 + 2 == iv) ? 1.f : 0.f;
        v.w = (col4 + 3 == iv) ? 1.f : 0.f;
        *(float4*)(out + OFF_ENC + (size_t)q * 4) = v;
        if ((q & 255) == 0) out[OFF_IDX + row] = (float)iv;
    }
}

// ======================================================================
// k_final: perplexity + loss scalar, deterministic
// ======================================================================
__global__ __launch_bounds__(256) void k_final(const int* __restrict__ idx,
                                               const double* __restrict__ lossp,
                                               float* __restrict__ out) {
    __shared__ int cnt[NE];
    __shared__ double sh[4];
    int t = threadIdx.x;
    for (int k = t; k < NE; k += 256) cnt[k] = 0;
    __syncthreads();
    for (int n = t; n < NPTS; n += 256) atomicAdd(&cnt[idx[n]], 1);
    __syncthreads();
    double psum = 0.0;
    for (int k = t; k < NE; k += 256) {
        float em = (float)cnt[k] / 32768.0f;
        float term = em * logf(em + 1e-10f);
        psum += (double)term;
    }
    for (int off = 32; off; off >>= 1) psum += __shfl_down(psum, off);
    if ((t & 63) == 0) sh[t >> 6] = psum;
    __syncthreads();
    if (t == 0) {
        double tot = (sh[0] + sh[1]) + (sh[2] + sh[3]);
        out[OFF_PPL] = expf(-(float)tot);
    }
    __syncthreads();
    double ls = 0.0;
    for (int i = t; i < NLOSSP; i += 256) ls += lossp[i];
    for (int off = 32; off; off >>= 1) ls += __shfl_down(ls, off);
    __syncthreads();
    if ((t & 63) == 0) sh[t >> 6] = ls;
    __syncthreads();
    if (t == 0) {
        double m = ((sh[0] + sh[1]) + (sh[2] + sh[3])) / 8388608.0;
        float mf = (float)m;
        out[OFF_LOSS] = mf + 0.25f * mf;
    }
}

// ======================================================================
extern "C" void kernel_launch(void* const* d_in, const int* in_sizes, int n_in,
                              void* d_out, int out_size, void* d_ws, size_t ws_size,
                              hipStream_t stream) {
    const float* z  = (const float*)d_in[0];
    const float* cb = (const float*)d_in[1];
    float* out = (float*)d_out;
    char* ws = (char*)d_ws;

    int*    idx   = (int*)(ws + WS_IDX);
    float*  zz    = (float*)(ws + WS_ZZ);
    float*  ee    = (float*)(ws + WS_EE);
    double* lossp = (double*)(ws + WS_LOSSP);

    if (ws_size >= WS_NEED) {
        u16* eh = (u16*)(ws + WS_EH);
        u16* el = (u16*)(ws + WS_EL);
        u16* zh = (u16*)(ws + WS_ZH);
        u16* zl = (u16*)(ws + WS_ZL);
        u8*  ccnt  = (u8*)(ws + WS_CCNT);
        int* candk = (int*)(ws + WS_CANDK);
        float* cands = (float*)(ws + WS_CANDS);

        k_prep   <<<4,    256, 0, stream>>>(cb, ee, eh, el);
        k_zz     <<<128,  256, 0, stream>>>(z, zz);
        k_zsplit <<<2048, 256, 0, stream>>>(z, zh, zl);
        k_filter <<<1024, 256, 0, stream>>>(zh, zl, eh, el, ee, ccnt, candk, cands);
        k_rescore<<<256,  128, 0, stream>>>(z, cb, ee, zz, ccnt, candk, cands, idx);
        k_out1   <<<8192, 256, 0, stream>>>(z, cb, idx, out, lossp, 0);
    } else {
        float* eT = (float*)(ws + WS_ET_FB);
        k_prep_old<<<4,   256, 0, stream>>>(cb, ee, eT);
        k_zz      <<<128, 256, 0, stream>>>(z, zz);
        k_main    <<<512, 256, 0, stream>>>(z, eT, ee, zz, idx);
        k_out1    <<<8192,256, 0, stream>>>(z, eT, idx, out, lossp, 1);
    }
    k_out2 <<<2048, 256, 0, stream>>>(idx, out);
    k_final<<<1,    256, 0, stream>>>(idx, lossp, out);
}

// Round 5
// 506.793 us; speedup vs baseline: 5.3161x; 4.8229x over previous
//
#include <hip/hip_runtime.h>
#include <hip/hip_bf16.h>
#include <cstdint>
#include <cstddef>

typedef unsigned short u16;
typedef unsigned char u8;
typedef __attribute__((ext_vector_type(8))) short bf16x8;
typedef __attribute__((ext_vector_type(4))) float f32x4;

// ---- problem sizes ----
#define NPTS 32768      // B*H*W = 32*32*32
#define NE   1024       // codes
#define ED   256        // embedding dim (= C)
#define ZPLANE 262144   // 256*1024 floats per batch image (C*H*W)

// ---- output layout (floats) ----
#define OFF_LOSS 0
#define OFF_ZQ   1
#define OFF_PPL  8388609
#define OFF_ENC  8388610
#define OFF_IDX  41943042

// ---- ws layout (bytes) ----
#define WS_IDX   0              // int[32768]
#define WS_ZZ    131072         // float[32768]
#define WS_EE    262144         // float[1024]
#define WS_LOSSP 266240         // double[8192]
#define NLOSSP   8192
#define WS_ET_FB 331776         // float[256*1024] (FALLBACK ONLY, overlays EH/EL)
#define WS_EH    331776         // u16[1024*256]
#define WS_EL    856064
#define WS_ZH    1380352        // u16[32768*256]
#define WS_ZL    18157568
#define WS_CCNT  34934784       // u8[4*32768] packed counts
#define WS_CANDK 35065856       // int[12*32768]
#define WS_CANDS 36638720       // float[12*32768]
#define WS_OCNT  38211584       // int: overflow count
#define WS_OLIST 38211588       // int[4096]: overflow point list
#define WS_NEED  38227972ULL

#define MARGIN 3.0e-4f          // k_filter emission margin (capture bound)
#define AMB    2.0e-4f          // certification ambiguity window (>2E, <=MARGIN)
#define OCAP   4096

// ======================================================================
// k_prep: ||e||^2 (numpy pairwise order) + bf16 hi/lo split + ocnt=0
// ======================================================================
__global__ __launch_bounds__(256) void k_prep(const float* __restrict__ cb,
                                              float* __restrict__ ee,
                                              u16* __restrict__ eh,
                                              u16* __restrict__ el,
                                              int* __restrict__ ocnt) {
#pragma clang fp contract(off)
    if (blockIdx.x == 0 && threadIdx.x == 0) *ocnt = 0;
    int k = blockIdx.x * 256 + threadIdx.x;
    if (k >= NE) return;
    const float* row = cb + (size_t)k * ED;
    float s[2];
    for (int h = 0; h < 2; ++h) {
        const float* a = row + h * 128;
        float r[8];
        for (int j = 0; j < 8; ++j) { float v = a[j]; r[j] = v * v; }
        for (int i = 8; i < 128; i += 8)
            for (int j = 0; j < 8; ++j) { float v = a[i + j]; r[j] += v * v; }
        s[h] = ((r[0] + r[1]) + (r[2] + r[3])) + ((r[4] + r[5]) + (r[6] + r[7]));
    }
    ee[k] = s[0] + s[1];
    for (int c = 0; c < ED; ++c) {
        float f = row[c];
        __hip_bfloat16 h = __float2bfloat16(f);
        float hf = __bfloat162float(h);
        __hip_bfloat16 l = __float2bfloat16(f - hf);
        eh[(size_t)k * ED + c] = *(u16*)&h;
        el[(size_t)k * ED + c] = *(u16*)&l;
    }
}

// k_prep_old: fallback (also writes eT)
__global__ __launch_bounds__(256) void k_prep_old(const float* __restrict__ cb,
                                                  float* __restrict__ ee,
                                                  float* __restrict__ eT) {
#pragma clang fp contract(off)
    int k = blockIdx.x * 256 + threadIdx.x;
    if (k >= NE) return;
    const float* row = cb + (size_t)k * ED;
    float s[2];
    for (int h = 0; h < 2; ++h) {
        const float* a = row + h * 128;
        float r[8];
        for (int j = 0; j < 8; ++j) { float v = a[j]; r[j] = v * v; }
        for (int i = 8; i < 128; i += 8)
            for (int j = 0; j < 8; ++j) { float v = a[i + j]; r[j] += v * v; }
        s[h] = ((r[0] + r[1]) + (r[2] + r[3])) + ((r[4] + r[5]) + (r[6] + r[7]));
    }
    ee[k] = s[0] + s[1];
    for (int c = 0; c < ED; ++c) eT[(size_t)c * NE + k] = row[c];
}

// ======================================================================
// k_zz: per-point ||z||^2, numpy pairwise order (proven exact)
// ======================================================================
__global__ __launch_bounds__(256) void k_zz(const float* __restrict__ z,
                                            float* __restrict__ zz) {
#pragma clang fp contract(off)
    int n = blockIdx.x * 256 + threadIdx.x;      // 128 blocks
    int b = n >> 10, hw = n & 1023;
    const float* a0 = z + (size_t)b * ZPLANE + hw;
    float s[2];
    for (int h = 0; h < 2; ++h) {
        const float* a = a0 + (size_t)h * 128 * 1024;
        float r[8];
        for (int j = 0; j < 8; ++j) { float v = a[(size_t)j * 1024]; r[j] = v * v; }
        for (int i = 8; i < 128; i += 8)
            for (int j = 0; j < 8; ++j) { float v = a[(size_t)(i + j) * 1024]; r[j] += v * v; }
        s[h] = ((r[0] + r[1]) + (r[2] + r[3])) + ((r[4] + r[5]) + (r[6] + r[7]));
    }
    zz[n] = s[0] + s[1];
}

// ======================================================================
// k_zsplit: transpose z (b,c,hw)->point-major + bf16 hi/lo split
// ======================================================================
__global__ __launch_bounds__(256) void k_zsplit(const float* __restrict__ z,
                                                u16* __restrict__ zh,
                                                u16* __restrict__ zl) {
    __shared__ float tile[64][65];
    int t = threadIdx.x;
    int blk = blockIdx.x;              // 2048 = 32b * 4c * 16hw
    int b   = blk >> 6;
    int c0  = ((blk >> 4) & 3) * 64;
    int hw0 = (blk & 15) * 64;
    int lane = t & 63, q = t >> 6;
    for (int i = 0; i < 16; ++i) {
        int cl = i * 4 + q;
        tile[cl][lane] = z[(size_t)b * ZPLANE + (size_t)(c0 + cl) * 1024 + hw0 + lane];
    }
    __syncthreads();
    int p = t >> 2, cq = t & 3;
    size_t n = (size_t)b * 1024 + hw0 + p;
    u16 hbuf[16], lbuf[16];
#pragma unroll
    for (int k = 0; k < 16; ++k) {
        float f = tile[cq * 16 + k][p];
        __hip_bfloat16 h = __float2bfloat16(f);
        float hf = __bfloat162float(h);
        __hip_bfloat16 l = __float2bfloat16(f - hf);
        hbuf[k] = *(u16*)&h; lbuf[k] = *(u16*)&l;
    }
    u16* dh = zh + n * 256 + c0 + cq * 16;
    u16* dl = zl + n * 256 + c0 + cq * 16;
    *(bf16x8*)(dh)     = *(bf16x8*)&hbuf[0];
    *(bf16x8*)(dh + 8) = *(bf16x8*)&hbuf[8];
    *(bf16x8*)(dl)     = *(bf16x8*)&lbuf[0];
    *(bf16x8*)(dl + 8) = *(bf16x8*)&lbuf[8];
}

// ======================================================================
// k_filter: bf16x3 MFMA approx scores + margin candidate emission
// (stores score values; appends overflow points to global list).
// ======================================================================
__global__ __launch_bounds__(256, 4) void k_filter(const u16* __restrict__ zh,
                                                   const u16* __restrict__ zl,
                                                   const u16* __restrict__ eh,
                                                   const u16* __restrict__ el,
                                                   const float* __restrict__ ee,
                                                   u8* __restrict__ candcnt,
                                                   int* __restrict__ candk,
                                                   float* __restrict__ cands,
                                                   int* __restrict__ ocnt,
                                                   int* __restrict__ olist) {
    __shared__ u16  Bh[128 * 64];     // 16 KB, XOR-swizzled
    __shared__ u16  Bl[128 * 64];     // 16 KB
    __shared__ float eeL[128];
    __shared__ int  cntL[128];
    __shared__ int  ckL[128][3];
    __shared__ float csL[128][3];

    int t = threadIdx.x;
    int lane = t & 63, w = t >> 6;
    int g = blockIdx.x & 255;
    int q = blockIdx.x >> 8;
    int n0 = g * 128;
    int kqbase = q * 256;
    int prow = w * 32 + (lane & 15);
    const u16* zh0 = zh + (size_t)(n0 + prow) * 256;
    const u16* zl0 = zl + (size_t)(n0 + prow) * 256;
    const u16* zh1 = zh0 + 16 * 256;
    const u16* zl1 = zl0 + 16 * 256;
    int koff_lane = (lane >> 4) * 8;

    if (t < 128) cntL[t] = 0;
    float runmin[2][4];
#pragma unroll
    for (int gg = 0; gg < 2; ++gg)
#pragma unroll
        for (int j = 0; j < 4; ++j) runmin[gg][j] = 3.4e38f;

    for (int nc = 0; nc < 2; ++nc) {
        int kcbase = kqbase + nc * 128;
        f32x4 acc0[8], acc1[8];
#pragma unroll
        for (int nf = 0; nf < 8; ++nf) {
            acc0[nf] = (f32x4){0.f, 0.f, 0.f, 0.f};
            acc1[nf] = (f32x4){0.f, 0.f, 0.f, 0.f};
        }
        for (int kb = 0; kb < 4; ++kb) {
            __syncthreads();
            if (kb == 0 && t < 128) eeL[t] = ee[kcbase + t];
#pragma unroll
            for (int i = 0; i < 8; ++i) {
                int f = i * 256 + t;
                int a = f >> 10, r = (f >> 3) & 127, seg = f & 7;
                const u16* src = (a ? el : eh) + (size_t)(kcbase + r) * 256 + kb * 64 + seg * 8;
                bf16x8 v = *(const bf16x8*)src;
                int bo = (r * 128 + seg * 16) ^ ((r & 7) << 4);
                *(bf16x8*)((char*)(a ? Bl : Bh) + bo) = v;
            }
            __syncthreads();
#pragma unroll
            for (int ks2 = 0; ks2 < 2; ++ks2) {
                int ko = kb * 64 + ks2 * 32 + koff_lane;
                bf16x8 ah0 = *(const bf16x8*)(zh0 + ko);
                bf16x8 al0 = *(const bf16x8*)(zl0 + ko);
                bf16x8 ah1 = *(const bf16x8*)(zh1 + ko);
                bf16x8 al1 = *(const bf16x8*)(zl1 + ko);
#pragma unroll
                for (int nf = 0; nf < 8; ++nf) {
                    int r = nf * 16 + (lane & 15);
                    int bo = (r * 128 + ks2 * 64 + (lane >> 4) * 16) ^ ((r & 7) << 4);
                    bf16x8 bh = *(const bf16x8*)((const char*)Bh + bo);
                    bf16x8 bl = *(const bf16x8*)((const char*)Bl + bo);
                    acc0[nf] = __builtin_amdgcn_mfma_f32_16x16x32_bf16(ah0, bh, acc0[nf], 0, 0, 0);
                    acc0[nf] = __builtin_amdgcn_mfma_f32_16x16x32_bf16(al0, bh, acc0[nf], 0, 0, 0);
                    acc0[nf] = __builtin_amdgcn_mfma_f32_16x16x32_bf16(ah0, bl, acc0[nf], 0, 0, 0);
                    acc1[nf] = __builtin_amdgcn_mfma_f32_16x16x32_bf16(ah1, bh, acc1[nf], 0, 0, 0);
                    acc1[nf] = __builtin_amdgcn_mfma_f32_16x16x32_bf16(al1, bh, acc1[nf], 0, 0, 0);
                    acc1[nf] = __builtin_amdgcn_mfma_f32_16x16x32_bf16(ah1, bl, acc1[nf], 0, 0, 0);
                }
            }
        }
        // epilogue: s = ee - 2*dot'; chunk-min; emission vs quarter running min
#pragma unroll
        for (int gg = 0; gg < 2; ++gg) {
#pragma unroll
            for (int nf = 0; nf < 8; ++nf) {
                float eev = eeL[nf * 16 + (lane & 15)];
                f32x4 d = gg ? acc1[nf] : acc0[nf];
                f32x4 s;
#pragma unroll
                for (int j = 0; j < 4; ++j) s[j] = fmaf(-2.f, d[j], eev);
                if (gg) acc1[nf] = s; else acc0[nf] = s;
            }
#pragma unroll
            for (int j = 0; j < 4; ++j) {
                float m = 3.4e38f;
#pragma unroll
                for (int nf = 0; nf < 8; ++nf) m = fminf(m, gg ? acc1[nf][j] : acc0[nf][j]);
                m = fminf(m, __shfl_xor(m, 1, 64));
                m = fminf(m, __shfl_xor(m, 2, 64));
                m = fminf(m, __shfl_xor(m, 4, 64));
                m = fminf(m, __shfl_xor(m, 8, 64));
                runmin[gg][j] = fminf(runmin[gg][j], m);
                float th = runmin[gg][j] + MARGIN;
                int ml = w * 32 + gg * 16 + (lane >> 4) * 4 + j;
#pragma unroll
                for (int nf = 0; nf < 8; ++nf) {
                    float sv = gg ? acc1[nf][j] : acc0[nf][j];
                    if (sv <= th) {
                        int pos = atomicAdd(&cntL[ml], 1);
                        if (pos < 3) { ckL[ml][pos] = kcbase + nf * 16 + (lane & 15);
                                       csL[ml][pos] = sv; }
                    }
                }
            }
        }
    }
    __syncthreads();
    if (t < 128) {
        int n = n0 + t;
        int cnt = cntL[t];
        candcnt[(size_t)n * 4 + q] = (u8)(cnt > 255 ? 255 : cnt);
        int* dk = candk + (size_t)n * 12 + q * 3;
        float* ds = cands + (size_t)n * 12 + q * 3;
#pragma unroll
        for (int i = 0; i < 3; ++i) {
            dk[i] = (i < cnt) ? ckL[t][i] : 0;
            ds[i] = (i < cnt) ? csL[t][i] : 3.4e38f;
        }
        if (cnt > 3) {
            int pos = atomicAdd(ocnt, 1);
            if (pos < OCAP) olist[pos] = n;
        }
    }
}

// ======================================================================
// k_rescore: certification + survivors-only exact dots (all static-
// indexed, register-resident). Overflow points handled by k_exact.
// ======================================================================
__global__ __launch_bounds__(128) void k_rescore(const float* __restrict__ z,
                                                 const float* __restrict__ cb,
                                                 const float* __restrict__ ee,
                                                 const float* __restrict__ zz,
                                                 const u8* __restrict__ candcnt,
                                                 const int* __restrict__ candk,
                                                 const float* __restrict__ cands,
                                                 int* __restrict__ idx_out) {
    int t = threadIdx.x;
    int n = blockIdx.x * 128 + t;                 // 256 blocks
    int packed = ((const int*)candcnt)[n];
    int c0 = packed & 255, c1 = (packed >> 8) & 255,
        c2 = (packed >> 16) & 255, c3 = (packed >> 24) & 255;
    if ((c0 > 3) | (c1 > 3) | (c2 > 3) | (c3 > 3)) return;  // k_exact owns it

    int ks[12]; float ss[12];
    const int*   ck = candk + (size_t)n * 12;
    const float* cs = cands + (size_t)n * 12;
#pragma unroll
    for (int p = 0; p < 3; ++p) {
        *(int4*)&ks[p * 4]   = *(const int4*)(ck + p * 4);
        *(float4*)&ss[p * 4] = *(const float4*)(cs + p * 4);
    }
    float gmin = 3.4e38f;
#pragma unroll
    for (int j = 0; j < 12; ++j) gmin = fminf(gmin, ss[j]);
    float th = gmin + AMB;

    int nsurv = 0;
#pragma unroll
    for (int j = 0; j < 12; ++j) nsurv += (ss[j] <= th) ? 1 : 0;

    if (nsurv == 1) {
        // certified: unique survivor is provably the numpy argmin
        int k = 0;
#pragma unroll
        for (int j = 0; j < 12; ++j) if (ss[j] <= th) k = ks[j];
        idx_out[n] = k;
        return;
    }

    // ambiguous (~2-3% of points): exact fp32 d for survivors only
    int b = n >> 10, hw = n & 1023;
    const float* zp = z + (size_t)b * ZPLANE + hw;
    float zzv = zz[n];
    float bd = 3.4e38f; int bk = 1 << 30;
#pragma unroll
    for (int j = 0; j < 12; ++j) {
        if (ss[j] <= th) {
            int k = ks[j];
            const float* e0 = cb + (size_t)k * ED;
            float a0 = 0.f;
            for (int c = 0; c < ED; c += 4) {
                float4 ev = *(const float4*)(e0 + c);
                a0 = fmaf(zp[(size_t)c * 1024],       ev.x, a0);
                a0 = fmaf(zp[(size_t)(c + 1) * 1024], ev.y, a0);
                a0 = fmaf(zp[(size_t)(c + 2) * 1024], ev.z, a0);
                a0 = fmaf(zp[(size_t)(c + 3) * 1024], ev.w, a0);
            }
            float d0 = (zzv + ee[k]) - 2.f * a0;
            if (d0 < bd || (d0 == bd && k < bk)) { bd = d0; bk = k; }
        }
    }
    idx_out[n] = bk;
}

// ======================================================================
// k_exact: full 1024-code exact scan for overflow points (one point per
// block iteration; z-row staged in LDS; deterministic index-tie argmin).
// ======================================================================
__global__ __launch_bounds__(256) void k_exact(const float* __restrict__ z,
                                               const float* __restrict__ cb,
                                               const float* __restrict__ ee,
                                               const float* __restrict__ zz,
                                               const int* __restrict__ ocnt,
                                               const int* __restrict__ olist,
                                               int* __restrict__ idx_out) {
    __shared__ float zL[ED];
    __shared__ float rv[4];
    __shared__ int   ri[4];
    int cnt = *ocnt; if (cnt > OCAP) cnt = OCAP;
    int t = threadIdx.x;
    for (int i = blockIdx.x; i < cnt; i += gridDim.x) {
        int n = olist[i];
        int b = n >> 10, hw = n & 1023;
        const float* zp = z + (size_t)b * ZPLANE + hw;
        __syncthreads();
        zL[t] = zp[(size_t)t * 1024];
        __syncthreads();
        float zzv = zz[n];
        float bd = 3.4e38f; int bk = 1 << 30;
#pragma unroll 1
        for (int rep = 0; rep < 4; ++rep) {
            int k = rep * 256 + t;
            const float* e0 = cb + (size_t)k * ED;
            float a0 = 0.f;
            for (int c = 0; c < ED; c += 4) {
                float4 ev = *(const float4*)(e0 + c);
                a0 = fmaf(zL[c],     ev.x, a0);
                a0 = fmaf(zL[c + 1], ev.y, a0);
                a0 = fmaf(zL[c + 2], ev.z, a0);
                a0 = fmaf(zL[c + 3], ev.w, a0);
            }
            float d0 = (zzv + ee[k]) - 2.f * a0;
            if (d0 < bd || (d0 == bd && k < bk)) { bd = d0; bk = k; }
        }
        for (int off = 32; off; off >>= 1) {
            float ov = __shfl_down(bd, off);
            int   oi = __shfl_down(bk, off);
            if (ov < bd || (ov == bd && oi < bk)) { bd = ov; bk = oi; }
        }
        if ((t & 63) == 0) { rv[t >> 6] = bd; ri[t >> 6] = bk; }
        __syncthreads();
        if (t == 0) {
            for (int wv = 1; wv < 4; ++wv)
                if (rv[wv] < bd || (rv[wv] == bd && ri[wv] < bk)) { bd = rv[wv]; bk = ri[wv]; }
            idx_out[n] = bk;
        }
    }
}

// ======================================================================
// k_main (fallback path only): exact fp32 distances + argmin, proven.
// ======================================================================
#define TM 64
#define TK 128
#define CCH 64
__global__ __launch_bounds__(256) void k_main(const float* __restrict__ z,
                                              const float* __restrict__ eT,
                                              const float* __restrict__ ee,
                                              const float* __restrict__ zz,
                                              int* __restrict__ idx_out) {
    __shared__ float zt[CCH][TM];
    __shared__ float et[CCH][TK];
    __shared__ float redv[TM][16];
    __shared__ int   redi[TM][16];
    __shared__ float bestv[TM];
    __shared__ int   besti[TM];
    __shared__ float zzl[TM];
    int t = threadIdx.x;
    int n0 = blockIdx.x * TM;
    int b = n0 >> 10, hw0 = n0 & 1023;
    const float* zb = z + (size_t)b * ZPLANE + hw0;
    int trow = t >> 4, tcol = t & 15;
    if (t < TM) { bestv[t] = 3.4e38f; besti[t] = 0; zzl[t] = zz[n0 + t]; }
    for (int kt = 0; kt < NE / TK; ++kt) {
        int k0 = kt * TK;
        float acc[4][8];
        for (int i = 0; i < 4; ++i)
            for (int j = 0; j < 8; ++j) acc[i][j] = 0.f;
        for (int cc = 0; cc < ED / CCH; ++cc) {
            __syncthreads();
            {
                int m4 = (t & 15) * 4; int cb0 = t >> 4;
                for (int p = 0; p < 4; ++p) {
                    int cl = p * 16 + cb0;
                    float4 v = *(const float4*)(zb + (size_t)(cc * CCH + cl) * 1024 + m4);
                    *(float4*)&zt[cl][m4] = v;
                }
            }
            {
                int k4 = (t & 31) * 4; int cb0 = t >> 5;
                for (int p = 0; p < 8; ++p) {
                    int cl = p * 8 + cb0;
                    float4 v = *(const float4*)(eT + (size_t)(cc * CCH + cl) * 1024 + k0 + k4);
                    *(float4*)&et[cl][k4] = v;
                }
            }
            __syncthreads();
            for (int c = 0; c < CCH; ++c) {
                float4 zm = *(const float4*)&zt[c][trow * 4];
                float4 e0 = *(const float4*)&et[c][tcol * 8];
                float4 e1 = *(const float4*)&et[c][tcol * 8 + 4];
                float zv[4] = {zm.x, zm.y, zm.z, zm.w};
                float ev[8] = {e0.x, e0.y, e0.z, e0.w, e1.x, e1.y, e1.z, e1.w};
                for (int i = 0; i < 4; ++i)
                    for (int j = 0; j < 8; ++j)
                        acc[i][j] = fmaf(zv[i], ev[j], acc[i][j]);
            }
        }
        for (int i = 0; i < 4; ++i) {
            int m = trow * 4 + i;
            float zv = zzl[m];
            float bv = 3.4e38f; int bi = 0;
            for (int j = 0; j < 8; ++j) {
                int k = k0 + tcol * 8 + j;
                float t1 = zv + ee[k];
                float d  = t1 - 2.0f * acc[i][j];
                if (d < bv) { bv = d; bi = k; }
            }
            redv[m][tcol] = bv; redi[m][tcol] = bi;
        }
        __syncthreads();
        if (t < TM) {
            float bv = bestv[t]; int bi = besti[t];
            for (int tc = 0; tc < 16; ++tc) {
                float v = redv[t][tc]; int ix = redi[t][tc];
                if (v < bv || (v == bv && ix < bi)) { bv = v; bi = ix; }
            }
            bestv[t] = bv; besti[t] = bi;
        }
    }
    __syncthreads();
    if (t < TM) idx_out[n0 + t] = besti[t];
}

// ======================================================================
// k_out1: z_q straight-through (B,C,H,W) + loss partials.
// ======================================================================
__global__ __launch_bounds__(256) void k_out1(const float* __restrict__ z,
                                              const float* __restrict__ ecb,
                                              const int* __restrict__ idx,
                                              float* __restrict__ out,
                                              double* __restrict__ lossp,
                                              int use_eT) {
#pragma clang fp contract(off)
    int t = threadIdx.x;
    double lsum = 0.0;
    for (int it = 0; it < 4; ++it) {
        int e = (blockIdx.x * 4 + it) * 256 + t;
        int c  = (e >> 10) & 255;
        int bb = e >> 18;
        int hw = e & 1023;
        int n  = (bb << 10) + hw;
        int iv = idx[n];
        float zv = z[e];
        float zq = use_eT ? ecb[(size_t)c * NE + iv] : ecb[(size_t)iv * ED + c];
        float d  = zq - zv;
        out[OFF_ZQ + (size_t)e] = zv + d;
        lsum += (double)(d * d);
    }
    for (int off = 32; off; off >>= 1) lsum += __shfl_down(lsum, off);
    __shared__ double wsum[4];
    if ((t & 63) == 0) wsum[t >> 6] = lsum;
    __syncthreads();
    if (t == 0) lossp[blockIdx.x] = (wsum[0] + wsum[1]) + (wsum[2] + wsum[3]);
}

// ======================================================================
// k_out2: one-hot encodings (float4 stores) + indices
// ======================================================================
__global__ __launch_bounds__(256) void k_out2(const int* __restrict__ idx,
                                              float* __restrict__ out) {
    int t = threadIdx.x;
    for (int it = 0; it < 16; ++it) {
        int q = (blockIdx.x * 16 + it) * 256 + t;  // grid 2048 -> 8388608 float4
        int row  = q >> 8;
        int col4 = (q & 255) * 4;
        int iv = idx[row];
        float4 v;
        v.x = (col4     == iv) ? 1.f : 0.f;
        v.y = (col4 + 1 == iv) ? 1.f : 0.f;
        v.z = (col4 + 2 == iv) ? 1.f : 0.f;
        v.w = (col4 + 3 == iv) ? 1.f : 0.f;
        *(float4*)(out + OFF_ENC + (size_t)q * 4) = v;
        if ((q & 255) == 0) out[OFF_IDX + row] = (float)iv;
    }
}

// ======================================================================
// k_final: perplexity + loss scalar, deterministic
// ======================================================================
__global__ __launch_bounds__(256) void k_final(const int* __restrict__ idx,
                                               const double* __restrict__ lossp,
                                               float* __restrict__ out) {
    __shared__ int cnt[NE];
    __shared__ double sh[4];
    int t = threadIdx.x;
    for (int k = t; k < NE; k += 256) cnt[k] = 0;
    __syncthreads();
    for (int n = t; n < NPTS; n += 256) atomicAdd(&cnt[idx[n]], 1);
    __syncthreads();
    double psum = 0.0;
    for (int k = t; k < NE; k += 256) {
        float em = (float)cnt[k] / 32768.0f;
        float term = em * logf(em + 1e-10f);
        psum += (double)term;
    }
    for (int off = 32; off; off >>= 1) psum += __shfl_down(psum, off);
    if ((t & 63) == 0) sh[t >> 6] = psum;
    __syncthreads();
    if (t == 0) {
        double tot = (sh[0] + sh[1]) + (sh[2] + sh[3]);
        out[OFF_PPL] = expf(-(float)tot);
    }
    __syncthreads();
    double ls = 0.0;
    for (int i = t; i < NLOSSP; i += 256) ls += lossp[i];
    for (int off = 32; off; off >>= 1) ls += __shfl_down(ls, off);
    __syncthreads();
    if ((t & 63) == 0) sh[t >> 6] = ls;
    __syncthreads();
    if (t == 0) {
        double m = ((sh[0] + sh[1]) + (sh[2] + sh[3])) / 8388608.0;
        float mf = (float)m;
        out[OFF_LOSS] = mf + 0.25f * mf;
    }
}

// ======================================================================
extern "C" void kernel_launch(void* const* d_in, const int* in_sizes, int n_in,
                              void* d_out, int out_size, void* d_ws, size_t ws_size,
                              hipStream_t stream) {
    const float* z  = (const float*)d_in[0];
    const float* cb = (const float*)d_in[1];
    float* out = (float*)d_out;
    char* ws = (char*)d_ws;

    int*    idx   = (int*)(ws + WS_IDX);
    float*  zz    = (float*)(ws + WS_ZZ);
    float*  ee    = (float*)(ws + WS_EE);
    double* lossp = (double*)(ws + WS_LOSSP);

    if (ws_size >= WS_NEED) {
        u16* eh = (u16*)(ws + WS_EH);
        u16* el = (u16*)(ws + WS_EL);
        u16* zh = (u16*)(ws + WS_ZH);
        u16* zl = (u16*)(ws + WS_ZL);
        u8*  ccnt  = (u8*)(ws + WS_CCNT);
        int* candk = (int*)(ws + WS_CANDK);
        float* cands = (float*)(ws + WS_CANDS);
        int* ocnt  = (int*)(ws + WS_OCNT);
        int* olist = (int*)(ws + WS_OLIST);

        k_prep   <<<4,    256, 0, stream>>>(cb, ee, eh, el, ocnt);
        k_zz     <<<128,  256, 0, stream>>>(z, zz);
        k_zsplit <<<2048, 256, 0, stream>>>(z, zh, zl);
        k_filter <<<1024, 256, 0, stream>>>(zh, zl, eh, el, ee, ccnt, candk, cands, ocnt, olist);
        k_rescore<<<256,  128, 0, stream>>>(z, cb, ee, zz, ccnt, candk, cands, idx);
        k_exact  <<<64,   256, 0, stream>>>(z, cb, ee, zz, ocnt, olist, idx);
        k_out1   <<<8192, 256, 0, stream>>>(z, cb, idx, out, lossp, 0);
    } else {
        float* eT = (float*)(ws + WS_ET_FB);
        k_prep_old<<<4,   256, 0, stream>>>(cb, ee, eT);
        k_zz      <<<128, 256, 0, stream>>>(z, zz);
        k_main    <<<512, 256, 0, stream>>>(z, eT, ee, zz, idx);
        k_out1    <<<8192,256, 0, stream>>>(z, eT, idx, out, lossp, 1);
    }
    k_out2 <<<2048, 256, 0, stream>>>(idx, out);
    k_final<<<1,    256, 0, stream>>>(idx, lossp, out);
}

// Round 6
// 386.835 us; speedup vs baseline: 6.9647x; 1.3101x over previous
//
#include <hip/hip_runtime.h>
#include <hip/hip_bf16.h>
#include <cstdint>
#include <cstddef>

typedef unsigned short u16;
typedef unsigned char u8;
typedef __attribute__((ext_vector_type(8))) short bf16x8;
typedef __attribute__((ext_vector_type(4))) float f32x4;

// ---- problem sizes ----
#define NPTS 32768      // B*H*W = 32*32*32
#define NE   1024       // codes
#define ED   256        // embedding dim (= C)
#define ZPLANE 262144   // 256*1024 floats per batch image (C*H*W)

// ---- output layout (floats) ----
#define OFF_LOSS 0
#define OFF_ZQ   1
#define OFF_PPL  8388609
#define OFF_ENC  8388610
#define OFF_IDX  41943042

// ---- ws layout (bytes) ----
#define WS_IDX   0              // int[32768]
#define WS_ZZ    131072         // float[32768]
#define WS_EE    262144         // float[1024]
#define WS_LOSSP 266240         // double[8192]
#define NLOSSP   8192
#define WS_ET_FB 331776         // float[256*1024] (FALLBACK ONLY, overlays EH/EL)
#define WS_EH    331776         // u16[1024*256]
#define WS_EL    856064
#define WS_ZH    1380352        // u16[32768*256]
#define WS_ZL    18157568
#define WS_CCNT  34934784       // u8[4*32768] packed counts
#define WS_CANDK 35065856       // int[12*32768]
#define WS_CANDS 36638720       // float[12*32768]
#define WS_OCNT  38211584       // int: overflow count
#define WS_OLIST 38211588       // int[4096]: overflow point list
#define WS_NEED  38227972ULL

#define MARGIN 3.0e-4f          // k_filter emission margin (capture bound)
#define AMB    2.0e-4f          // certification ambiguity window (>2E, <=MARGIN)
#define OCAP   4096

// ======================================================================
// k_prep: ||e||^2 (numpy pairwise order) + bf16 hi/lo split + ocnt=0
// ======================================================================
__global__ __launch_bounds__(256) void k_prep(const float* __restrict__ cb,
                                              float* __restrict__ ee,
                                              u16* __restrict__ eh,
                                              u16* __restrict__ el,
                                              int* __restrict__ ocnt) {
#pragma clang fp contract(off)
    if (blockIdx.x == 0 && threadIdx.x == 0) *ocnt = 0;
    int k = blockIdx.x * 256 + threadIdx.x;
    if (k >= NE) return;
    const float* row = cb + (size_t)k * ED;
    float s[2];
    for (int h = 0; h < 2; ++h) {
        const float* a = row + h * 128;
        float r[8];
        for (int j = 0; j < 8; ++j) { float v = a[j]; r[j] = v * v; }
        for (int i = 8; i < 128; i += 8)
            for (int j = 0; j < 8; ++j) { float v = a[i + j]; r[j] += v * v; }
        s[h] = ((r[0] + r[1]) + (r[2] + r[3])) + ((r[4] + r[5]) + (r[6] + r[7]));
    }
    ee[k] = s[0] + s[1];
    for (int c = 0; c < ED; ++c) {
        float f = row[c];
        __hip_bfloat16 h = __float2bfloat16(f);
        float hf = __bfloat162float(h);
        __hip_bfloat16 l = __float2bfloat16(f - hf);
        eh[(size_t)k * ED + c] = *(u16*)&h;
        el[(size_t)k * ED + c] = *(u16*)&l;
    }
}

// k_prep_old: fallback (also writes eT)
__global__ __launch_bounds__(256) void k_prep_old(const float* __restrict__ cb,
                                                  float* __restrict__ ee,
                                                  float* __restrict__ eT) {
#pragma clang fp contract(off)
    int k = blockIdx.x * 256 + threadIdx.x;
    if (k >= NE) return;
    const float* row = cb + (size_t)k * ED;
    float s[2];
    for (int h = 0; h < 2; ++h) {
        const float* a = row + h * 128;
        float r[8];
        for (int j = 0; j < 8; ++j) { float v = a[j]; r[j] = v * v; }
        for (int i = 8; i < 128; i += 8)
            for (int j = 0; j < 8; ++j) { float v = a[i + j]; r[j] += v * v; }
        s[h] = ((r[0] + r[1]) + (r[2] + r[3])) + ((r[4] + r[5]) + (r[6] + r[7]));
    }
    ee[k] = s[0] + s[1];
    for (int c = 0; c < ED; ++c) eT[(size_t)c * NE + k] = row[c];
}

// ======================================================================
// k_zz: per-point ||z||^2, numpy pairwise order (proven exact)
// ======================================================================
__global__ __launch_bounds__(256) void k_zz(const float* __restrict__ z,
                                            float* __restrict__ zz) {
#pragma clang fp contract(off)
    int n = blockIdx.x * 256 + threadIdx.x;      // 128 blocks
    int b = n >> 10, hw = n & 1023;
    const float* a0 = z + (size_t)b * ZPLANE + hw;
    float s[2];
    for (int h = 0; h < 2; ++h) {
        const float* a = a0 + (size_t)h * 128 * 1024;
        float r[8];
        for (int j = 0; j < 8; ++j) { float v = a[(size_t)j * 1024]; r[j] = v * v; }
        for (int i = 8; i < 128; i += 8)
            for (int j = 0; j < 8; ++j) { float v = a[(size_t)(i + j) * 1024]; r[j] += v * v; }
        s[h] = ((r[0] + r[1]) + (r[2] + r[3])) + ((r[4] + r[5]) + (r[6] + r[7]));
    }
    zz[n] = s[0] + s[1];
}

// ======================================================================
// k_zsplit: transpose z (b,c,hw)->point-major + bf16 hi/lo split
// ======================================================================
__global__ __launch_bounds__(256) void k_zsplit(const float* __restrict__ z,
                                                u16* __restrict__ zh,
                                                u16* __restrict__ zl) {
    __shared__ float tile[64][65];
    int t = threadIdx.x;
    int blk = blockIdx.x;              // 2048 = 32b * 4c * 16hw
    int b   = blk >> 6;
    int c0  = ((blk >> 4) & 3) * 64;
    int hw0 = (blk & 15) * 64;
    int lane = t & 63, q = t >> 6;
    for (int i = 0; i < 16; ++i) {
        int cl = i * 4 + q;
        tile[cl][lane] = z[(size_t)b * ZPLANE + (size_t)(c0 + cl) * 1024 + hw0 + lane];
    }
    __syncthreads();
    int p = t >> 2, cq = t & 3;
    size_t n = (size_t)b * 1024 + hw0 + p;
    u16 hbuf[16], lbuf[16];
#pragma unroll
    for (int k = 0; k < 16; ++k) {
        float f = tile[cq * 16 + k][p];
        __hip_bfloat16 h = __float2bfloat16(f);
        float hf = __bfloat162float(h);
        __hip_bfloat16 l = __float2bfloat16(f - hf);
        hbuf[k] = *(u16*)&h; lbuf[k] = *(u16*)&l;
    }
    u16* dh = zh + n * 256 + c0 + cq * 16;
    u16* dl = zl + n * 256 + c0 + cq * 16;
    *(bf16x8*)(dh)     = *(bf16x8*)&hbuf[0];
    *(bf16x8*)(dh + 8) = *(bf16x8*)&hbuf[8];
    *(bf16x8*)(dl)     = *(bf16x8*)&lbuf[0];
    *(bf16x8*)(dl + 8) = *(bf16x8*)&lbuf[8];
}

// ======================================================================
// k_filter: bf16x3 MFMA approx scores + margin candidate emission
// (stores score values; appends overflow points to global list).
// ======================================================================
__global__ __launch_bounds__(256, 4) void k_filter(const u16* __restrict__ zh,
                                                   const u16* __restrict__ zl,
                                                   const u16* __restrict__ eh,
                                                   const u16* __restrict__ el,
                                                   const float* __restrict__ ee,
                                                   u8* __restrict__ candcnt,
                                                   int* __restrict__ candk,
                                                   float* __restrict__ cands,
                                                   int* __restrict__ ocnt,
                                                   int* __restrict__ olist) {
    __shared__ u16  Bh[128 * 64];     // 16 KB, XOR-swizzled
    __shared__ u16  Bl[128 * 64];     // 16 KB
    __shared__ float eeL[128];
    __shared__ int  cntL[128];
    __shared__ int  ckL[128][3];
    __shared__ float csL[128][3];

    int t = threadIdx.x;
    int lane = t & 63, w = t >> 6;
    int g = blockIdx.x & 255;
    int q = blockIdx.x >> 8;
    int n0 = g * 128;
    int kqbase = q * 256;
    int prow = w * 32 + (lane & 15);
    const u16* zh0 = zh + (size_t)(n0 + prow) * 256;
    const u16* zl0 = zl + (size_t)(n0 + prow) * 256;
    const u16* zh1 = zh0 + 16 * 256;
    const u16* zl1 = zl0 + 16 * 256;
    int koff_lane = (lane >> 4) * 8;

    if (t < 128) cntL[t] = 0;
    float runmin[2][4];
#pragma unroll
    for (int gg = 0; gg < 2; ++gg)
#pragma unroll
        for (int j = 0; j < 4; ++j) runmin[gg][j] = 3.4e38f;

    for (int nc = 0; nc < 2; ++nc) {
        int kcbase = kqbase + nc * 128;
        f32x4 acc0[8], acc1[8];
#pragma unroll
        for (int nf = 0; nf < 8; ++nf) {
            acc0[nf] = (f32x4){0.f, 0.f, 0.f, 0.f};
            acc1[nf] = (f32x4){0.f, 0.f, 0.f, 0.f};
        }
        for (int kb = 0; kb < 4; ++kb) {
            __syncthreads();
            if (kb == 0 && t < 128) eeL[t] = ee[kcbase + t];
#pragma unroll
            for (int i = 0; i < 8; ++i) {
                int f = i * 256 + t;
                int a = f >> 10, r = (f >> 3) & 127, seg = f & 7;
                const u16* src = (a ? el : eh) + (size_t)(kcbase + r) * 256 + kb * 64 + seg * 8;
                bf16x8 v = *(const bf16x8*)src;
                int bo = (r * 128 + seg * 16) ^ ((r & 7) << 4);
                *(bf16x8*)((char*)(a ? Bl : Bh) + bo) = v;
            }
            __syncthreads();
#pragma unroll
            for (int ks2 = 0; ks2 < 2; ++ks2) {
                int ko = kb * 64 + ks2 * 32 + koff_lane;
                bf16x8 ah0 = *(const bf16x8*)(zh0 + ko);
                bf16x8 al0 = *(const bf16x8*)(zl0 + ko);
                bf16x8 ah1 = *(const bf16x8*)(zh1 + ko);
                bf16x8 al1 = *(const bf16x8*)(zl1 + ko);
#pragma unroll
                for (int nf = 0; nf < 8; ++nf) {
                    int r = nf * 16 + (lane & 15);
                    int bo = (r * 128 + ks2 * 64 + (lane >> 4) * 16) ^ ((r & 7) << 4);
                    bf16x8 bh = *(const bf16x8*)((const char*)Bh + bo);
                    bf16x8 bl = *(const bf16x8*)((const char*)Bl + bo);
                    acc0[nf] = __builtin_amdgcn_mfma_f32_16x16x32_bf16(ah0, bh, acc0[nf], 0, 0, 0);
                    acc0[nf] = __builtin_amdgcn_mfma_f32_16x16x32_bf16(al0, bh, acc0[nf], 0, 0, 0);
                    acc0[nf] = __builtin_amdgcn_mfma_f32_16x16x32_bf16(ah0, bl, acc0[nf], 0, 0, 0);
                    acc1[nf] = __builtin_amdgcn_mfma_f32_16x16x32_bf16(ah1, bh, acc1[nf], 0, 0, 0);
                    acc1[nf] = __builtin_amdgcn_mfma_f32_16x16x32_bf16(al1, bh, acc1[nf], 0, 0, 0);
                    acc1[nf] = __builtin_amdgcn_mfma_f32_16x16x32_bf16(ah1, bl, acc1[nf], 0, 0, 0);
                }
            }
        }
        // epilogue: s = ee - 2*dot'; chunk-min; emission vs quarter running min
#pragma unroll
        for (int gg = 0; gg < 2; ++gg) {
#pragma unroll
            for (int nf = 0; nf < 8; ++nf) {
                float eev = eeL[nf * 16 + (lane & 15)];
                f32x4 d = gg ? acc1[nf] : acc0[nf];
                f32x4 s;
#pragma unroll
                for (int j = 0; j < 4; ++j) s[j] = fmaf(-2.f, d[j], eev);
                if (gg) acc1[nf] = s; else acc0[nf] = s;
            }
#pragma unroll
            for (int j = 0; j < 4; ++j) {
                float m = 3.4e38f;
#pragma unroll
                for (int nf = 0; nf < 8; ++nf) m = fminf(m, gg ? acc1[nf][j] : acc0[nf][j]);
                m = fminf(m, __shfl_xor(m, 1, 64));
                m = fminf(m, __shfl_xor(m, 2, 64));
                m = fminf(m, __shfl_xor(m, 4, 64));
                m = fminf(m, __shfl_xor(m, 8, 64));
                runmin[gg][j] = fminf(runmin[gg][j], m);
                float th = runmin[gg][j] + MARGIN;
                int ml = w * 32 + gg * 16 + (lane >> 4) * 4 + j;
#pragma unroll
                for (int nf = 0; nf < 8; ++nf) {
                    float sv = gg ? acc1[nf][j] : acc0[nf][j];
                    if (sv <= th) {
                        int pos = atomicAdd(&cntL[ml], 1);
                        if (pos < 3) { ckL[ml][pos] = kcbase + nf * 16 + (lane & 15);
                                       csL[ml][pos] = sv; }
                    }
                }
            }
        }
    }
    __syncthreads();
    if (t < 128) {
        int n = n0 + t;
        int cnt = cntL[t];
        candcnt[(size_t)n * 4 + q] = (u8)(cnt > 255 ? 255 : cnt);
        int* dk = candk + (size_t)n * 12 + q * 3;
        float* ds = cands + (size_t)n * 12 + q * 3;
#pragma unroll
        for (int i = 0; i < 3; ++i) {
            dk[i] = (i < cnt) ? ckL[t][i] : 0;
            ds[i] = (i < cnt) ? csL[t][i] : 3.4e38f;
        }
        if (cnt > 3) {
            int pos = atomicAdd(ocnt, 1);
            if (pos < OCAP) olist[pos] = n;
        }
    }
}

// ======================================================================
// k_rescore: certification + survivors-only exact dots (all static-
// indexed, register-resident). Overflow points handled by k_exact.
// ======================================================================
__global__ __launch_bounds__(128) void k_rescore(const float* __restrict__ z,
                                                 const float* __restrict__ cb,
                                                 const float* __restrict__ ee,
                                                 const float* __restrict__ zz,
                                                 const u8* __restrict__ candcnt,
                                                 const int* __restrict__ candk,
                                                 const float* __restrict__ cands,
                                                 int* __restrict__ idx_out) {
    int t = threadIdx.x;
    int n = blockIdx.x * 128 + t;                 // 256 blocks
    int packed = ((const int*)candcnt)[n];
    int c0 = packed & 255, c1 = (packed >> 8) & 255,
        c2 = (packed >> 16) & 255, c3 = (packed >> 24) & 255;
    if ((c0 > 3) | (c1 > 3) | (c2 > 3) | (c3 > 3)) return;  // k_exact owns it

    int ks[12]; float ss[12];
    const int*   ck = candk + (size_t)n * 12;
    const float* cs = cands + (size_t)n * 12;
#pragma unroll
    for (int p = 0; p < 3; ++p) {
        *(int4*)&ks[p * 4]   = *(const int4*)(ck + p * 4);
        *(float4*)&ss[p * 4] = *(const float4*)(cs + p * 4);
    }
    float gmin = 3.4e38f;
#pragma unroll
    for (int j = 0; j < 12; ++j) gmin = fminf(gmin, ss[j]);
    float th = gmin + AMB;

    int nsurv = 0;
#pragma unroll
    for (int j = 0; j < 12; ++j) nsurv += (ss[j] <= th) ? 1 : 0;

    if (nsurv == 1) {
        // certified: unique survivor is provably the numpy argmin
        int k = 0;
#pragma unroll
        for (int j = 0; j < 12; ++j) if (ss[j] <= th) k = ks[j];
        idx_out[n] = k;
        return;
    }

    // ambiguous (~2-3% of points): exact fp32 d for survivors only
    int b = n >> 10, hw = n & 1023;
    const float* zp = z + (size_t)b * ZPLANE + hw;
    float zzv = zz[n];
    float bd = 3.4e38f; int bk = 1 << 30;
#pragma unroll
    for (int j = 0; j < 12; ++j) {
        if (ss[j] <= th) {
            int k = ks[j];
            const float* e0 = cb + (size_t)k * ED;
            float a0 = 0.f;
            for (int c = 0; c < ED; c += 4) {
                float4 ev = *(const float4*)(e0 + c);
                a0 = fmaf(zp[(size_t)c * 1024],       ev.x, a0);
                a0 = fmaf(zp[(size_t)(c + 1) * 1024], ev.y, a0);
                a0 = fmaf(zp[(size_t)(c + 2) * 1024], ev.z, a0);
                a0 = fmaf(zp[(size_t)(c + 3) * 1024], ev.w, a0);
            }
            float d0 = (zzv + ee[k]) - 2.f * a0;
            if (d0 < bd || (d0 == bd && k < bk)) { bd = d0; bk = k; }
        }
    }
    idx_out[n] = bk;
}

// ======================================================================
// k_exact: full 1024-code exact scan for overflow points. One point per
// block (grid-stride); 4 codes/thread as 4 INDEPENDENT fmaf chains
// (same per-code sequential arithmetic, 4-way ILP, pipelined loads).
// ======================================================================
__global__ __launch_bounds__(256) void k_exact(const float* __restrict__ z,
                                               const float* __restrict__ cb,
                                               const float* __restrict__ ee,
                                               const float* __restrict__ zz,
                                               const int* __restrict__ ocnt,
                                               const int* __restrict__ olist,
                                               int* __restrict__ idx_out) {
    __shared__ float zL[ED];
    __shared__ float rv[4];
    __shared__ int   ri[4];
    int cnt = *ocnt; if (cnt > OCAP) cnt = OCAP;
    int t = threadIdx.x;
    for (int i = blockIdx.x; i < cnt; i += gridDim.x) {
        int n = olist[i];
        int b = n >> 10, hw = n & 1023;
        const float* zp = z + (size_t)b * ZPLANE + hw;
        __syncthreads();
        zL[t] = zp[(size_t)t * 1024];
        __syncthreads();
        float zzv = zz[n];
        int k0 = t, k1 = 256 + t, k2 = 512 + t, k3 = 768 + t;
        const float* e0 = cb + (size_t)k0 * ED;
        const float* e1 = cb + (size_t)k1 * ED;
        const float* e2 = cb + (size_t)k2 * ED;
        const float* e3 = cb + (size_t)k3 * ED;
        float a0 = 0.f, a1 = 0.f, a2 = 0.f, a3 = 0.f;
#pragma unroll 8
        for (int c = 0; c < ED; c += 4) {
            float4 z4 = *(const float4*)&zL[c];
            float4 v0 = *(const float4*)(e0 + c);
            float4 v1 = *(const float4*)(e1 + c);
            float4 v2 = *(const float4*)(e2 + c);
            float4 v3 = *(const float4*)(e3 + c);
            a0 = fmaf(z4.x, v0.x, a0); a0 = fmaf(z4.y, v0.y, a0);
            a0 = fmaf(z4.z, v0.z, a0); a0 = fmaf(z4.w, v0.w, a0);
            a1 = fmaf(z4.x, v1.x, a1); a1 = fmaf(z4.y, v1.y, a1);
            a1 = fmaf(z4.z, v1.z, a1); a1 = fmaf(z4.w, v1.w, a1);
            a2 = fmaf(z4.x, v2.x, a2); a2 = fmaf(z4.y, v2.y, a2);
            a2 = fmaf(z4.z, v2.z, a2); a2 = fmaf(z4.w, v2.w, a2);
            a3 = fmaf(z4.x, v3.x, a3); a3 = fmaf(z4.y, v3.y, a3);
            a3 = fmaf(z4.z, v3.z, a3); a3 = fmaf(z4.w, v3.w, a3);
        }
        float d0 = (zzv + ee[k0]) - 2.f * a0;
        float d1 = (zzv + ee[k1]) - 2.f * a1;
        float d2 = (zzv + ee[k2]) - 2.f * a2;
        float d3 = (zzv + ee[k3]) - 2.f * a3;
        // ascending k order, strict < keeps lowest index
        float bd = d0; int bk = k0;
        if (d1 < bd) { bd = d1; bk = k1; }
        if (d2 < bd) { bd = d2; bk = k2; }
        if (d3 < bd) { bd = d3; bk = k3; }
        for (int off = 32; off; off >>= 1) {
            float ov = __shfl_down(bd, off);
            int   oi = __shfl_down(bk, off);
            if (ov < bd || (ov == bd && oi < bk)) { bd = ov; bk = oi; }
        }
        if ((t & 63) == 0) { rv[t >> 6] = bd; ri[t >> 6] = bk; }
        __syncthreads();
        if (t == 0) {
            for (int wv = 1; wv < 4; ++wv)
                if (rv[wv] < bd || (rv[wv] == bd && ri[wv] < bk)) { bd = rv[wv]; bk = ri[wv]; }
            idx_out[n] = bk;
        }
    }
}

// ======================================================================
// k_main (fallback path only): exact fp32 distances + argmin, proven.
// ======================================================================
#define TM 64
#define TK 128
#define CCH 64
__global__ __launch_bounds__(256) void k_main(const float* __restrict__ z,
                                              const float* __restrict__ eT,
                                              const float* __restrict__ ee,
                                              const float* __restrict__ zz,
                                              int* __restrict__ idx_out) {
    __shared__ float zt[CCH][TM];
    __shared__ float et[CCH][TK];
    __shared__ float redv[TM][16];
    __shared__ int   redi[TM][16];
    __shared__ float bestv[TM];
    __shared__ int   besti[TM];
    __shared__ float zzl[TM];
    int t = threadIdx.x;
    int n0 = blockIdx.x * TM;
    int b = n0 >> 10, hw0 = n0 & 1023;
    const float* zb = z + (size_t)b * ZPLANE + hw0;
    int trow = t >> 4, tcol = t & 15;
    if (t < TM) { bestv[t] = 3.4e38f; besti[t] = 0; zzl[t] = zz[n0 + t]; }
    for (int kt = 0; kt < NE / TK; ++kt) {
        int k0 = kt * TK;
        float acc[4][8];
        for (int i = 0; i < 4; ++i)
            for (int j = 0; j < 8; ++j) acc[i][j] = 0.f;
        for (int cc = 0; cc < ED / CCH; ++cc) {
            __syncthreads();
            {
                int m4 = (t & 15) * 4; int cb0 = t >> 4;
                for (int p = 0; p < 4; ++p) {
                    int cl = p * 16 + cb0;
                    float4 v = *(const float4*)(zb + (size_t)(cc * CCH + cl) * 1024 + m4);
                    *(float4*)&zt[cl][m4] = v;
                }
            }
            {
                int k4 = (t & 31) * 4; int cb0 = t >> 5;
                for (int p = 0; p < 8; ++p) {
                    int cl = p * 8 + cb0;
                    float4 v = *(const float4*)(eT + (size_t)(cc * CCH + cl) * 1024 + k0 + k4);
                    *(float4*)&et[cl][k4] = v;
                }
            }
            __syncthreads();
            for (int c = 0; c < CCH; ++c) {
                float4 zm = *(const float4*)&zt[c][trow * 4];
                float4 e0 = *(const float4*)&et[c][tcol * 8];
                float4 e1 = *(const float4*)&et[c][tcol * 8 + 4];
                float zv[4] = {zm.x, zm.y, zm.z, zm.w};
                float ev[8] = {e0.x, e0.y, e0.z, e0.w, e1.x, e1.y, e1.z, e1.w};
                for (int i = 0; i < 4; ++i)
                    for (int j = 0; j < 8; ++j)
                        acc[i][j] = fmaf(zv[i], ev[j], acc[i][j]);
            }
        }
        for (int i = 0; i < 4; ++i) {
            int m = trow * 4 + i;
            float zv = zzl[m];
            float bv = 3.4e38f; int bi = 0;
            for (int j = 0; j < 8; ++j) {
                int k = k0 + tcol * 8 + j;
                float t1 = zv + ee[k];
                float d  = t1 - 2.0f * acc[i][j];
                if (d < bv) { bv = d; bi = k; }
            }
            redv[m][tcol] = bv; redi[m][tcol] = bi;
        }
        __syncthreads();
        if (t < TM) {
            float bv = bestv[t]; int bi = besti[t];
            for (int tc = 0; tc < 16; ++tc) {
                float v = redv[t][tc]; int ix = redi[t][tc];
                if (v < bv || (v == bv && ix < bi)) { bv = v; bi = ix; }
            }
            bestv[t] = bv; besti[t] = bi;
        }
    }
    __syncthreads();
    if (t < TM) idx_out[n0 + t] = besti[t];
}

// ======================================================================
// k_out1: z_q straight-through (B,C,H,W) + loss partials.
// ======================================================================
__global__ __launch_bounds__(256) void k_out1(const float* __restrict__ z,
                                              const float* __restrict__ ecb,
                                              const int* __restrict__ idx,
                                              float* __restrict__ out,
                                              double* __restrict__ lossp,
                                              int use_eT) {
#pragma clang fp contract(off)
    int t = threadIdx.x;
    double lsum = 0.0;
    for (int it = 0; it < 4; ++it) {
        int e = (blockIdx.x * 4 + it) * 256 + t;
        int c  = (e >> 10) & 255;
        int bb = e >> 18;
        int hw = e & 1023;
        int n  = (bb << 10) + hw;
        int iv = idx[n];
        float zv = z[e];
        float zq = use_eT ? ecb[(size_t)c * NE + iv] : ecb[(size_t)iv * ED + c];
        float d  = zq - zv;
        out[OFF_ZQ + (size_t)e] = zv + d;
        lsum += (double)(d * d);
    }
    for (int off = 32; off; off >>= 1) lsum += __shfl_down(lsum, off);
    __shared__ double wsum[4];
    if ((t & 63) == 0) wsum[t >> 6] = lsum;
    __syncthreads();
    if (t == 0) lossp[blockIdx.x] = (wsum[0] + wsum[1]) + (wsum[2] + wsum[3]);
}

// ======================================================================
// k_out2: one-hot encodings (float4 stores) + indices
// ======================================================================
__global__ __launch_bounds__(256) void k_out2(const int* __restrict__ idx,
                                              float* __restrict__ out) {
    int t = threadIdx.x;
    for (int it = 0; it < 16; ++it) {
        int q = (blockIdx.x * 16 + it) * 256 + t;  // grid 2048 -> 8388608 float4
        int row  = q >> 8;
        int col4 = (q & 255) * 4;
        int iv = idx[row];
        float4 v;
        v.x = (col4     == iv) ? 1.f : 0.f;
        v.y = (col4 + 1 == iv) ? 1.f : 0.f;
        v.z = (col4 + 2 == iv) ? 1.f : 0.f;
        v.w = (col4 + 3 == iv) ? 1.f : 0.f;
        *(float4*)(out + OFF_ENC + (size_t)q * 4) = v;
        if ((q & 255) == 0) out[OFF_IDX + row] = (float)iv;
    }
}

// ======================================================================
// k_final: perplexity + loss scalar, deterministic
// ======================================================================
__global__ __launch_bounds__(256) void k_final(const int* __restrict__ idx,
                                               const double* __restrict__ lossp,
                                               float* __restrict__ out) {
    __shared__ int cnt[NE];
    __shared__ double sh[4];
    int t = threadIdx.x;
    for (int k = t; k < NE; k += 256) cnt[k] = 0;
    __syncthreads();
    for (int n = t; n < NPTS; n += 256) atomicAdd(&cnt[idx[n]], 1);
    __syncthreads();
    double psum = 0.0;
    for (int k = t; k < NE; k += 256) {
        float em = (float)cnt[k] / 32768.0f;
        float term = em * logf(em + 1e-10f);
        psum += (double)term;
    }
    for (int off = 32; off; off >>= 1) psum += __shfl_down(psum, off);
    if ((t & 63) == 0) sh[t >> 6] = psum;
    __syncthreads();
    if (t == 0) {
        double tot = (sh[0] + sh[1]) + (sh[2] + sh[3]);
        out[OFF_PPL] = expf(-(float)tot);
    }
    __syncthreads();
    double ls = 0.0;
    for (int i = t; i < NLOSSP; i += 256) ls += lossp[i];
    for (int off = 32; off; off >>= 1) ls += __shfl_down(ls, off);
    __syncthreads();
    if ((t & 63) == 0) sh[t >> 6] = ls;
    __syncthreads();
    if (t == 0) {
        double m = ((sh[0] + sh[1]) + (sh[2] + sh[3])) / 8388608.0;
        float mf = (float)m;
        out[OFF_LOSS] = mf + 0.25f * mf;
    }
}

// ======================================================================
extern "C" void kernel_launch(void* const* d_in, const int* in_sizes, int n_in,
                              void* d_out, int out_size, void* d_ws, size_t ws_size,
                              hipStream_t stream) {
    const float* z  = (const float*)d_in[0];
    const float* cb = (const float*)d_in[1];
    float* out = (float*)d_out;
    char* ws = (char*)d_ws;

    int*    idx   = (int*)(ws + WS_IDX);
    float*  zz    = (float*)(ws + WS_ZZ);
    float*  ee    = (float*)(ws + WS_EE);
    double* lossp = (double*)(ws + WS_LOSSP);

    if (ws_size >= WS_NEED) {
        u16* eh = (u16*)(ws + WS_EH);
        u16* el = (u16*)(ws + WS_EL);
        u16* zh = (u16*)(ws + WS_ZH);
        u16* zl = (u16*)(ws + WS_ZL);
        u8*  ccnt  = (u8*)(ws + WS_CCNT);
        int* candk = (int*)(ws + WS_CANDK);
        float* cands = (float*)(ws + WS_CANDS);
        int* ocnt  = (int*)(ws + WS_OCNT);
        int* olist = (int*)(ws + WS_OLIST);

        k_prep   <<<4,    256, 0, stream>>>(cb, ee, eh, el, ocnt);
        k_zz     <<<128,  256, 0, stream>>>(z, zz);
        k_zsplit <<<2048, 256, 0, stream>>>(z, zh, zl);
        k_filter <<<1024, 256, 0, stream>>>(zh, zl, eh, el, ee, ccnt, candk, cands, ocnt, olist);
        k_rescore<<<256,  128, 0, stream>>>(z, cb, ee, zz, ccnt, candk, cands, idx);
        k_exact  <<<512,  256, 0, stream>>>(z, cb, ee, zz, ocnt, olist, idx);
        k_out1   <<<8192, 256, 0, stream>>>(z, cb, idx, out, lossp, 0);
    } else {
        float* eT = (float*)(ws + WS_ET_FB);
        k_prep_old<<<4,   256, 0, stream>>>(cb, ee, eT);
        k_zz      <<<128, 256, 0, stream>>>(z, zz);
        k_main    <<<512, 256, 0, stream>>>(z, eT, ee, zz, idx);
        k_out1    <<<8192,256, 0, stream>>>(z, eT, idx, out, lossp, 1);
    }
    k_out2 <<<2048, 256, 0, stream>>>(idx, out);
    k_final<<<1,    256, 0, stream>>>(idx, lossp, out);
}

// Round 7
// 338.559 us; speedup vs baseline: 7.9578x; 1.1426x over previous
//
#include <hip/hip_runtime.h>
#include <hip/hip_bf16.h>
#include <cstdint>
#include <cstddef>

typedef unsigned short u16;
typedef unsigned char u8;
typedef __attribute__((ext_vector_type(8))) short bf16x8;
typedef __attribute__((ext_vector_type(4))) float f32x4;

// ---- problem sizes ----
#define NPTS 32768      // B*H*W = 32*32*32
#define NE   1024       // codes
#define ED   256        // embedding dim (= C)
#define ZPLANE 262144   // 256*1024 floats per batch image (C*H*W)

// ---- output layout (floats) ----
#define OFF_LOSS 0
#define OFF_ZQ   1
#define OFF_PPL  8388609
#define OFF_ENC  8388610
#define OFF_IDX  41943042

// ---- ws layout (bytes) ----
#define WS_IDX   0              // int[32768]
#define WS_ZZ    131072         // float[32768]
#define WS_EE    262144         // float[1024]
#define WS_LOSSP 266240         // double[8192]
#define NLOSSP   8192
#define WS_ET_FB 331776         // float[256*1024] (FALLBACK ONLY, overlays EH/EL)
#define WS_EH    331776         // u16[1024*256]
#define WS_EL    856064
#define WS_ZH    1380352        // u16[32768*256]
#define WS_ZL    18157568
#define WS_CCNT  34934784       // u8[4*32768] packed counts
#define WS_CANDK 35065856       // int[12*32768]
#define WS_CANDS 36638720       // float[12*32768]
#define WS_OCNT  38211584       // int: overflow count
#define WS_OLIST 38211588       // int[4096]: overflow point list
#define WS_NEED  38227972ULL

#define MARGIN 3.0e-4f          // k_filter emission margin (capture bound)
#define AMB    2.0e-4f          // certification ambiguity window (>2E, <=MARGIN)
#define OCAP   4096

// ======================================================================
// k_prep: ||e||^2 (numpy pairwise order) + ocnt=0  (split moved out)
// ======================================================================
__global__ __launch_bounds__(256) void k_prep(const float* __restrict__ cb,
                                              float* __restrict__ ee,
                                              int* __restrict__ ocnt) {
#pragma clang fp contract(off)
    if (blockIdx.x == 0 && threadIdx.x == 0) *ocnt = 0;
    int k = blockIdx.x * 256 + threadIdx.x;
    if (k >= NE) return;
    const float* row = cb + (size_t)k * ED;
    float s[2];
    for (int h = 0; h < 2; ++h) {
        const float* a = row + h * 128;
        float r[8];
        for (int j = 0; j < 8; ++j) { float v = a[j]; r[j] = v * v; }
        for (int i = 8; i < 128; i += 8)
            for (int j = 0; j < 8; ++j) { float v = a[i + j]; r[j] += v * v; }
        s[h] = ((r[0] + r[1]) + (r[2] + r[3])) + ((r[4] + r[5]) + (r[6] + r[7]));
    }
    ee[k] = s[0] + s[1];
}

// k_esplit: coalesced bf16 hi/lo split of codebook (one block per code)
__global__ __launch_bounds__(256) void k_esplit(const float* __restrict__ cb,
                                                u16* __restrict__ eh,
                                                u16* __restrict__ el) {
    int k = blockIdx.x;
    int c = threadIdx.x;
    float f = cb[(size_t)k * ED + c];
    __hip_bfloat16 h = __float2bfloat16(f);
    float hf = __bfloat162float(h);
    __hip_bfloat16 l = __float2bfloat16(f - hf);
    eh[(size_t)k * ED + c] = *(u16*)&h;
    el[(size_t)k * ED + c] = *(u16*)&l;
}

// k_prep_old: fallback (also writes eT)
__global__ __launch_bounds__(256) void k_prep_old(const float* __restrict__ cb,
                                                  float* __restrict__ ee,
                                                  float* __restrict__ eT) {
#pragma clang fp contract(off)
    int k = blockIdx.x * 256 + threadIdx.x;
    if (k >= NE) return;
    const float* row = cb + (size_t)k * ED;
    float s[2];
    for (int h = 0; h < 2; ++h) {
        const float* a = row + h * 128;
        float r[8];
        for (int j = 0; j < 8; ++j) { float v = a[j]; r[j] = v * v; }
        for (int i = 8; i < 128; i += 8)
            for (int j = 0; j < 8; ++j) { float v = a[i + j]; r[j] += v * v; }
        s[h] = ((r[0] + r[1]) + (r[2] + r[3])) + ((r[4] + r[5]) + (r[6] + r[7]));
    }
    ee[k] = s[0] + s[1];
    for (int c = 0; c < ED; ++c) eT[(size_t)c * NE + k] = row[c];
}

// ======================================================================
// k_zz: per-point ||z||^2, numpy pairwise order (proven exact)
// ======================================================================
__global__ __launch_bounds__(256) void k_zz(const float* __restrict__ z,
                                            float* __restrict__ zz) {
#pragma clang fp contract(off)
    int n = blockIdx.x * 256 + threadIdx.x;      // 128 blocks
    int b = n >> 10, hw = n & 1023;
    const float* a0 = z + (size_t)b * ZPLANE + hw;
    float s[2];
    for (int h = 0; h < 2; ++h) {
        const float* a = a0 + (size_t)h * 128 * 1024;
        float r[8];
        for (int j = 0; j < 8; ++j) { float v = a[(size_t)j * 1024]; r[j] = v * v; }
        for (int i = 8; i < 128; i += 8)
            for (int j = 0; j < 8; ++j) { float v = a[(size_t)(i + j) * 1024]; r[j] += v * v; }
        s[h] = ((r[0] + r[1]) + (r[2] + r[3])) + ((r[4] + r[5]) + (r[6] + r[7]));
    }
    zz[n] = s[0] + s[1];
}

// ======================================================================
// k_zsplit: transpose z (b,c,hw)->point-major + bf16 hi/lo split
// ======================================================================
__global__ __launch_bounds__(256) void k_zsplit(const float* __restrict__ z,
                                                u16* __restrict__ zh,
                                                u16* __restrict__ zl) {
    __shared__ float tile[64][65];
    int t = threadIdx.x;
    int blk = blockIdx.x;              // 2048 = 32b * 4c * 16hw
    int b   = blk >> 6;
    int c0  = ((blk >> 4) & 3) * 64;
    int hw0 = (blk & 15) * 64;
    int lane = t & 63, q = t >> 6;
    for (int i = 0; i < 16; ++i) {
        int cl = i * 4 + q;
        tile[cl][lane] = z[(size_t)b * ZPLANE + (size_t)(c0 + cl) * 1024 + hw0 + lane];
    }
    __syncthreads();
    int p = t >> 2, cq = t & 3;
    size_t n = (size_t)b * 1024 + hw0 + p;
    u16 hbuf[16], lbuf[16];
#pragma unroll
    for (int k = 0; k < 16; ++k) {
        float f = tile[cq * 16 + k][p];
        __hip_bfloat16 h = __float2bfloat16(f);
        float hf = __bfloat162float(h);
        __hip_bfloat16 l = __float2bfloat16(f - hf);
        hbuf[k] = *(u16*)&h; lbuf[k] = *(u16*)&l;
    }
    u16* dh = zh + n * 256 + c0 + cq * 16;
    u16* dl = zl + n * 256 + c0 + cq * 16;
    *(bf16x8*)(dh)     = *(bf16x8*)&hbuf[0];
    *(bf16x8*)(dh + 8) = *(bf16x8*)&hbuf[8];
    *(bf16x8*)(dl)     = *(bf16x8*)&lbuf[0];
    *(bf16x8*)(dl + 8) = *(bf16x8*)&lbuf[8];
}

// ======================================================================
// k_filter v2: bf16x3 MFMA approx scores, A-fragments read from global
// EXACTLY ONCE per block (both nc-chunk accumulators held live; B for
// both chunks staged per kb slice). Scores bit-identical to v1.
// ======================================================================
__global__ __launch_bounds__(256, 2) void k_filter(const u16* __restrict__ zh,
                                                   const u16* __restrict__ zl,
                                                   const u16* __restrict__ eh,
                                                   const u16* __restrict__ el,
                                                   const float* __restrict__ ee,
                                                   u8* __restrict__ candcnt,
                                                   int* __restrict__ candk,
                                                   float* __restrict__ cands,
                                                   int* __restrict__ ocnt,
                                                   int* __restrict__ olist) {
    __shared__ u16  Bh0[128 * 64];    // 16 KB each, XOR-swizzled
    __shared__ u16  Bl0[128 * 64];
    __shared__ u16  Bh1[128 * 64];
    __shared__ u16  Bl1[128 * 64];
    __shared__ float eeL[256];
    __shared__ int  cntL[128];
    __shared__ int  ckL[128][3];
    __shared__ float csL[128][3];

    int t = threadIdx.x;
    int lane = t & 63, w = t >> 6;
    int g = blockIdx.x & 255;
    int q = blockIdx.x >> 8;
    int n0 = g * 128;
    int kqbase = q * 256;
    int prow = w * 32 + (lane & 15);
    const u16* zh0 = zh + (size_t)(n0 + prow) * 256;
    const u16* zl0 = zl + (size_t)(n0 + prow) * 256;
    const u16* zh1 = zh0 + 16 * 256;
    const u16* zl1 = zl0 + 16 * 256;
    int koff_lane = (lane >> 4) * 8;

    if (t < 128) cntL[t] = 0;
    eeL[t] = ee[kqbase + t];

    // acc[nc][group][nf]
    f32x4 acc[2][2][8];
#pragma unroll
    for (int nc = 0; nc < 2; ++nc)
#pragma unroll
        for (int gg = 0; gg < 2; ++gg)
#pragma unroll
            for (int nf = 0; nf < 8; ++nf)
                acc[nc][gg][nf] = (f32x4){0.f, 0.f, 0.f, 0.f};

    for (int kb = 0; kb < 4; ++kb) {
        __syncthreads();
        // stage B for both nc chunks at this kb slice
#pragma unroll
        for (int nc = 0; nc < 2; ++nc) {
            int kcbase = kqbase + nc * 128;
            u16* BhX = nc ? Bh1 : Bh0;
            u16* BlX = nc ? Bl1 : Bl0;
#pragma unroll
            for (int i = 0; i < 8; ++i) {
                int f = i * 256 + t;
                int a = f >> 10, r = (f >> 3) & 127, seg = f & 7;
                const u16* src = (a ? el : eh) + (size_t)(kcbase + r) * 256 + kb * 64 + seg * 8;
                bf16x8 v = *(const bf16x8*)src;
                int bo = (r * 128 + seg * 16) ^ ((r & 7) << 4);
                *(bf16x8*)((char*)(a ? BlX : BhX) + bo) = v;
            }
        }
        __syncthreads();
#pragma unroll
        for (int ks2 = 0; ks2 < 2; ++ks2) {
            int ko = kb * 64 + ks2 * 32 + koff_lane;
            bf16x8 ah0 = *(const bf16x8*)(zh0 + ko);
            bf16x8 al0 = *(const bf16x8*)(zl0 + ko);
            bf16x8 ah1 = *(const bf16x8*)(zh1 + ko);
            bf16x8 al1 = *(const bf16x8*)(zl1 + ko);
#pragma unroll
            for (int nf = 0; nf < 8; ++nf) {
                int r = nf * 16 + (lane & 15);
                int bo = (r * 128 + ks2 * 64 + (lane >> 4) * 16) ^ ((r & 7) << 4);
                bf16x8 bh0v = *(const bf16x8*)((const char*)Bh0 + bo);
                bf16x8 bl0v = *(const bf16x8*)((const char*)Bl0 + bo);
                bf16x8 bh1v = *(const bf16x8*)((const char*)Bh1 + bo);
                bf16x8 bl1v = *(const bf16x8*)((const char*)Bl1 + bo);
                acc[0][0][nf] = __builtin_amdgcn_mfma_f32_16x16x32_bf16(ah0, bh0v, acc[0][0][nf], 0, 0, 0);
                acc[0][0][nf] = __builtin_amdgcn_mfma_f32_16x16x32_bf16(al0, bh0v, acc[0][0][nf], 0, 0, 0);
                acc[0][0][nf] = __builtin_amdgcn_mfma_f32_16x16x32_bf16(ah0, bl0v, acc[0][0][nf], 0, 0, 0);
                acc[0][1][nf] = __builtin_amdgcn_mfma_f32_16x16x32_bf16(ah1, bh0v, acc[0][1][nf], 0, 0, 0);
                acc[0][1][nf] = __builtin_amdgcn_mfma_f32_16x16x32_bf16(al1, bh0v, acc[0][1][nf], 0, 0, 0);
                acc[0][1][nf] = __builtin_amdgcn_mfma_f32_16x16x32_bf16(ah1, bl0v, acc[0][1][nf], 0, 0, 0);
                acc[1][0][nf] = __builtin_amdgcn_mfma_f32_16x16x32_bf16(ah0, bh1v, acc[1][0][nf], 0, 0, 0);
                acc[1][0][nf] = __builtin_amdgcn_mfma_f32_16x16x32_bf16(al0, bh1v, acc[1][0][nf], 0, 0, 0);
                acc[1][0][nf] = __builtin_amdgcn_mfma_f32_16x16x32_bf16(ah0, bl1v, acc[1][0][nf], 0, 0, 0);
                acc[1][1][nf] = __builtin_amdgcn_mfma_f32_16x16x32_bf16(ah1, bh1v, acc[1][1][nf], 0, 0, 0);
                acc[1][1][nf] = __builtin_amdgcn_mfma_f32_16x16x32_bf16(al1, bh1v, acc[1][1][nf], 0, 0, 0);
                acc[1][1][nf] = __builtin_amdgcn_mfma_f32_16x16x32_bf16(ah1, bl1v, acc[1][1][nf], 0, 0, 0);
            }
        }
    }
    __syncthreads();

    float runmin[2][4];
#pragma unroll
    for (int gg = 0; gg < 2; ++gg)
#pragma unroll
        for (int j = 0; j < 4; ++j) runmin[gg][j] = 3.4e38f;

    // epilogue: same emission order as v1 (nc outer, gg inner)
#pragma unroll
    for (int nc = 0; nc < 2; ++nc) {
        int kcbase = kqbase + nc * 128;
#pragma unroll
        for (int gg = 0; gg < 2; ++gg) {
#pragma unroll
            for (int nf = 0; nf < 8; ++nf) {
                float eev = eeL[nc * 128 + nf * 16 + (lane & 15)];
                f32x4 d = acc[nc][gg][nf];
                f32x4 s;
#pragma unroll
                for (int j = 0; j < 4; ++j) s[j] = fmaf(-2.f, d[j], eev);
                acc[nc][gg][nf] = s;
            }
#pragma unroll
            for (int j = 0; j < 4; ++j) {
                float m = 3.4e38f;
#pragma unroll
                for (int nf = 0; nf < 8; ++nf) m = fminf(m, acc[nc][gg][nf][j]);
                m = fminf(m, __shfl_xor(m, 1, 64));
                m = fminf(m, __shfl_xor(m, 2, 64));
                m = fminf(m, __shfl_xor(m, 4, 64));
                m = fminf(m, __shfl_xor(m, 8, 64));
                runmin[gg][j] = fminf(runmin[gg][j], m);
                float th = runmin[gg][j] + MARGIN;
                int ml = w * 32 + gg * 16 + (lane >> 4) * 4 + j;
#pragma unroll
                for (int nf = 0; nf < 8; ++nf) {
                    float sv = acc[nc][gg][nf][j];
                    if (sv <= th) {
                        int pos = atomicAdd(&cntL[ml], 1);
                        if (pos < 3) { ckL[ml][pos] = kcbase + nf * 16 + (lane & 15);
                                       csL[ml][pos] = sv; }
                    }
                }
            }
        }
    }
    __syncthreads();
    if (t < 128) {
        int n = n0 + t;
        int cnt = cntL[t];
        candcnt[(size_t)n * 4 + q] = (u8)(cnt > 255 ? 255 : cnt);
        int* dk = candk + (size_t)n * 12 + q * 3;
        float* ds = cands + (size_t)n * 12 + q * 3;
#pragma unroll
        for (int i = 0; i < 3; ++i) {
            dk[i] = (i < cnt) ? ckL[t][i] : 0;
            ds[i] = (i < cnt) ? csL[t][i] : 3.4e38f;
        }
        if (cnt > 3) {
            int pos = atomicAdd(ocnt, 1);
            if (pos < OCAP) olist[pos] = n;
        }
    }
}

// ======================================================================
// k_rescore: certification + survivors-only exact dots (all static-
// indexed, register-resident). Overflow points handled by k_exact.
// ======================================================================
__global__ __launch_bounds__(128) void k_rescore(const float* __restrict__ z,
                                                 const float* __restrict__ cb,
                                                 const float* __restrict__ ee,
                                                 const float* __restrict__ zz,
                                                 const u8* __restrict__ candcnt,
                                                 const int* __restrict__ candk,
                                                 const float* __restrict__ cands,
                                                 int* __restrict__ idx_out) {
    int t = threadIdx.x;
    int n = blockIdx.x * 128 + t;                 // 256 blocks
    int packed = ((const int*)candcnt)[n];
    int c0 = packed & 255, c1 = (packed >> 8) & 255,
        c2 = (packed >> 16) & 255, c3 = (packed >> 24) & 255;
    if ((c0 > 3) | (c1 > 3) | (c2 > 3) | (c3 > 3)) return;  // k_exact owns it

    int ks[12]; float ss[12];
    const int*   ck = candk + (size_t)n * 12;
    const float* cs = cands + (size_t)n * 12;
#pragma unroll
    for (int p = 0; p < 3; ++p) {
        *(int4*)&ks[p * 4]   = *(const int4*)(ck + p * 4);
        *(float4*)&ss[p * 4] = *(const float4*)(cs + p * 4);
    }
    float gmin = 3.4e38f;
#pragma unroll
    for (int j = 0; j < 12; ++j) gmin = fminf(gmin, ss[j]);
    float th = gmin + AMB;

    int nsurv = 0;
#pragma unroll
    for (int j = 0; j < 12; ++j) nsurv += (ss[j] <= th) ? 1 : 0;

    if (nsurv == 1) {
        // certified: unique survivor is provably the numpy argmin
        int k = 0;
#pragma unroll
        for (int j = 0; j < 12; ++j) if (ss[j] <= th) k = ks[j];
        idx_out[n] = k;
        return;
    }

    // ambiguous (~2-3% of points): exact fp32 d for survivors only
    int b = n >> 10, hw = n & 1023;
    const float* zp = z + (size_t)b * ZPLANE + hw;
    float zzv = zz[n];
    float bd = 3.4e38f; int bk = 1 << 30;
#pragma unroll
    for (int j = 0; j < 12; ++j) {
        if (ss[j] <= th) {
            int k = ks[j];
            const float* e0 = cb + (size_t)k * ED;
            float a0 = 0.f;
            for (int c = 0; c < ED; c += 4) {
                float4 ev = *(const float4*)(e0 + c);
                a0 = fmaf(zp[(size_t)c * 1024],       ev.x, a0);
                a0 = fmaf(zp[(size_t)(c + 1) * 1024], ev.y, a0);
                a0 = fmaf(zp[(size_t)(c + 2) * 1024], ev.z, a0);
                a0 = fmaf(zp[(size_t)(c + 3) * 1024], ev.w, a0);
            }
            float d0 = (zzv + ee[k]) - 2.f * a0;
            if (d0 < bd || (d0 == bd && k < bk)) { bd = d0; bk = k; }
        }
    }
    idx_out[n] = bk;
}

// ======================================================================
// k_exact: full 1024-code exact scan for overflow points. One point per
// block (grid-stride); 4 codes/thread as 4 INDEPENDENT fmaf chains
// (same per-code sequential arithmetic, 4-way ILP, pipelined loads).
// ======================================================================
__global__ __launch_bounds__(256) void k_exact(const float* __restrict__ z,
                                               const float* __restrict__ cb,
                                               const float* __restrict__ ee,
                                               const float* __restrict__ zz,
                                               const int* __restrict__ ocnt,
                                               const int* __restrict__ olist,
                                               int* __restrict__ idx_out) {
    __shared__ float zL[ED];
    __shared__ float rv[4];
    __shared__ int   ri[4];
    int cnt = *ocnt; if (cnt > OCAP) cnt = OCAP;
    int t = threadIdx.x;
    for (int i = blockIdx.x; i < cnt; i += gridDim.x) {
        int n = olist[i];
        int b = n >> 10, hw = n & 1023;
        const float* zp = z + (size_t)b * ZPLANE + hw;
        __syncthreads();
        zL[t] = zp[(size_t)t * 1024];
        __syncthreads();
        float zzv = zz[n];
        int k0 = t, k1 = 256 + t, k2 = 512 + t, k3 = 768 + t;
        const float* e0 = cb + (size_t)k0 * ED;
        const float* e1 = cb + (size_t)k1 * ED;
        const float* e2 = cb + (size_t)k2 * ED;
        const float* e3 = cb + (size_t)k3 * ED;
        float a0 = 0.f, a1 = 0.f, a2 = 0.f, a3 = 0.f;
#pragma unroll 8
        for (int c = 0; c < ED; c += 4) {
            float4 z4 = *(const float4*)&zL[c];
            float4 v0 = *(const float4*)(e0 + c);
            float4 v1 = *(const float4*)(e1 + c);
            float4 v2 = *(const float4*)(e2 + c);
            float4 v3 = *(const float4*)(e3 + c);
            a0 = fmaf(z4.x, v0.x, a0); a0 = fmaf(z4.y, v0.y, a0);
            a0 = fmaf(z4.z, v0.z, a0); a0 = fmaf(z4.w, v0.w, a0);
            a1 = fmaf(z4.x, v1.x, a1); a1 = fmaf(z4.y, v1.y, a1);
            a1 = fmaf(z4.z, v1.z, a1); a1 = fmaf(z4.w, v1.w, a1);
            a2 = fmaf(z4.x, v2.x, a2); a2 = fmaf(z4.y, v2.y, a2);
            a2 = fmaf(z4.z, v2.z, a2); a2 = fmaf(z4.w, v2.w, a2);
            a3 = fmaf(z4.x, v3.x, a3); a3 = fmaf(z4.y, v3.y, a3);
            a3 = fmaf(z4.z, v3.z, a3); a3 = fmaf(z4.w, v3.w, a3);
        }
        float d0 = (zzv + ee[k0]) - 2.f * a0;
        float d1 = (zzv + ee[k1]) - 2.f * a1;
        float d2 = (zzv + ee[k2]) - 2.f * a2;
        float d3 = (zzv + ee[k3]) - 2.f * a3;
        // ascending k order, strict < keeps lowest index
        float bd = d0; int bk = k0;
        if (d1 < bd) { bd = d1; bk = k1; }
        if (d2 < bd) { bd = d2; bk = k2; }
        if (d3 < bd) { bd = d3; bk = k3; }
        for (int off = 32; off; off >>= 1) {
            float ov = __shfl_down(bd, off);
            int   oi = __shfl_down(bk, off);
            if (ov < bd || (ov == bd && oi < bk)) { bd = ov; bk = oi; }
        }
        if ((t & 63) == 0) { rv[t >> 6] = bd; ri[t >> 6] = bk; }
        __syncthreads();
        if (t == 0) {
            for (int wv = 1; wv < 4; ++wv)
                if (rv[wv] < bd || (rv[wv] == bd && ri[wv] < bk)) { bd = rv[wv]; bk = ri[wv]; }
            idx_out[n] = bk;
        }
    }
}

// ======================================================================
// k_main (fallback path only): exact fp32 distances + argmin, proven.
// ======================================================================
#define TM 64
#define TK 128
#define CCH 64
__global__ __launch_bounds__(256) void k_main(const float* __restrict__ z,
                                              const float* __restrict__ eT,
                                              const float* __restrict__ ee,
                                              const float* __restrict__ zz,
                                              int* __restrict__ idx_out) {
    __shared__ float zt[CCH][TM];
    __shared__ float et[CCH][TK];
    __shared__ float redv[TM][16];
    __shared__ int   redi[TM][16];
    __shared__ float bestv[TM];
    __shared__ int   besti[TM];
    __shared__ float zzl[TM];
    int t = threadIdx.x;
    int n0 = blockIdx.x * TM;
    int b = n0 >> 10, hw0 = n0 & 1023;
    const float* zb = z + (size_t)b * ZPLANE + hw0;
    int trow = t >> 4, tcol = t & 15;
    if (t < TM) { bestv[t] = 3.4e38f; besti[t] = 0; zzl[t] = zz[n0 + t]; }
    for (int kt = 0; kt < NE / TK; ++kt) {
        int k0 = kt * TK;
        float acc[4][8];
        for (int i = 0; i < 4; ++i)
            for (int j = 0; j < 8; ++j) acc[i][j] = 0.f;
        for (int cc = 0; cc < ED / CCH; ++cc) {
            __syncthreads();
            {
                int m4 = (t & 15) * 4; int cb0 = t >> 4;
                for (int p = 0; p < 4; ++p) {
                    int cl = p * 16 + cb0;
                    float4 v = *(const float4*)(zb + (size_t)(cc * CCH + cl) * 1024 + m4);
                    *(float4*)&zt[cl][m4] = v;
                }
            }
            {
                int k4 = (t & 31) * 4; int cb0 = t >> 5;
                for (int p = 0; p < 8; ++p) {
                    int cl = p * 8 + cb0;
                    float4 v = *(const float4*)(eT + (size_t)(cc * CCH + cl) * 1024 + k0 + k4);
                    *(float4*)&et[cl][k4] = v;
                }
            }
            __syncthreads();
            for (int c = 0; c < CCH; ++c) {
                float4 zm = *(const float4*)&zt[c][trow * 4];
                float4 e0 = *(const float4*)&et[c][tcol * 8];
                float4 e1 = *(const float4*)&et[c][tcol * 8 + 4];
                float zv[4] = {zm.x, zm.y, zm.z, zm.w};
                float ev[8] = {e0.x, e0.y, e0.z, e0.w, e1.x, e1.y, e1.z, e1.w};
                for (int i = 0; i < 4; ++i)
                    for (int j = 0; j < 8; ++j)
                        acc[i][j] = fmaf(zv[i], ev[j], acc[i][j]);
            }
        }
        for (int i = 0; i < 4; ++i) {
            int m = trow * 4 + i;
            float zv = zzl[m];
            float bv = 3.4e38f; int bi = 0;
            for (int j = 0; j < 8; ++j) {
                int k = k0 + tcol * 8 + j;
                float t1 = zv + ee[k];
                float d  = t1 - 2.0f * acc[i][j];
                if (d < bv) { bv = d; bi = k; }
            }
            redv[m][tcol] = bv; redi[m][tcol] = bi;
        }
        __syncthreads();
        if (t < TM) {
            float bv = bestv[t]; int bi = besti[t];
            for (int tc = 0; tc < 16; ++tc) {
                float v = redv[t][tc]; int ix = redi[t][tc];
                if (v < bv || (v == bv && ix < bi)) { bv = v; bi = ix; }
            }
            bestv[t] = bv; besti[t] = bi;
        }
    }
    __syncthreads();
    if (t < TM) idx_out[n0 + t] = besti[t];
}

// ======================================================================
// k_out1: z_q straight-through (B,C,H,W) + loss partials.
// ======================================================================
__global__ __launch_bounds__(256) void k_out1(const float* __restrict__ z,
                                              const float* __restrict__ ecb,
                                              const int* __restrict__ idx,
                                              float* __restrict__ out,
                                              double* __restrict__ lossp,
                                              int use_eT) {
#pragma clang fp contract(off)
    int t = threadIdx.x;
    double lsum = 0.0;
    for (int it = 0; it < 4; ++it) {
        int e = (blockIdx.x * 4 + it) * 256 + t;
        int c  = (e >> 10) & 255;
        int bb = e >> 18;
        int hw = e & 1023;
        int n  = (bb << 10) + hw;
        int iv = idx[n];
        float zv = z[e];
        float zq = use_eT ? ecb[(size_t)c * NE + iv] : ecb[(size_t)iv * ED + c];
        float d  = zq - zv;
        out[OFF_ZQ + (size_t)e] = zv + d;
        lsum += (double)(d * d);
    }
    for (int off = 32; off; off >>= 1) lsum += __shfl_down(lsum, off);
    __shared__ double wsum[4];
    if ((t & 63) == 0) wsum[t >> 6] = lsum;
    __syncthreads();
    if (t == 0) lossp[blockIdx.x] = (wsum[0] + wsum[1]) + (wsum[2] + wsum[3]);
}

// ======================================================================
// k_out2: one-hot encodings (float4 stores) + indices
// ======================================================================
__global__ __launch_bounds__(256) void k_out2(const int* __restrict__ idx,
                                              float* __restrict__ out) {
    int t = threadIdx.x;
    for (int it = 0; it < 16; ++it) {
        int q = (blockIdx.x * 16 + it) * 256 + t;  // grid 2048 -> 8388608 float4
        int row  = q >> 8;
        int col4 = (q & 255) * 4;
        int iv = idx[row];
        float4 v;
        v.x = (col4     == iv) ? 1.f : 0.f;
        v.y = (col4 + 1 == iv) ? 1.f : 0.f;
        v.z = (col4 + 2 == iv) ? 1.f : 0.f;
        v.w = (col4 + 3 == iv) ? 1.f : 0.f;
        *(float4*)(out + OFF_ENC + (size_t)q * 4) = v;
        if ((q & 255) == 0) out[OFF_IDX + row] = (float)iv;
    }
}

// ======================================================================
// k_final: perplexity + loss scalar, deterministic
// ======================================================================
__global__ __launch_bounds__(256) void k_final(const int* __restrict__ idx,
                                               const double* __restrict__ lossp,
                                               float* __restrict__ out) {
    __shared__ int cnt[NE];
    __shared__ double sh[4];
    int t = threadIdx.x;
    for (int k = t; k < NE; k += 256) cnt[k] = 0;
    __syncthreads();
    for (int n = t; n < NPTS; n += 256) atomicAdd(&cnt[idx[n]], 1);
    __syncthreads();
    double psum = 0.0;
    for (int k = t; k < NE; k += 256) {
        float em = (float)cnt[k] / 32768.0f;
        float term = em * logf(em + 1e-10f);
        psum += (double)term;
    }
    for (int off = 32; off; off >>= 1) psum += __shfl_down(psum, off);
    if ((t & 63) == 0) sh[t >> 6] = psum;
    __syncthreads();
    if (t == 0) {
        double tot = (sh[0] + sh[1]) + (sh[2] + sh[3]);
        out[OFF_PPL] = expf(-(float)tot);
    }
    __syncthreads();
    double ls = 0.0;
    for (int i = t; i < NLOSSP; i += 256) ls += lossp[i];
    for (int off = 32; off; off >>= 1) ls += __shfl_down(ls, off);
    __syncthreads();
    if ((t & 63) == 0) sh[t >> 6] = ls;
    __syncthreads();
    if (t == 0) {
        double m = ((sh[0] + sh[1]) + (sh[2] + sh[3])) / 8388608.0;
        float mf = (float)m;
        out[OFF_LOSS] = mf + 0.25f * mf;
    }
}

// ======================================================================
extern "C" void kernel_launch(void* const* d_in, const int* in_sizes, int n_in,
                              void* d_out, int out_size, void* d_ws, size_t ws_size,
                              hipStream_t stream) {
    const float* z  = (const float*)d_in[0];
    const float* cb = (const float*)d_in[1];
    float* out = (float*)d_out;
    char* ws = (char*)d_ws;

    int*    idx   = (int*)(ws + WS_IDX);
    float*  zz    = (float*)(ws + WS_ZZ);
    float*  ee    = (float*)(ws + WS_EE);
    double* lossp = (double*)(ws + WS_LOSSP);

    if (ws_size >= WS_NEED) {
        u16* eh = (u16*)(ws + WS_EH);
        u16* el = (u16*)(ws + WS_EL);
        u16* zh = (u16*)(ws + WS_ZH);
        u16* zl = (u16*)(ws + WS_ZL);
        u8*  ccnt  = (u8*)(ws + WS_CCNT);
        int* candk = (int*)(ws + WS_CANDK);
        float* cands = (float*)(ws + WS_CANDS);
        int* ocnt  = (int*)(ws + WS_OCNT);
        int* olist = (int*)(ws + WS_OLIST);

        k_prep   <<<4,    256, 0, stream>>>(cb, ee, ocnt);
        k_esplit <<<1024, 256, 0, stream>>>(cb, eh, el);
        k_zz     <<<128,  256, 0, stream>>>(z, zz);
        k_zsplit <<<2048, 256, 0, stream>>>(z, zh, zl);
        k_filter <<<1024, 256, 0, stream>>>(zh, zl, eh, el, ee, ccnt, candk, cands, ocnt, olist);
        k_rescore<<<256,  128, 0, stream>>>(z, cb, ee, zz, ccnt, candk, cands, idx);
        k_exact  <<<512,  256, 0, stream>>>(z, cb, ee, zz, ocnt, olist, idx);
        k_out1   <<<8192, 256, 0, stream>>>(z, cb, idx, out, lossp, 0);
    } else {
        float* eT = (float*)(ws + WS_ET_FB);
        k_prep_old<<<4,   256, 0, stream>>>(cb, ee, eT);
        k_zz      <<<128, 256, 0, stream>>>(z, zz);
        k_main    <<<512, 256, 0, stream>>>(z, eT, ee, zz, idx);
        k_out1    <<<8192,256, 0, stream>>>(z, eT, idx, out, lossp, 1);
    }
    k_out2 <<<2048, 256, 0, stream>>>(idx, out);
    k_final<<<1,    256, 0, stream>>>(idx, lossp, out);
}

// Round 8
// 295.065 us; speedup vs baseline: 9.1308x; 1.1474x over previous
//
#include <hip/hip_runtime.h>
#include <hip/hip_bf16.h>
#include <cstdint>
#include <cstddef>

typedef unsigned short u16;
typedef unsigned char u8;
typedef __attribute__((ext_vector_type(8))) short bf16x8;
typedef __attribute__((ext_vector_type(4))) float f32x4;

// ---- problem sizes ----
#define NPTS 32768      // B*H*W = 32*32*32
#define NE   1024       // codes
#define ED   256        // embedding dim (= C)
#define ZPLANE 262144   // 256*1024 floats per batch image (C*H*W)

// ---- output layout (floats) ----
#define OFF_LOSS 0
#define OFF_ZQ   1
#define OFF_PPL  8388609
#define OFF_ENC  8388610
#define OFF_IDX  41943042

// ---- ws layout (bytes) ----
#define WS_IDX   0              // int[32768]
#define WS_ZZ    131072         // float[32768]
#define WS_EE    262144         // float[1024]
#define WS_LOSSP 266240         // double[1024]
#define NLOSSP   1024
#define WS_ET_FB 331776         // float[256*1024] (FALLBACK ONLY, overlays EH/EL)
#define WS_EH    331776         // u16[1024*256]
#define WS_EL    856064
#define WS_ZH    1380352        // u16[32768*256]
#define WS_ZL    18157568
#define WS_CCNT  34934784       // u8[4*32768] packed counts
#define WS_CANDK 35065856       // int[12*32768]
#define WS_CANDS 36638720       // float[12*32768]
#define WS_OCNT  38211584       // int: overflow count
#define WS_OLIST 38211588       // int[4096]: overflow point list
#define WS_NEED  38227972ULL

#define MARGIN 3.0e-4f          // k_filter emission margin (capture bound)
#define AMB    2.0e-4f          // certification ambiguity window (>2E, <=MARGIN)
#define OCAP   4096

// ======================================================================
// k_eprep: fused ||e||^2 (numpy pairwise order) + bf16 hi/lo split.
// One block per code; coalesced row read; t==0 does exact pairwise sum.
// ======================================================================
__global__ __launch_bounds__(256) void k_eprep(const float* __restrict__ cb,
                                               float* __restrict__ ee,
                                               u16* __restrict__ eh,
                                               u16* __restrict__ el,
                                               int* __restrict__ ocnt) {
#pragma clang fp contract(off)
    __shared__ float row[256];
    int k = blockIdx.x;
    int c = threadIdx.x;
    if (k == 0 && c == 0) *ocnt = 0;
    float f = cb[(size_t)k * ED + c];
    row[c] = f;
    __hip_bfloat16 h = __float2bfloat16(f);
    float hf = __bfloat162float(h);
    __hip_bfloat16 l = __float2bfloat16(f - hf);
    eh[(size_t)k * ED + c] = *(u16*)&h;
    el[(size_t)k * ED + c] = *(u16*)&l;
    __syncthreads();
    if (c == 0) {
        float s[2];
        for (int h2 = 0; h2 < 2; ++h2) {
            const float* a = &row[h2 * 128];
            float r[8];
            for (int j = 0; j < 8; ++j) { float v = a[j]; r[j] = v * v; }
            for (int i = 8; i < 128; i += 8)
                for (int j = 0; j < 8; ++j) { float v = a[i + j]; r[j] += v * v; }
            s[h2] = ((r[0] + r[1]) + (r[2] + r[3])) + ((r[4] + r[5]) + (r[6] + r[7]));
        }
        ee[k] = s[0] + s[1];
    }
}

// k_prep_old: fallback (ee + eT)
__global__ __launch_bounds__(256) void k_prep_old(const float* __restrict__ cb,
                                                  float* __restrict__ ee,
                                                  float* __restrict__ eT) {
#pragma clang fp contract(off)
    int k = blockIdx.x * 256 + threadIdx.x;
    if (k >= NE) return;
    const float* row = cb + (size_t)k * ED;
    float s[2];
    for (int h = 0; h < 2; ++h) {
        const float* a = row + h * 128;
        float r[8];
        for (int j = 0; j < 8; ++j) { float v = a[j]; r[j] = v * v; }
        for (int i = 8; i < 128; i += 8)
            for (int j = 0; j < 8; ++j) { float v = a[i + j]; r[j] += v * v; }
        s[h] = ((r[0] + r[1]) + (r[2] + r[3])) + ((r[4] + r[5]) + (r[6] + r[7]));
    }
    ee[k] = s[0] + s[1];
    for (int c = 0; c < ED; ++c) eT[(size_t)c * NE + k] = row[c];
}

// ======================================================================
// k_zz: fallback-only per-point ||z||^2 (proven exact)
// ======================================================================
__global__ __launch_bounds__(256) void k_zz(const float* __restrict__ z,
                                            float* __restrict__ zz) {
#pragma clang fp contract(off)
    int n = blockIdx.x * 256 + threadIdx.x;      // 128 blocks
    int b = n >> 10, hw = n & 1023;
    const float* a0 = z + (size_t)b * ZPLANE + hw;
    float s[2];
    for (int h = 0; h < 2; ++h) {
        const float* a = a0 + (size_t)h * 128 * 1024;
        float r[8];
        for (int j = 0; j < 8; ++j) { float v = a[(size_t)j * 1024]; r[j] = v * v; }
        for (int i = 8; i < 128; i += 8)
            for (int j = 0; j < 8; ++j) { float v = a[(size_t)(i + j) * 1024]; r[j] += v * v; }
        s[h] = ((r[0] + r[1]) + (r[2] + r[3])) + ((r[4] + r[5]) + (r[6] + r[7]));
    }
    zz[n] = s[0] + s[1];
}

// ======================================================================
// k_zprep: fused transpose+split+zz. One z pass. 1024 blocks, each
// 256c x 32hw tile in LDS; zz computed with exact numpy pairwise order.
// ======================================================================
__global__ __launch_bounds__(256) void k_zprep(const float* __restrict__ z,
                                               float* __restrict__ zz,
                                               u16* __restrict__ zh,
                                               u16* __restrict__ zl) {
#pragma clang fp contract(off)
    __shared__ float tile[256 * 33];   // 33.8 KB
    int t = threadIdx.x;
    int blk = blockIdx.x;              // 1024 = 32b * 32hwgrp
    int b   = blk >> 5;
    int hw0 = (blk & 31) * 32;
    int lane = t & 31, cg = t >> 5;
    const float* zb = z + (size_t)b * ZPLANE + hw0;
    for (int i = 0; i < 32; ++i) {
        int c = i * 8 + cg;
        tile[c * 33 + lane] = zb[(size_t)c * 1024 + lane];
    }
    __syncthreads();
    // zz for 32 points, exact numpy pairwise order
    if (t < 32) {
        int p = t;
        float s[2];
        for (int h = 0; h < 2; ++h) {
            float r[8];
            for (int j = 0; j < 8; ++j) { float v = tile[(h * 128 + j) * 33 + p]; r[j] = v * v; }
            for (int i = 8; i < 128; i += 8)
                for (int j = 0; j < 8; ++j) { float v = tile[(h * 128 + i + j) * 33 + p]; r[j] += v * v; }
            s[h] = ((r[0] + r[1]) + (r[2] + r[3])) + ((r[4] + r[5]) + (r[6] + r[7]));
        }
        zz[(b << 10) + hw0 + p] = s[0] + s[1];
    }
    // bf16 hi/lo split: p=t>>3 point, cq=t&7 -> c in [cq*32, cq*32+32)
    int p = t >> 3, cq = t & 7;
    size_t n = (size_t)(b << 10) + hw0 + p;
    u16* dh = zh + n * 256 + cq * 32;
    u16* dl = zl + n * 256 + cq * 32;
#pragma unroll
    for (int g8 = 0; g8 < 4; ++g8) {
        u16 hbuf[8], lbuf[8];
#pragma unroll
        for (int kk = 0; kk < 8; ++kk) {
            float f = tile[(cq * 32 + g8 * 8 + kk) * 33 + p];
            __hip_bfloat16 h = __float2bfloat16(f);
            float hf = __bfloat162float(h);
            __hip_bfloat16 l = __float2bfloat16(f - hf);
            hbuf[kk] = *(u16*)&h; lbuf[kk] = *(u16*)&l;
        }
        *(bf16x8*)(dh + g8 * 8) = *(bf16x8*)&hbuf[0];
        *(bf16x8*)(dl + g8 * 8) = *(bf16x8*)&lbuf[0];
    }
}

// ======================================================================
// k_filter v2: bf16x3 MFMA approx scores, A-fragments read from global
// EXACTLY ONCE per block. Scores bit-identical to proven v1.
// ======================================================================
__global__ __launch_bounds__(256, 2) void k_filter(const u16* __restrict__ zh,
                                                   const u16* __restrict__ zl,
                                                   const u16* __restrict__ eh,
                                                   const u16* __restrict__ el,
                                                   const float* __restrict__ ee,
                                                   u8* __restrict__ candcnt,
                                                   int* __restrict__ candk,
                                                   float* __restrict__ cands,
                                                   int* __restrict__ ocnt,
                                                   int* __restrict__ olist) {
    __shared__ u16  Bh0[128 * 64];    // 16 KB each, XOR-swizzled
    __shared__ u16  Bl0[128 * 64];
    __shared__ u16  Bh1[128 * 64];
    __shared__ u16  Bl1[128 * 64];
    __shared__ float eeL[256];
    __shared__ int  cntL[128];
    __shared__ int  ckL[128][3];
    __shared__ float csL[128][3];

    int t = threadIdx.x;
    int lane = t & 63, w = t >> 6;
    int g = blockIdx.x & 255;
    int q = blockIdx.x >> 8;
    int n0 = g * 128;
    int kqbase = q * 256;
    int prow = w * 32 + (lane & 15);
    const u16* zh0 = zh + (size_t)(n0 + prow) * 256;
    const u16* zl0 = zl + (size_t)(n0 + prow) * 256;
    const u16* zh1 = zh0 + 16 * 256;
    const u16* zl1 = zl0 + 16 * 256;
    int koff_lane = (lane >> 4) * 8;

    if (t < 128) cntL[t] = 0;
    eeL[t] = ee[kqbase + t];

    f32x4 acc[2][2][8];
#pragma unroll
    for (int nc = 0; nc < 2; ++nc)
#pragma unroll
        for (int gg = 0; gg < 2; ++gg)
#pragma unroll
            for (int nf = 0; nf < 8; ++nf)
                acc[nc][gg][nf] = (f32x4){0.f, 0.f, 0.f, 0.f};

    for (int kb = 0; kb < 4; ++kb) {
        __syncthreads();
#pragma unroll
        for (int nc = 0; nc < 2; ++nc) {
            int kcbase = kqbase + nc * 128;
            u16* BhX = nc ? Bh1 : Bh0;
            u16* BlX = nc ? Bl1 : Bl0;
#pragma unroll
            for (int i = 0; i < 8; ++i) {
                int f = i * 256 + t;
                int a = f >> 10, r = (f >> 3) & 127, seg = f & 7;
                const u16* src = (a ? el : eh) + (size_t)(kcbase + r) * 256 + kb * 64 + seg * 8;
                bf16x8 v = *(const bf16x8*)src;
                int bo = (r * 128 + seg * 16) ^ ((r & 7) << 4);
                *(bf16x8*)((char*)(a ? BlX : BhX) + bo) = v;
            }
        }
        __syncthreads();
#pragma unroll
        for (int ks2 = 0; ks2 < 2; ++ks2) {
            int ko = kb * 64 + ks2 * 32 + koff_lane;
            bf16x8 ah0 = *(const bf16x8*)(zh0 + ko);
            bf16x8 al0 = *(const bf16x8*)(zl0 + ko);
            bf16x8 ah1 = *(const bf16x8*)(zh1 + ko);
            bf16x8 al1 = *(const bf16x8*)(zl1 + ko);
#pragma unroll
            for (int nf = 0; nf < 8; ++nf) {
                int r = nf * 16 + (lane & 15);
                int bo = (r * 128 + ks2 * 64 + (lane >> 4) * 16) ^ ((r & 7) << 4);
                bf16x8 bh0v = *(const bf16x8*)((const char*)Bh0 + bo);
                bf16x8 bl0v = *(const bf16x8*)((const char*)Bl0 + bo);
                bf16x8 bh1v = *(const bf16x8*)((const char*)Bh1 + bo);
                bf16x8 bl1v = *(const bf16x8*)((const char*)Bl1 + bo);
                acc[0][0][nf] = __builtin_amdgcn_mfma_f32_16x16x32_bf16(ah0, bh0v, acc[0][0][nf], 0, 0, 0);
                acc[0][0][nf] = __builtin_amdgcn_mfma_f32_16x16x32_bf16(al0, bh0v, acc[0][0][nf], 0, 0, 0);
                acc[0][0][nf] = __builtin_amdgcn_mfma_f32_16x16x32_bf16(ah0, bl0v, acc[0][0][nf], 0, 0, 0);
                acc[0][1][nf] = __builtin_amdgcn_mfma_f32_16x16x32_bf16(ah1, bh0v, acc[0][1][nf], 0, 0, 0);
                acc[0][1][nf] = __builtin_amdgcn_mfma_f32_16x16x32_bf16(al1, bh0v, acc[0][1][nf], 0, 0, 0);
                acc[0][1][nf] = __builtin_amdgcn_mfma_f32_16x16x32_bf16(ah1, bl0v, acc[0][1][nf], 0, 0, 0);
                acc[1][0][nf] = __builtin_amdgcn_mfma_f32_16x16x32_bf16(ah0, bh1v, acc[1][0][nf], 0, 0, 0);
                acc[1][0][nf] = __builtin_amdgcn_mfma_f32_16x16x32_bf16(al0, bh1v, acc[1][0][nf], 0, 0, 0);
                acc[1][0][nf] = __builtin_amdgcn_mfma_f32_16x16x32_bf16(ah0, bl1v, acc[1][0][nf], 0, 0, 0);
                acc[1][1][nf] = __builtin_amdgcn_mfma_f32_16x16x32_bf16(ah1, bh1v, acc[1][1][nf], 0, 0, 0);
                acc[1][1][nf] = __builtin_amdgcn_mfma_f32_16x16x32_bf16(al1, bh1v, acc[1][1][nf], 0, 0, 0);
                acc[1][1][nf] = __builtin_amdgcn_mfma_f32_16x16x32_bf16(ah1, bl1v, acc[1][1][nf], 0, 0, 0);
            }
        }
    }
    __syncthreads();

    float runmin[2][4];
#pragma unroll
    for (int gg = 0; gg < 2; ++gg)
#pragma unroll
        for (int j = 0; j < 4; ++j) runmin[gg][j] = 3.4e38f;

#pragma unroll
    for (int nc = 0; nc < 2; ++nc) {
        int kcbase = kqbase + nc * 128;
#pragma unroll
        for (int gg = 0; gg < 2; ++gg) {
#pragma unroll
            for (int nf = 0; nf < 8; ++nf) {
                float eev = eeL[nc * 128 + nf * 16 + (lane & 15)];
                f32x4 d = acc[nc][gg][nf];
                f32x4 s;
#pragma unroll
                for (int j = 0; j < 4; ++j) s[j] = fmaf(-2.f, d[j], eev);
                acc[nc][gg][nf] = s;
            }
#pragma unroll
            for (int j = 0; j < 4; ++j) {
                float m = 3.4e38f;
#pragma unroll
                for (int nf = 0; nf < 8; ++nf) m = fminf(m, acc[nc][gg][nf][j]);
                m = fminf(m, __shfl_xor(m, 1, 64));
                m = fminf(m, __shfl_xor(m, 2, 64));
                m = fminf(m, __shfl_xor(m, 4, 64));
                m = fminf(m, __shfl_xor(m, 8, 64));
                runmin[gg][j] = fminf(runmin[gg][j], m);
                float th = runmin[gg][j] + MARGIN;
                int ml = w * 32 + gg * 16 + (lane >> 4) * 4 + j;
#pragma unroll
                for (int nf = 0; nf < 8; ++nf) {
                    float sv = acc[nc][gg][nf][j];
                    if (sv <= th) {
                        int pos = atomicAdd(&cntL[ml], 1);
                        if (pos < 3) { ckL[ml][pos] = kcbase + nf * 16 + (lane & 15);
                                       csL[ml][pos] = sv; }
                    }
                }
            }
        }
    }
    __syncthreads();
    if (t < 128) {
        int n = n0 + t;
        int cnt = cntL[t];
        candcnt[(size_t)n * 4 + q] = (u8)(cnt > 255 ? 255 : cnt);
        int* dk = candk + (size_t)n * 12 + q * 3;
        float* ds = cands + (size_t)n * 12 + q * 3;
#pragma unroll
        for (int i = 0; i < 3; ++i) {
            dk[i] = (i < cnt) ? ckL[t][i] : 0;
            ds[i] = (i < cnt) ? csL[t][i] : 3.4e38f;
        }
        if (cnt > 3) {
            int pos = atomicAdd(ocnt, 1);
            if (pos < OCAP) olist[pos] = n;
        }
    }
}

// ======================================================================
// k_rescore: certification + survivors-only exact dots.
// ======================================================================
__global__ __launch_bounds__(128) void k_rescore(const float* __restrict__ z,
                                                 const float* __restrict__ cb,
                                                 const float* __restrict__ ee,
                                                 const float* __restrict__ zz,
                                                 const u8* __restrict__ candcnt,
                                                 const int* __restrict__ candk,
                                                 const float* __restrict__ cands,
                                                 int* __restrict__ idx_out) {
    int t = threadIdx.x;
    int n = blockIdx.x * 128 + t;                 // 256 blocks
    int packed = ((const int*)candcnt)[n];
    int c0 = packed & 255, c1 = (packed >> 8) & 255,
        c2 = (packed >> 16) & 255, c3 = (packed >> 24) & 255;
    if ((c0 > 3) | (c1 > 3) | (c2 > 3) | (c3 > 3)) return;  // k_exact owns it

    int ks[12]; float ss[12];
    const int*   ck = candk + (size_t)n * 12;
    const float* cs = cands + (size_t)n * 12;
#pragma unroll
    for (int p = 0; p < 3; ++p) {
        *(int4*)&ks[p * 4]   = *(const int4*)(ck + p * 4);
        *(float4*)&ss[p * 4] = *(const float4*)(cs + p * 4);
    }
    float gmin = 3.4e38f;
#pragma unroll
    for (int j = 0; j < 12; ++j) gmin = fminf(gmin, ss[j]);
    float th = gmin + AMB;

    int nsurv = 0;
#pragma unroll
    for (int j = 0; j < 12; ++j) nsurv += (ss[j] <= th) ? 1 : 0;

    if (nsurv == 1) {
        int k = 0;
#pragma unroll
        for (int j = 0; j < 12; ++j) if (ss[j] <= th) k = ks[j];
        idx_out[n] = k;
        return;
    }

    int b = n >> 10, hw = n & 1023;
    const float* zp = z + (size_t)b * ZPLANE + hw;
    float zzv = zz[n];
    float bd = 3.4e38f; int bk = 1 << 30;
#pragma unroll
    for (int j = 0; j < 12; ++j) {
        if (ss[j] <= th) {
            int k = ks[j];
            const float* e0 = cb + (size_t)k * ED;
            float a0 = 0.f;
            for (int c = 0; c < ED; c += 4) {
                float4 ev = *(const float4*)(e0 + c);
                a0 = fmaf(zp[(size_t)c * 1024],       ev.x, a0);
                a0 = fmaf(zp[(size_t)(c + 1) * 1024], ev.y, a0);
                a0 = fmaf(zp[(size_t)(c + 2) * 1024], ev.z, a0);
                a0 = fmaf(zp[(size_t)(c + 3) * 1024], ev.w, a0);
            }
            float d0 = (zzv + ee[k]) - 2.f * a0;
            if (d0 < bd || (d0 == bd && k < bk)) { bd = d0; bk = k; }
        }
    }
    idx_out[n] = bk;
}

// ======================================================================
// k_exact: full 1024-code exact scan for overflow points (4 independent
// fmaf chains per thread; same per-code sequential arithmetic).
// ======================================================================
__global__ __launch_bounds__(256) void k_exact(const float* __restrict__ z,
                                               const float* __restrict__ cb,
                                               const float* __restrict__ ee,
                                               const float* __restrict__ zz,
                                               const int* __restrict__ ocnt,
                                               const int* __restrict__ olist,
                                               int* __restrict__ idx_out) {
    __shared__ float zL[ED];
    __shared__ float rv[4];
    __shared__ int   ri[4];
    int cnt = *ocnt; if (cnt > OCAP) cnt = OCAP;
    int t = threadIdx.x;
    for (int i = blockIdx.x; i < cnt; i += gridDim.x) {
        int n = olist[i];
        int b = n >> 10, hw = n & 1023;
        const float* zp = z + (size_t)b * ZPLANE + hw;
        __syncthreads();
        zL[t] = zp[(size_t)t * 1024];
        __syncthreads();
        float zzv = zz[n];
        int k0 = t, k1 = 256 + t, k2 = 512 + t, k3 = 768 + t;
        const float* e0 = cb + (size_t)k0 * ED;
        const float* e1 = cb + (size_t)k1 * ED;
        const float* e2 = cb + (size_t)k2 * ED;
        const float* e3 = cb + (size_t)k3 * ED;
        float a0 = 0.f, a1 = 0.f, a2 = 0.f, a3 = 0.f;
#pragma unroll 8
        for (int c = 0; c < ED; c += 4) {
            float4 z4 = *(const float4*)&zL[c];
            float4 v0 = *(const float4*)(e0 + c);
            float4 v1 = *(const float4*)(e1 + c);
            float4 v2 = *(const float4*)(e2 + c);
            float4 v3 = *(const float4*)(e3 + c);
            a0 = fmaf(z4.x, v0.x, a0); a0 = fmaf(z4.y, v0.y, a0);
            a0 = fmaf(z4.z, v0.z, a0); a0 = fmaf(z4.w, v0.w, a0);
            a1 = fmaf(z4.x, v1.x, a1); a1 = fmaf(z4.y, v1.y, a1);
            a1 = fmaf(z4.z, v1.z, a1); a1 = fmaf(z4.w, v1.w, a1);
            a2 = fmaf(z4.x, v2.x, a2); a2 = fmaf(z4.y, v2.y, a2);
            a2 = fmaf(z4.z, v2.z, a2); a2 = fmaf(z4.w, v2.w, a2);
            a3 = fmaf(z4.x, v3.x, a3); a3 = fmaf(z4.y, v3.y, a3);
            a3 = fmaf(z4.z, v3.z, a3); a3 = fmaf(z4.w, v3.w, a3);
        }
        float d0 = (zzv + ee[k0]) - 2.f * a0;
        float d1 = (zzv + ee[k1]) - 2.f * a1;
        float d2 = (zzv + ee[k2]) - 2.f * a2;
        float d3 = (zzv + ee[k3]) - 2.f * a3;
        float bd = d0; int bk = k0;
        if (d1 < bd) { bd = d1; bk = k1; }
        if (d2 < bd) { bd = d2; bk = k2; }
        if (d3 < bd) { bd = d3; bk = k3; }
        for (int off = 32; off; off >>= 1) {
            float ov = __shfl_down(bd, off);
            int   oi = __shfl_down(bk, off);
            if (ov < bd || (ov == bd && oi < bk)) { bd = ov; bk = oi; }
        }
        if ((t & 63) == 0) { rv[t >> 6] = bd; ri[t >> 6] = bk; }
        __syncthreads();
        if (t == 0) {
            for (int wv = 1; wv < 4; ++wv)
                if (rv[wv] < bd || (rv[wv] == bd && ri[wv] < bk)) { bd = rv[wv]; bk = ri[wv]; }
            idx_out[n] = bk;
        }
    }
}

// ======================================================================
// k_main (fallback path only): exact fp32 distances + argmin, proven.
// ======================================================================
#define TM 64
#define TK 128
#define CCH 64
__global__ __launch_bounds__(256) void k_main(const float* __restrict__ z,
                                              const float* __restrict__ eT,
                                              const float* __restrict__ ee,
                                              const float* __restrict__ zz,
                                              int* __restrict__ idx_out) {
    __shared__ float zt[CCH][TM];
    __shared__ float et[CCH][TK];
    __shared__ float redv[TM][16];
    __shared__ int   redi[TM][16];
    __shared__ float bestv[TM];
    __shared__ int   besti[TM];
    __shared__ float zzl[TM];
    int t = threadIdx.x;
    int n0 = blockIdx.x * TM;
    int b = n0 >> 10, hw0 = n0 & 1023;
    const float* zb = z + (size_t)b * ZPLANE + hw0;
    int trow = t >> 4, tcol = t & 15;
    if (t < TM) { bestv[t] = 3.4e38f; besti[t] = 0; zzl[t] = zz[n0 + t]; }
    for (int kt = 0; kt < NE / TK; ++kt) {
        int k0 = kt * TK;
        float acc[4][8];
        for (int i = 0; i < 4; ++i)
            for (int j = 0; j < 8; ++j) acc[i][j] = 0.f;
        for (int cc = 0; cc < ED / CCH; ++cc) {
            __syncthreads();
            {
                int m4 = (t & 15) * 4; int cb0 = t >> 4;
                for (int p = 0; p < 4; ++p) {
                    int cl = p * 16 + cb0;
                    float4 v = *(const float4*)(zb + (size_t)(cc * CCH + cl) * 1024 + m4);
                    *(float4*)&zt[cl][m4] = v;
                }
            }
            {
                int k4 = (t & 31) * 4; int cb0 = t >> 5;
                for (int p = 0; p < 8; ++p) {
                    int cl = p * 8 + cb0;
                    float4 v = *(const float4*)(eT + (size_t)(cc * CCH + cl) * 1024 + k0 + k4);
                    *(float4*)&et[cl][k4] = v;
                }
            }
            __syncthreads();
            for (int c = 0; c < CCH; ++c) {
                float4 zm = *(const float4*)&zt[c][trow * 4];
                float4 e0 = *(const float4*)&et[c][tcol * 8];
                float4 e1 = *(const float4*)&et[c][tcol * 8 + 4];
                float zv[4] = {zm.x, zm.y, zm.z, zm.w};
                float ev[8] = {e0.x, e0.y, e0.z, e0.w, e1.x, e1.y, e1.z, e1.w};
                for (int i = 0; i < 4; ++i)
                    for (int j = 0; j < 8; ++j)
                        acc[i][j] = fmaf(zv[i], ev[j], acc[i][j]);
            }
        }
        for (int i = 0; i < 4; ++i) {
            int m = trow * 4 + i;
            float zv = zzl[m];
            float bv = 3.4e38f; int bi = 0;
            for (int j = 0; j < 8; ++j) {
                int k = k0 + tcol * 8 + j;
                float t1 = zv + ee[k];
                float d  = t1 - 2.0f * acc[i][j];
                if (d < bv) { bv = d; bi = k; }
            }
            redv[m][tcol] = bv; redi[m][tcol] = bi;
        }
        __syncthreads();
        if (t < TM) {
            float bv = bestv[t]; int bi = besti[t];
            for (int tc = 0; tc < 16; ++tc) {
                float v = redv[t][tc]; int ix = redi[t][tc];
                if (v < bv || (v == bv && ix < bi)) { bv = v; bi = ix; }
            }
            bestv[t] = bv; besti[t] = bi;
        }
    }
    __syncthreads();
    if (t < TM) idx_out[n0 + t] = besti[t];
}

// ======================================================================
// k_out1 v2: z_q straight-through + loss partials. Stages the block's
// 32 codebook rows in LDS (coalesced float4 row reads, 257-stride
// conflict-free layout); fully coalesced z read / zq write.
// ======================================================================
__global__ __launch_bounds__(256) void k_out1(const float* __restrict__ z,
                                              const float* __restrict__ cb,
                                              const int* __restrict__ idx,
                                              float* __restrict__ out,
                                              double* __restrict__ lossp) {
#pragma clang fp contract(off)
    __shared__ float eL[32 * 257];     // 32.9 KB
    __shared__ int idxL[32];
    __shared__ double wsum[4];
    int t = threadIdx.x;
    int blk = blockIdx.x;              // 1024 = 32b * 32hwgrp
    int b   = blk >> 5;
    int hw0 = (blk & 31) * 32;
    int n0  = (b << 10) + hw0;
    if (t < 32) idxL[t] = idx[n0 + t];
    __syncthreads();
    {
        int w = t >> 6, lane = t & 63;
        for (int rr = 0; rr < 8; ++rr) {
            int r = w * 8 + rr;
            int iv = idxL[r];
            float4 v = *(const float4*)(cb + (size_t)iv * ED + lane * 4);
            float* dst = &eL[r * 257 + lane * 4];
            dst[0] = v.x; dst[1] = v.y; dst[2] = v.z; dst[3] = v.w;
        }
    }
    __syncthreads();
    int p = t & 31, cg = t >> 5;
    const float* zb = z + (size_t)b * ZPLANE + hw0;
    float* ob = out + OFF_ZQ + (size_t)b * ZPLANE + hw0;
    double lsum = 0.0;
    for (int i = 0; i < 32; ++i) {
        int c = i * 8 + cg;
        float zv = zb[(size_t)c * 1024 + p];
        float zq = eL[p * 257 + c];
        float d  = zq - zv;
        ob[(size_t)c * 1024 + p] = zv + d;
        lsum += (double)(d * d);
    }
    for (int off = 32; off; off >>= 1) lsum += __shfl_down(lsum, off);
    if ((t & 63) == 0) wsum[t >> 6] = lsum;
    __syncthreads();
    if (t == 0) lossp[blk] = (wsum[0] + wsum[1]) + (wsum[2] + wsum[3]);
}

// ======================================================================
// k_out2: one-hot encodings (float4 stores) + indices
// ======================================================================
__global__ __launch_bounds__(256) void k_out2(const int* __restrict__ idx,
                                              float* __restrict__ out) {
    int t = threadIdx.x;
    for (int it = 0; it < 16; ++it) {
        int q = (blockIdx.x * 16 + it) * 256 + t;  // grid 2048 -> 8388608 float4
        int row  = q >> 8;
        int col4 = (q & 255) * 4;
        int iv = idx[row];
        float4 v;
        v.x = (col4     == iv) ? 1.f : 0.f;
        v.y = (col4 + 1 == iv) ? 1.f : 0.f;
        v.z = (col4 + 2 == iv) ? 1.f : 0.f;
        v.w = (col4 + 3 == iv) ? 1.f : 0.f;
        *(float4*)(out + OFF_ENC + (size_t)q * 4) = v;
        if ((q & 255) == 0) out[OFF_IDX + row] = (float)iv;
    }
}

// ======================================================================
// k_final: perplexity + loss scalar, deterministic
// ======================================================================
__global__ __launch_bounds__(256) void k_final(const int* __restrict__ idx,
                                               const double* __restrict__ lossp,
                                               float* __restrict__ out) {
    __shared__ int cnt[NE];
    __shared__ double sh[4];
    int t = threadIdx.x;
    for (int k = t; k < NE; k += 256) cnt[k] = 0;
    __syncthreads();
    for (int n = t; n < NPTS; n += 256) atomicAdd(&cnt[idx[n]], 1);
    __syncthreads();
    double psum = 0.0;
    for (int k = t; k < NE; k += 256) {
        float em = (float)cnt[k] / 32768.0f;
        float term = em * logf(em + 1e-10f);
        psum += (double)term;
    }
    for (int off = 32; off; off >>= 1) psum += __shfl_down(psum, off);
    if ((t & 63) == 0) sh[t >> 6] = psum;
    __syncthreads();
    if (t == 0) {
        double tot = (sh[0] + sh[1]) + (sh[2] + sh[3]);
        out[OFF_PPL] = expf(-(float)tot);
    }
    __syncthreads();
    double ls = 0.0;
    for (int i = t; i < NLOSSP; i += 256) ls += lossp[i];
    for (int off = 32; off; off >>= 1) ls += __shfl_down(ls, off);
    __syncthreads();
    if ((t & 63) == 0) sh[t >> 6] = ls;
    __syncthreads();
    if (t == 0) {
        double m = ((sh[0] + sh[1]) + (sh[2] + sh[3])) / 8388608.0;
        float mf = (float)m;
        out[OFF_LOSS] = mf + 0.25f * mf;
    }
}

// ======================================================================
extern "C" void kernel_launch(void* const* d_in, const int* in_sizes, int n_in,
                              void* d_out, int out_size, void* d_ws, size_t ws_size,
                              hipStream_t stream) {
    const float* z  = (const float*)d_in[0];
    const float* cb = (const float*)d_in[1];
    float* out = (float*)d_out;
    char* ws = (char*)d_ws;

    int*    idx   = (int*)(ws + WS_IDX);
    float*  zz    = (float*)(ws + WS_ZZ);
    float*  ee    = (float*)(ws + WS_EE);
    double* lossp = (double*)(ws + WS_LOSSP);

    if (ws_size >= WS_NEED) {
        u16* eh = (u16*)(ws + WS_EH);
        u16* el = (u16*)(ws + WS_EL);
        u16* zh = (u16*)(ws + WS_ZH);
        u16* zl = (u16*)(ws + WS_ZL);
        u8*  ccnt  = (u8*)(ws + WS_CCNT);
        int* candk = (int*)(ws + WS_CANDK);
        float* cands = (float*)(ws + WS_CANDS);
        int* ocnt  = (int*)(ws + WS_OCNT);
        int* olist = (int*)(ws + WS_OLIST);

        k_eprep  <<<1024, 256, 0, stream>>>(cb, ee, eh, el, ocnt);
        k_zprep  <<<1024, 256, 0, stream>>>(z, zz, zh, zl);
        k_filter <<<1024, 256, 0, stream>>>(zh, zl, eh, el, ee, ccnt, candk, cands, ocnt, olist);
        k_rescore<<<256,  128, 0, stream>>>(z, cb, ee, zz, ccnt, candk, cands, idx);
        k_exact  <<<512,  256, 0, stream>>>(z, cb, ee, zz, ocnt, olist, idx);
        k_out1   <<<1024, 256, 0, stream>>>(z, cb, idx, out, lossp);
    } else {
        float* eT = (float*)(ws + WS_ET_FB);
        k_prep_old<<<4,   256, 0, stream>>>(cb, ee, eT);
        k_zz      <<<128, 256, 0, stream>>>(z, zz);
        k_main    <<<512, 256, 0, stream>>>(z, eT, ee, zz, idx);
        k_out1    <<<1024,256, 0, stream>>>(z, cb, idx, out, lossp);
    }
    k_out2 <<<2048, 256, 0, stream>>>(idx, out);
    k_final<<<1,    256, 0, stream>>>(idx, lossp, out);
}

// Round 9
// 257.892 us; speedup vs baseline: 10.4469x; 1.1441x over previous
//
#include <hip/hip_runtime.h>
#include <hip/hip_bf16.h>
#include <cstdint>
#include <cstddef>

typedef unsigned short u16;
typedef unsigned char u8;
typedef __attribute__((ext_vector_type(8))) short bf16x8;
typedef __attribute__((ext_vector_type(4))) float f32x4;

// ---- problem sizes ----
#define NPTS 32768      // B*H*W = 32*32*32
#define NE   1024       // codes
#define ED   256        // embedding dim (= C)
#define ZPLANE 262144   // 256*1024 floats per batch image (C*H*W)

// ---- output layout (floats) ----
#define OFF_LOSS 0
#define OFF_ZQ   1
#define OFF_PPL  8388609
#define OFF_ENC  8388610
#define OFF_IDX  41943042

// ---- ws layout (bytes) ----
#define WS_IDX   0              // int[32768]
#define WS_ZZ    131072         // float[32768]
#define WS_EE    262144         // float[1024]
#define WS_LOSSP 266240         // double[1024]
#define NLOSSP   1024
#define WS_HIST  274432         // int[1024] (dead gap before ET_FB)
#define WS_ET_FB 331776         // float[256*1024] (FALLBACK ONLY, overlays EH/EL)
#define WS_EH    331776         // u16[1024*256]
#define WS_EL    856064
#define WS_ZH    1380352        // u16[32768*256]
#define WS_ZL    18157568
#define WS_CCNT  34934784       // u8[4*32768] packed counts
#define WS_CANDK 35065856       // int[12*32768]
#define WS_CANDS 36638720       // float[12*32768]
#define WS_OCNT  38211584       // int: overflow count
#define WS_OLIST 38211588       // int[4096]: overflow point list
#define WS_NEED  38227972ULL

#define MARGIN 3.0e-4f          // k_filter emission margin (capture bound)
#define AMB    2.0e-4f          // certification ambiguity window (>2E, <=MARGIN)
#define OCAP   4096

// ======================================================================
// k_prep0: fused zprep (blocks 0-1023) + eprep (blocks 1024-2047).
// zprep: one z pass (float4 loads), LDS transpose, zz exact numpy
// pairwise order, bf16 hi/lo split. eprep: ||e||^2 + e split + zeroing.
// ======================================================================
__global__ __launch_bounds__(256) void k_prep0(const float* __restrict__ z,
                                               const float* __restrict__ cb,
                                               float* __restrict__ zz,
                                               u16* __restrict__ zh,
                                               u16* __restrict__ zl,
                                               float* __restrict__ ee,
                                               u16* __restrict__ eh,
                                               u16* __restrict__ el,
                                               int* __restrict__ ocnt,
                                               int* __restrict__ hist) {
#pragma clang fp contract(off)
    __shared__ float tile[256 * 33];   // 33.8 KB (eprep uses first 256)
    int t = threadIdx.x;
    int blk = blockIdx.x;

    if (blk < 1024) {
        // ---------------- zprep ----------------
        int b   = blk >> 5;
        int hw0 = (blk & 31) * 32;
        const float* zb = z + (size_t)b * ZPLANE + hw0;
        int p4 = (t & 7) * 4, cr = t >> 3;
#pragma unroll
        for (int i = 0; i < 8; ++i) {
            int c = i * 32 + cr;
            float4 v = *(const float4*)(zb + (size_t)c * 1024 + p4);
            float* dst = &tile[c * 33 + p4];
            dst[0] = v.x; dst[1] = v.y; dst[2] = v.z; dst[3] = v.w;
        }
        __syncthreads();
        // zz for 32 points, exact numpy pairwise order
        if (t < 32) {
            int p = t;
            float s[2];
            for (int h = 0; h < 2; ++h) {
                float r[8];
                for (int j = 0; j < 8; ++j) { float v = tile[(h * 128 + j) * 33 + p]; r[j] = v * v; }
                for (int i = 8; i < 128; i += 8)
                    for (int j = 0; j < 8; ++j) { float v = tile[(h * 128 + i + j) * 33 + p]; r[j] += v * v; }
                s[h] = ((r[0] + r[1]) + (r[2] + r[3])) + ((r[4] + r[5]) + (r[6] + r[7]));
            }
            zz[(b << 10) + hw0 + p] = s[0] + s[1];
        }
        // bf16 hi/lo split
        int p = t >> 3, cq = t & 7;
        size_t n = (size_t)(b << 10) + hw0 + p;
        u16* dh = zh + n * 256 + cq * 32;
        u16* dl = zl + n * 256 + cq * 32;
#pragma unroll
        for (int g8 = 0; g8 < 4; ++g8) {
            u16 hbuf[8], lbuf[8];
#pragma unroll
            for (int kk = 0; kk < 8; ++kk) {
                float f = tile[(cq * 32 + g8 * 8 + kk) * 33 + p];
                __hip_bfloat16 h = __float2bfloat16(f);
                float hf = __bfloat162float(h);
                __hip_bfloat16 l = __float2bfloat16(f - hf);
                hbuf[kk] = *(u16*)&h; lbuf[kk] = *(u16*)&l;
            }
            *(bf16x8*)(dh + g8 * 8) = *(bf16x8*)&hbuf[0];
            *(bf16x8*)(dl + g8 * 8) = *(bf16x8*)&lbuf[0];
        }
    } else {
        // ---------------- eprep ----------------
        int k = blk - 1024;
        if (k == 0) {
            if (t == 0) *ocnt = 0;
            for (int i = t; i < NE; i += 256) hist[i] = 0;
        }
        float f = cb[(size_t)k * ED + t];
        tile[t] = f;
        __hip_bfloat16 h = __float2bfloat16(f);
        float hf = __bfloat162float(h);
        __hip_bfloat16 l = __float2bfloat16(f - hf);
        eh[(size_t)k * ED + t] = *(u16*)&h;
        el[(size_t)k * ED + t] = *(u16*)&l;
        __syncthreads();
        if (t == 0) {
            float s[2];
            for (int h2 = 0; h2 < 2; ++h2) {
                const float* a = &tile[h2 * 128];
                float r[8];
                for (int j = 0; j < 8; ++j) { float v = a[j]; r[j] = v * v; }
                for (int i = 8; i < 128; i += 8)
                    for (int j = 0; j < 8; ++j) { float v = a[i + j]; r[j] += v * v; }
                s[h2] = ((r[0] + r[1]) + (r[2] + r[3])) + ((r[4] + r[5]) + (r[6] + r[7]));
            }
            ee[k] = s[0] + s[1];
        }
    }
}

// k_prep_old: fallback (ee + eT + hist zero)
__global__ __launch_bounds__(256) void k_prep_old(const float* __restrict__ cb,
                                                  float* __restrict__ ee,
                                                  float* __restrict__ eT,
                                                  int* __restrict__ hist) {
#pragma clang fp contract(off)
    if (blockIdx.x == 0) for (int i = threadIdx.x; i < NE; i += 256) hist[i] = 0;
    int k = blockIdx.x * 256 + threadIdx.x;
    if (k >= NE) return;
    const float* row = cb + (size_t)k * ED;
    float s[2];
    for (int h = 0; h < 2; ++h) {
        const float* a = row + h * 128;
        float r[8];
        for (int j = 0; j < 8; ++j) { float v = a[j]; r[j] = v * v; }
        for (int i = 8; i < 128; i += 8)
            for (int j = 0; j < 8; ++j) { float v = a[i + j]; r[j] += v * v; }
        s[h] = ((r[0] + r[1]) + (r[2] + r[3])) + ((r[4] + r[5]) + (r[6] + r[7]));
    }
    ee[k] = s[0] + s[1];
    for (int c = 0; c < ED; ++c) eT[(size_t)c * NE + k] = row[c];
}

// ======================================================================
// k_zz: fallback-only per-point ||z||^2 (proven exact)
// ======================================================================
__global__ __launch_bounds__(256) void k_zz(const float* __restrict__ z,
                                            float* __restrict__ zz) {
#pragma clang fp contract(off)
    int n = blockIdx.x * 256 + threadIdx.x;      // 128 blocks
    int b = n >> 10, hw = n & 1023;
    const float* a0 = z + (size_t)b * ZPLANE + hw;
    float s[2];
    for (int h = 0; h < 2; ++h) {
        const float* a = a0 + (size_t)h * 128 * 1024;
        float r[8];
        for (int j = 0; j < 8; ++j) { float v = a[(size_t)j * 1024]; r[j] = v * v; }
        for (int i = 8; i < 128; i += 8)
            for (int j = 0; j < 8; ++j) { float v = a[(size_t)(i + j) * 1024]; r[j] += v * v; }
        s[h] = ((r[0] + r[1]) + (r[2] + r[3])) + ((r[4] + r[5]) + (r[6] + r[7]));
    }
    zz[n] = s[0] + s[1];
}

// ======================================================================
// k_filter: bf16x3 MFMA approx scores, A read once per block (proven).
// ======================================================================
__global__ __launch_bounds__(256, 2) void k_filter(const u16* __restrict__ zh,
                                                   const u16* __restrict__ zl,
                                                   const u16* __restrict__ eh,
                                                   const u16* __restrict__ el,
                                                   const float* __restrict__ ee,
                                                   u8* __restrict__ candcnt,
                                                   int* __restrict__ candk,
                                                   float* __restrict__ cands,
                                                   int* __restrict__ ocnt,
                                                   int* __restrict__ olist) {
    __shared__ u16  Bh0[128 * 64];
    __shared__ u16  Bl0[128 * 64];
    __shared__ u16  Bh1[128 * 64];
    __shared__ u16  Bl1[128 * 64];
    __shared__ float eeL[256];
    __shared__ int  cntL[128];
    __shared__ int  ckL[128][3];
    __shared__ float csL[128][3];

    int t = threadIdx.x;
    int lane = t & 63, w = t >> 6;
    int g = blockIdx.x & 255;
    int q = blockIdx.x >> 8;
    int n0 = g * 128;
    int kqbase = q * 256;
    int prow = w * 32 + (lane & 15);
    const u16* zh0 = zh + (size_t)(n0 + prow) * 256;
    const u16* zl0 = zl + (size_t)(n0 + prow) * 256;
    const u16* zh1 = zh0 + 16 * 256;
    const u16* zl1 = zl0 + 16 * 256;
    int koff_lane = (lane >> 4) * 8;

    if (t < 128) cntL[t] = 0;
    eeL[t] = ee[kqbase + t];

    f32x4 acc[2][2][8];
#pragma unroll
    for (int nc = 0; nc < 2; ++nc)
#pragma unroll
        for (int gg = 0; gg < 2; ++gg)
#pragma unroll
            for (int nf = 0; nf < 8; ++nf)
                acc[nc][gg][nf] = (f32x4){0.f, 0.f, 0.f, 0.f};

    for (int kb = 0; kb < 4; ++kb) {
        __syncthreads();
#pragma unroll
        for (int nc = 0; nc < 2; ++nc) {
            int kcbase = kqbase + nc * 128;
            u16* BhX = nc ? Bh1 : Bh0;
            u16* BlX = nc ? Bl1 : Bl0;
#pragma unroll
            for (int i = 0; i < 8; ++i) {
                int f = i * 256 + t;
                int a = f >> 10, r = (f >> 3) & 127, seg = f & 7;
                const u16* src = (a ? el : eh) + (size_t)(kcbase + r) * 256 + kb * 64 + seg * 8;
                bf16x8 v = *(const bf16x8*)src;
                int bo = (r * 128 + seg * 16) ^ ((r & 7) << 4);
                *(bf16x8*)((char*)(a ? BlX : BhX) + bo) = v;
            }
        }
        __syncthreads();
#pragma unroll
        for (int ks2 = 0; ks2 < 2; ++ks2) {
            int ko = kb * 64 + ks2 * 32 + koff_lane;
            bf16x8 ah0 = *(const bf16x8*)(zh0 + ko);
            bf16x8 al0 = *(const bf16x8*)(zl0 + ko);
            bf16x8 ah1 = *(const bf16x8*)(zh1 + ko);
            bf16x8 al1 = *(const bf16x8*)(zl1 + ko);
#pragma unroll
            for (int nf = 0; nf < 8; ++nf) {
                int r = nf * 16 + (lane & 15);
                int bo = (r * 128 + ks2 * 64 + (lane >> 4) * 16) ^ ((r & 7) << 4);
                bf16x8 bh0v = *(const bf16x8*)((const char*)Bh0 + bo);
                bf16x8 bl0v = *(const bf16x8*)((const char*)Bl0 + bo);
                bf16x8 bh1v = *(const bf16x8*)((const char*)Bh1 + bo);
                bf16x8 bl1v = *(const bf16x8*)((const char*)Bl1 + bo);
                acc[0][0][nf] = __builtin_amdgcn_mfma_f32_16x16x32_bf16(ah0, bh0v, acc[0][0][nf], 0, 0, 0);
                acc[0][0][nf] = __builtin_amdgcn_mfma_f32_16x16x32_bf16(al0, bh0v, acc[0][0][nf], 0, 0, 0);
                acc[0][0][nf] = __builtin_amdgcn_mfma_f32_16x16x32_bf16(ah0, bl0v, acc[0][0][nf], 0, 0, 0);
                acc[0][1][nf] = __builtin_amdgcn_mfma_f32_16x16x32_bf16(ah1, bh0v, acc[0][1][nf], 0, 0, 0);
                acc[0][1][nf] = __builtin_amdgcn_mfma_f32_16x16x32_bf16(al1, bh0v, acc[0][1][nf], 0, 0, 0);
                acc[0][1][nf] = __builtin_amdgcn_mfma_f32_16x16x32_bf16(ah1, bl0v, acc[0][1][nf], 0, 0, 0);
                acc[1][0][nf] = __builtin_amdgcn_mfma_f32_16x16x32_bf16(ah0, bh1v, acc[1][0][nf], 0, 0, 0);
                acc[1][0][nf] = __builtin_amdgcn_mfma_f32_16x16x32_bf16(al0, bh1v, acc[1][0][nf], 0, 0, 0);
                acc[1][0][nf] = __builtin_amdgcn_mfma_f32_16x16x32_bf16(ah0, bl1v, acc[1][0][nf], 0, 0, 0);
                acc[1][1][nf] = __builtin_amdgcn_mfma_f32_16x16x32_bf16(ah1, bh1v, acc[1][1][nf], 0, 0, 0);
                acc[1][1][nf] = __builtin_amdgcn_mfma_f32_16x16x32_bf16(al1, bh1v, acc[1][1][nf], 0, 0, 0);
                acc[1][1][nf] = __builtin_amdgcn_mfma_f32_16x16x32_bf16(ah1, bl1v, acc[1][1][nf], 0, 0, 0);
            }
        }
    }
    __syncthreads();

    float runmin[2][4];
#pragma unroll
    for (int gg = 0; gg < 2; ++gg)
#pragma unroll
        for (int j = 0; j < 4; ++j) runmin[gg][j] = 3.4e38f;

#pragma unroll
    for (int nc = 0; nc < 2; ++nc) {
        int kcbase = kqbase + nc * 128;
#pragma unroll
        for (int gg = 0; gg < 2; ++gg) {
#pragma unroll
            for (int nf = 0; nf < 8; ++nf) {
                float eev = eeL[nc * 128 + nf * 16 + (lane & 15)];
                f32x4 d = acc[nc][gg][nf];
                f32x4 s;
#pragma unroll
                for (int j = 0; j < 4; ++j) s[j] = fmaf(-2.f, d[j], eev);
                acc[nc][gg][nf] = s;
            }
#pragma unroll
            for (int j = 0; j < 4; ++j) {
                float m = 3.4e38f;
#pragma unroll
                for (int nf = 0; nf < 8; ++nf) m = fminf(m, acc[nc][gg][nf][j]);
                m = fminf(m, __shfl_xor(m, 1, 64));
                m = fminf(m, __shfl_xor(m, 2, 64));
                m = fminf(m, __shfl_xor(m, 4, 64));
                m = fminf(m, __shfl_xor(m, 8, 64));
                runmin[gg][j] = fminf(runmin[gg][j], m);
                float th = runmin[gg][j] + MARGIN;
                int ml = w * 32 + gg * 16 + (lane >> 4) * 4 + j;
#pragma unroll
                for (int nf = 0; nf < 8; ++nf) {
                    float sv = acc[nc][gg][nf][j];
                    if (sv <= th) {
                        int pos = atomicAdd(&cntL[ml], 1);
                        if (pos < 3) { ckL[ml][pos] = kcbase + nf * 16 + (lane & 15);
                                       csL[ml][pos] = sv; }
                    }
                }
            }
        }
    }
    __syncthreads();
    if (t < 128) {
        int n = n0 + t;
        int cnt = cntL[t];
        candcnt[(size_t)n * 4 + q] = (u8)(cnt > 255 ? 255 : cnt);
        int* dk = candk + (size_t)n * 12 + q * 3;
        float* ds = cands + (size_t)n * 12 + q * 3;
#pragma unroll
        for (int i = 0; i < 3; ++i) {
            dk[i] = (i < cnt) ? ckL[t][i] : 0;
            ds[i] = (i < cnt) ? csL[t][i] : 3.4e38f;
        }
        if (cnt > 3) {
            int pos = atomicAdd(ocnt, 1);
            if (pos < OCAP) olist[pos] = n;
        }
    }
}

// ======================================================================
// k_score: fused rescore (phase 1, t<128) + overflow exact scan (phase
// 2, grid-stride, all 256 threads). Same arithmetic as proven kernels.
// ======================================================================
__global__ __launch_bounds__(256) void k_score(const float* __restrict__ z,
                                               const float* __restrict__ cb,
                                               const float* __restrict__ ee,
                                               const float* __restrict__ zz,
                                               const u8* __restrict__ candcnt,
                                               const int* __restrict__ candk,
                                               const float* __restrict__ cands,
                                               const int* __restrict__ ocnt,
                                               const int* __restrict__ olist,
                                               int* __restrict__ idx_out) {
    __shared__ float zL[ED];
    __shared__ float rv[4];
    __shared__ int   ri[4];
    int t = threadIdx.x;

    // ---------------- phase 1: certification + survivor rescore ------
    if (t < 128) {
        int n = blockIdx.x * 128 + t;                 // 256 blocks
        int packed = ((const int*)candcnt)[n];
        int c0 = packed & 255, c1 = (packed >> 8) & 255,
            c2 = (packed >> 16) & 255, c3 = (packed >> 24) & 255;
        if (!((c0 > 3) | (c1 > 3) | (c2 > 3) | (c3 > 3))) {
            int ks[12]; float ss[12];
            const int*   ck = candk + (size_t)n * 12;
            const float* cs = cands + (size_t)n * 12;
#pragma unroll
            for (int p = 0; p < 3; ++p) {
                *(int4*)&ks[p * 4]   = *(const int4*)(ck + p * 4);
                *(float4*)&ss[p * 4] = *(const float4*)(cs + p * 4);
            }
            float gmin = 3.4e38f;
#pragma unroll
            for (int j = 0; j < 12; ++j) gmin = fminf(gmin, ss[j]);
            float th = gmin + AMB;
            int nsurv = 0;
#pragma unroll
            for (int j = 0; j < 12; ++j) nsurv += (ss[j] <= th) ? 1 : 0;

            if (nsurv == 1) {
                int k = 0;
#pragma unroll
                for (int j = 0; j < 12; ++j) if (ss[j] <= th) k = ks[j];
                idx_out[n] = k;
            } else {
                int b = n >> 10, hw = n & 1023;
                const float* zp = z + (size_t)b * ZPLANE + hw;
                float zzv = zz[n];
                float bd = 3.4e38f; int bk = 1 << 30;
#pragma unroll
                for (int j = 0; j < 12; ++j) {
                    if (ss[j] <= th) {
                        int k = ks[j];
                        const float* e0 = cb + (size_t)k * ED;
                        float a0 = 0.f;
                        for (int c = 0; c < ED; c += 4) {
                            float4 ev = *(const float4*)(e0 + c);
                            a0 = fmaf(zp[(size_t)c * 1024],       ev.x, a0);
                            a0 = fmaf(zp[(size_t)(c + 1) * 1024], ev.y, a0);
                            a0 = fmaf(zp[(size_t)(c + 2) * 1024], ev.z, a0);
                            a0 = fmaf(zp[(size_t)(c + 3) * 1024], ev.w, a0);
                        }
                        float d0 = (zzv + ee[k]) - 2.f * a0;
                        if (d0 < bd || (d0 == bd && k < bk)) { bd = d0; bk = k; }
                    }
                }
                idx_out[n] = bk;
            }
        }
    }
    __syncthreads();

    // ---------------- phase 2: overflow exact scan -------------------
    int cnt = *ocnt; if (cnt > OCAP) cnt = OCAP;
    for (int i = blockIdx.x; i < cnt; i += gridDim.x) {
        int n = olist[i];
        int b = n >> 10, hw = n & 1023;
        const float* zp = z + (size_t)b * ZPLANE + hw;
        __syncthreads();
        zL[t] = zp[(size_t)t * 1024];
        __syncthreads();
        float zzv = zz[n];
        int k0 = t, k1 = 256 + t, k2 = 512 + t, k3 = 768 + t;
        const float* e0 = cb + (size_t)k0 * ED;
        const float* e1 = cb + (size_t)k1 * ED;
        const float* e2 = cb + (size_t)k2 * ED;
        const float* e3 = cb + (size_t)k3 * ED;
        float a0 = 0.f, a1 = 0.f, a2 = 0.f, a3 = 0.f;
#pragma unroll 8
        for (int c = 0; c < ED; c += 4) {
            float4 z4 = *(const float4*)&zL[c];
            float4 v0 = *(const float4*)(e0 + c);
            float4 v1 = *(const float4*)(e1 + c);
            float4 v2 = *(const float4*)(e2 + c);
            float4 v3 = *(const float4*)(e3 + c);
            a0 = fmaf(z4.x, v0.x, a0); a0 = fmaf(z4.y, v0.y, a0);
            a0 = fmaf(z4.z, v0.z, a0); a0 = fmaf(z4.w, v0.w, a0);
            a1 = fmaf(z4.x, v1.x, a1); a1 = fmaf(z4.y, v1.y, a1);
            a1 = fmaf(z4.z, v1.z, a1); a1 = fmaf(z4.w, v1.w, a1);
            a2 = fmaf(z4.x, v2.x, a2); a2 = fmaf(z4.y, v2.y, a2);
            a2 = fmaf(z4.z, v2.z, a2); a2 = fmaf(z4.w, v2.w, a2);
            a3 = fmaf(z4.x, v3.x, a3); a3 = fmaf(z4.y, v3.y, a3);
            a3 = fmaf(z4.z, v3.z, a3); a3 = fmaf(z4.w, v3.w, a3);
        }
        float d0 = (zzv + ee[k0]) - 2.f * a0;
        float d1 = (zzv + ee[k1]) - 2.f * a1;
        float d2 = (zzv + ee[k2]) - 2.f * a2;
        float d3 = (zzv + ee[k3]) - 2.f * a3;
        float bd = d0; int bk = k0;
        if (d1 < bd) { bd = d1; bk = k1; }
        if (d2 < bd) { bd = d2; bk = k2; }
        if (d3 < bd) { bd = d3; bk = k3; }
        for (int off = 32; off; off >>= 1) {
            float ov = __shfl_down(bd, off);
            int   oi = __shfl_down(bk, off);
            if (ov < bd || (ov == bd && oi < bk)) { bd = ov; bk = oi; }
        }
        if ((t & 63) == 0) { rv[t >> 6] = bd; ri[t >> 6] = bk; }
        __syncthreads();
        if (t == 0) {
            for (int wv = 1; wv < 4; ++wv)
                if (rv[wv] < bd || (rv[wv] == bd && ri[wv] < bk)) { bd = rv[wv]; bk = ri[wv]; }
            idx_out[n] = bk;
        }
    }
}

// ======================================================================
// k_main (fallback path only): exact fp32 distances + argmin, proven.
// ======================================================================
#define TM 64
#define TK 128
#define CCH 64
__global__ __launch_bounds__(256) void k_main(const float* __restrict__ z,
                                              const float* __restrict__ eT,
                                              const float* __restrict__ ee,
                                              const float* __restrict__ zz,
                                              int* __restrict__ idx_out) {
    __shared__ float zt[CCH][TM];
    __shared__ float et[CCH][TK];
    __shared__ float redv[TM][16];
    __shared__ int   redi[TM][16];
    __shared__ float bestv[TM];
    __shared__ int   besti[TM];
    __shared__ float zzl[TM];
    int t = threadIdx.x;
    int n0 = blockIdx.x * TM;
    int b = n0 >> 10, hw0 = n0 & 1023;
    const float* zb = z + (size_t)b * ZPLANE + hw0;
    int trow = t >> 4, tcol = t & 15;
    if (t < TM) { bestv[t] = 3.4e38f; besti[t] = 0; zzl[t] = zz[n0 + t]; }
    for (int kt = 0; kt < NE / TK; ++kt) {
        int k0 = kt * TK;
        float acc[4][8];
        for (int i = 0; i < 4; ++i)
            for (int j = 0; j < 8; ++j) acc[i][j] = 0.f;
        for (int cc = 0; cc < ED / CCH; ++cc) {
            __syncthreads();
            {
                int m4 = (t & 15) * 4; int cb0 = t >> 4;
                for (int p = 0; p < 4; ++p) {
                    int cl = p * 16 + cb0;
                    float4 v = *(const float4*)(zb + (size_t)(cc * CCH + cl) * 1024 + m4);
                    *(float4*)&zt[cl][m4] = v;
                }
            }
            {
                int k4 = (t & 31) * 4; int cb0 = t >> 5;
                for (int p = 0; p < 8; ++p) {
                    int cl = p * 8 + cb0;
                    float4 v = *(const float4*)(eT + (size_t)(cc * CCH + cl) * 1024 + k0 + k4);
                    *(float4*)&et[cl][k4] = v;
                }
            }
            __syncthreads();
            for (int c = 0; c < CCH; ++c) {
                float4 zm = *(const float4*)&zt[c][trow * 4];
                float4 e0 = *(const float4*)&et[c][tcol * 8];
                float4 e1 = *(const float4*)&et[c][tcol * 8 + 4];
                float zv[4] = {zm.x, zm.y, zm.z, zm.w};
                float ev[8] = {e0.x, e0.y, e0.z, e0.w, e1.x, e1.y, e1.z, e1.w};
                for (int i = 0; i < 4; ++i)
                    for (int j = 0; j < 8; ++j)
                        acc[i][j] = fmaf(zv[i], ev[j], acc[i][j]);
            }
        }
        for (int i = 0; i < 4; ++i) {
            int m = trow * 4 + i;
            float zv = zzl[m];
            float bv = 3.4e38f; int bi = 0;
            for (int j = 0; j < 8; ++j) {
                int k = k0 + tcol * 8 + j;
                float t1 = zv + ee[k];
                float d  = t1 - 2.0f * acc[i][j];
                if (d < bv) { bv = d; bi = k; }
            }
            redv[m][tcol] = bv; redi[m][tcol] = bi;
        }
        __syncthreads();
        if (t < TM) {
            float bv = bestv[t]; int bi = besti[t];
            for (int tc = 0; tc < 16; ++tc) {
                float v = redv[t][tc]; int ix = redi[t][tc];
                if (v < bv || (v == bv && ix < bi)) { bv = v; bi = ix; }
            }
            bestv[t] = bv; besti[t] = bi;
        }
    }
    __syncthreads();
    if (t < TM) idx_out[n0 + t] = besti[t];
}

// ======================================================================
// k_out: fused out1 (blocks 0-1023: z_q + loss partials, float4) and
// out2 (blocks 1024-3071: one-hot float4 stores + indices + histogram).
// ======================================================================
__global__ __launch_bounds__(256) void k_out(const float* __restrict__ z,
                                             const float* __restrict__ cb,
                                             const int* __restrict__ idx,
                                             float* __restrict__ out,
                                             double* __restrict__ lossp,
                                             int* __restrict__ hist) {
#pragma clang fp contract(off)
    __shared__ float eL[32 * 257];     // 32.9 KB
    __shared__ int idxL[32];
    __shared__ double wsum[4];
    int t = threadIdx.x;
    int blk = blockIdx.x;

    if (blk < 1024) {
        // ---------------- out1: z_q + loss ----------------
        int b   = blk >> 5;
        int hw0 = (blk & 31) * 32;
        int n0  = (b << 10) + hw0;
        if (t < 32) idxL[t] = idx[n0 + t];
        __syncthreads();
        {
            int w = t >> 6, lane = t & 63;
            for (int rr = 0; rr < 8; ++rr) {
                int r = w * 8 + rr;
                int iv = idxL[r];
                float4 v = *(const float4*)(cb + (size_t)iv * ED + lane * 4);
                float* dst = &eL[r * 257 + lane * 4];
                dst[0] = v.x; dst[1] = v.y; dst[2] = v.z; dst[3] = v.w;
            }
        }
        __syncthreads();
        int p4 = (t & 7) * 4, cr = t >> 3;
        const float* zb = z + (size_t)b * ZPLANE + hw0;
        float* ob = out + OFF_ZQ + (size_t)b * ZPLANE + hw0;
        double lsum = 0.0;
#pragma unroll
        for (int i = 0; i < 8; ++i) {
            int c = i * 32 + cr;
            float4 zv4 = *(const float4*)(zb + (size_t)c * 1024 + p4);
            float4 o;
            float d0 = eL[(p4)     * 257 + c] - zv4.x; o.x = zv4.x + d0;
            float d1 = eL[(p4 + 1) * 257 + c] - zv4.y; o.y = zv4.y + d1;
            float d2 = eL[(p4 + 2) * 257 + c] - zv4.z; o.z = zv4.z + d2;
            float d3 = eL[(p4 + 3) * 257 + c] - zv4.w; o.w = zv4.w + d3;
            *(float4*)(ob + (size_t)c * 1024 + p4) = o;
            lsum += (double)(d0 * d0) + (double)(d1 * d1)
                  + (double)(d2 * d2) + (double)(d3 * d3);
        }
        for (int off = 32; off; off >>= 1) lsum += __shfl_down(lsum, off);
        if ((t & 63) == 0) wsum[t >> 6] = lsum;
        __syncthreads();
        if (t == 0) lossp[blk] = (wsum[0] + wsum[1]) + (wsum[2] + wsum[3]);
    } else {
        // ---------------- out2: one-hot + indices + histogram --------
        int blk2 = blk - 1024;
        if (t < 16) atomicAdd(&hist[idx[blk2 * 16 + t]], 1);
        for (int it = 0; it < 16; ++it) {
            int qq = (blk2 * 16 + it) * 256 + t;
            int row  = qq >> 8;
            int col4 = (qq & 255) * 4;
            int iv = idx[row];
            float4 v;
            v.x = (col4     == iv) ? 1.f : 0.f;
            v.y = (col4 + 1 == iv) ? 1.f : 0.f;
            v.z = (col4 + 2 == iv) ? 1.f : 0.f;
            v.w = (col4 + 3 == iv) ? 1.f : 0.f;
            *(float4*)(out + OFF_ENC + (size_t)qq * 4) = v;
            if ((qq & 255) == 0) out[OFF_IDX + row] = (float)iv;
        }
    }
}

// ======================================================================
// k_final2: perplexity from histogram + loss scalar. Deterministic.
// ======================================================================
__global__ __launch_bounds__(256) void k_final2(const int* __restrict__ hist,
                                                const double* __restrict__ lossp,
                                                float* __restrict__ out) {
    __shared__ double sh[4];
    int t = threadIdx.x;
    double psum = 0.0;
    for (int k = t; k < NE; k += 256) {
        float em = (float)hist[k] / 32768.0f;
        float term = em * logf(em + 1e-10f);
        psum += (double)term;
    }
    for (int off = 32; off; off >>= 1) psum += __shfl_down(psum, off);
    if ((t & 63) == 0) sh[t >> 6] = psum;
    __syncthreads();
    if (t == 0) {
        double tot = (sh[0] + sh[1]) + (sh[2] + sh[3]);
        out[OFF_PPL] = expf(-(float)tot);
    }
    __syncthreads();
    double ls = 0.0;
    for (int i = t; i < NLOSSP; i += 256) ls += lossp[i];
    for (int off = 32; off; off >>= 1) ls += __shfl_down(ls, off);
    __syncthreads();
    if ((t & 63) == 0) sh[t >> 6] = ls;
    __syncthreads();
    if (t == 0) {
        double m = ((sh[0] + sh[1]) + (sh[2] + sh[3])) / 8388608.0;
        float mf = (float)m;
        out[OFF_LOSS] = mf + 0.25f * mf;
    }
}

// ======================================================================
extern "C" void kernel_launch(void* const* d_in, const int* in_sizes, int n_in,
                              void* d_out, int out_size, void* d_ws, size_t ws_size,
                              hipStream_t stream) {
    const float* z  = (const float*)d_in[0];
    const float* cb = (const float*)d_in[1];
    float* out = (float*)d_out;
    char* ws = (char*)d_ws;

    int*    idx   = (int*)(ws + WS_IDX);
    float*  zz    = (float*)(ws + WS_ZZ);
    float*  ee    = (float*)(ws + WS_EE);
    double* lossp = (double*)(ws + WS_LOSSP);
    int*    hist  = (int*)(ws + WS_HIST);

    if (ws_size >= WS_NEED) {
        u16* eh = (u16*)(ws + WS_EH);
        u16* el = (u16*)(ws + WS_EL);
        u16* zh = (u16*)(ws + WS_ZH);
        u16* zl = (u16*)(ws + WS_ZL);
        u8*  ccnt  = (u8*)(ws + WS_CCNT);
        int* candk = (int*)(ws + WS_CANDK);
        float* cands = (float*)(ws + WS_CANDS);
        int* ocnt  = (int*)(ws + WS_OCNT);
        int* olist = (int*)(ws + WS_OLIST);

        k_prep0 <<<2048, 256, 0, stream>>>(z, cb, zz, zh, zl, ee, eh, el, ocnt, hist);
        k_filter<<<1024, 256, 0, stream>>>(zh, zl, eh, el, ee, ccnt, candk, cands, ocnt, olist);
        k_score <<<256,  256, 0, stream>>>(z, cb, ee, zz, ccnt, candk, cands, ocnt, olist, idx);
        k_out   <<<3072, 256, 0, stream>>>(z, cb, idx, out, lossp, hist);
    } else {
        float* eT = (float*)(ws + WS_ET_FB);
        k_prep_old<<<4,   256, 0, stream>>>(cb, ee, eT, hist);
        k_zz      <<<128, 256, 0, stream>>>(z, zz);
        k_main    <<<512, 256, 0, stream>>>(z, eT, ee, zz, idx);
        k_out     <<<3072,256, 0, stream>>>(z, cb, idx, out, lossp, hist);
    }
    k_final2<<<1, 256, 0, stream>>>(hist, lossp, out);
}

// Round 10
// 219.757 us; speedup vs baseline: 12.2598x; 1.1735x over previous
//
#include <hip/hip_runtime.h>
#include <hip/hip_bf16.h>
#include <cstdint>
#include <cstddef>

typedef unsigned short u16;
typedef unsigned char u8;
typedef __attribute__((ext_vector_type(8))) short bf16x8;
typedef __attribute__((ext_vector_type(4))) float f32x4;

// ---- problem sizes ----
#define NPTS 32768      // B*H*W = 32*32*32
#define NE   1024       // codes
#define ED   256        // embedding dim (= C)
#define ZPLANE 262144   // 256*1024 floats per batch image (C*H*W)

// ---- output layout (floats) ----
#define OFF_LOSS 0
#define OFF_ZQ   1
#define OFF_PPL  8388609
#define OFF_ENC  8388610
#define OFF_IDX  41943042

// ---- ws layout (bytes) ----
#define WS_IDX   0              // int[32768]
#define WS_ZZ    131072         // float[32768]
#define WS_EE    262144         // float[1024]
#define WS_LOSSP 266240         // double[1024]
#define NLOSSP   1024
#define WS_HIST  274432         // int[1024] (dead gap before ET_FB)
#define WS_ET_FB 331776         // float[256*1024] (FALLBACK ONLY, overlays EH/EL)
#define WS_EH    331776         // u16[1024*256]
#define WS_EL    856064
#define WS_ZH    1380352        // u16[32768*256]
#define WS_ZL    18157568
#define WS_CCNT  34934784       // u8[4*32768] packed counts
#define WS_CANDK 35065856       // int[12*32768]
#define WS_CANDS 36638720       // float[12*32768]
#define WS_OCNT  38211584       // int: overflow count
#define WS_OLIST 38211588       // int[4096]: overflow point list
#define WS_NEED  38227972ULL

#define MARGIN 3.0e-4f          // k_filter emission margin (capture bound)
#define AMB    2.0e-4f          // certification ambiguity window (>2E, <=MARGIN)
#define OCAP   4096

// ======================================================================
// k_prep0: fused zprep (blocks 0-1023) + eprep (blocks 1024-2047).
// ======================================================================
__global__ __launch_bounds__(256) void k_prep0(const float* __restrict__ z,
                                               const float* __restrict__ cb,
                                               float* __restrict__ zz,
                                               u16* __restrict__ zh,
                                               u16* __restrict__ zl,
                                               float* __restrict__ ee,
                                               u16* __restrict__ eh,
                                               u16* __restrict__ el,
                                               int* __restrict__ ocnt,
                                               int* __restrict__ hist) {
#pragma clang fp contract(off)
    __shared__ float tile[256 * 33];   // 33.8 KB (eprep uses first 256)
    int t = threadIdx.x;
    int blk = blockIdx.x;

    if (blk < 1024) {
        // ---------------- zprep ----------------
        int b   = blk >> 5;
        int hw0 = (blk & 31) * 32;
        const float* zb = z + (size_t)b * ZPLANE + hw0;
        int p4 = (t & 7) * 4, cr = t >> 3;
#pragma unroll
        for (int i = 0; i < 8; ++i) {
            int c = i * 32 + cr;
            float4 v = *(const float4*)(zb + (size_t)c * 1024 + p4);
            float* dst = &tile[c * 33 + p4];
            dst[0] = v.x; dst[1] = v.y; dst[2] = v.z; dst[3] = v.w;
        }
        __syncthreads();
        // zz for 32 points, exact numpy pairwise order
        if (t < 32) {
            int p = t;
            float s[2];
            for (int h = 0; h < 2; ++h) {
                float r[8];
                for (int j = 0; j < 8; ++j) { float v = tile[(h * 128 + j) * 33 + p]; r[j] = v * v; }
                for (int i = 8; i < 128; i += 8)
                    for (int j = 0; j < 8; ++j) { float v = tile[(h * 128 + i + j) * 33 + p]; r[j] += v * v; }
                s[h] = ((r[0] + r[1]) + (r[2] + r[3])) + ((r[4] + r[5]) + (r[6] + r[7]));
            }
            zz[(b << 10) + hw0 + p] = s[0] + s[1];
        }
        // bf16 hi/lo split
        int p = t >> 3, cq = t & 7;
        size_t n = (size_t)(b << 10) + hw0 + p;
        u16* dh = zh + n * 256 + cq * 32;
        u16* dl = zl + n * 256 + cq * 32;
#pragma unroll
        for (int g8 = 0; g8 < 4; ++g8) {
            u16 hbuf[8], lbuf[8];
#pragma unroll
            for (int kk = 0; kk < 8; ++kk) {
                float f = tile[(cq * 32 + g8 * 8 + kk) * 33 + p];
                __hip_bfloat16 h = __float2bfloat16(f);
                float hf = __bfloat162float(h);
                __hip_bfloat16 l = __float2bfloat16(f - hf);
                hbuf[kk] = *(u16*)&h; lbuf[kk] = *(u16*)&l;
            }
            *(bf16x8*)(dh + g8 * 8) = *(bf16x8*)&hbuf[0];
            *(bf16x8*)(dl + g8 * 8) = *(bf16x8*)&lbuf[0];
        }
    } else {
        // ---------------- eprep ----------------
        int k = blk - 1024;
        if (k == 0) {
            if (t == 0) *ocnt = 0;
            for (int i = t; i < NE; i += 256) hist[i] = 0;
        }
        float f = cb[(size_t)k * ED + t];
        tile[t] = f;
        __hip_bfloat16 h = __float2bfloat16(f);
        float hf = __bfloat162float(h);
        __hip_bfloat16 l = __float2bfloat16(f - hf);
        eh[(size_t)k * ED + t] = *(u16*)&h;
        el[(size_t)k * ED + t] = *(u16*)&l;
        __syncthreads();
        if (t == 0) {
            float s[2];
            for (int h2 = 0; h2 < 2; ++h2) {
                const float* a = &tile[h2 * 128];
                float r[8];
                for (int j = 0; j < 8; ++j) { float v = a[j]; r[j] = v * v; }
                for (int i = 8; i < 128; i += 8)
                    for (int j = 0; j < 8; ++j) { float v = a[i + j]; r[j] += v * v; }
                s[h2] = ((r[0] + r[1]) + (r[2] + r[3])) + ((r[4] + r[5]) + (r[6] + r[7]));
            }
            ee[k] = s[0] + s[1];
        }
    }
}

// k_prep_old: fallback (ee + eT + hist zero)
__global__ __launch_bounds__(256) void k_prep_old(const float* __restrict__ cb,
                                                  float* __restrict__ ee,
                                                  float* __restrict__ eT,
                                                  int* __restrict__ hist) {
#pragma clang fp contract(off)
    if (blockIdx.x == 0) for (int i = threadIdx.x; i < NE; i += 256) hist[i] = 0;
    int k = blockIdx.x * 256 + threadIdx.x;
    if (k >= NE) return;
    const float* row = cb + (size_t)k * ED;
    float s[2];
    for (int h = 0; h < 2; ++h) {
        const float* a = row + h * 128;
        float r[8];
        for (int j = 0; j < 8; ++j) { float v = a[j]; r[j] = v * v; }
        for (int i = 8; i < 128; i += 8)
            for (int j = 0; j < 8; ++j) { float v = a[i + j]; r[j] += v * v; }
        s[h] = ((r[0] + r[1]) + (r[2] + r[3])) + ((r[4] + r[5]) + (r[6] + r[7]));
    }
    ee[k] = s[0] + s[1];
    for (int c = 0; c < ED; ++c) eT[(size_t)c * NE + k] = row[c];
}

// ======================================================================
// k_zz: fallback-only per-point ||z||^2 (proven exact)
// ======================================================================
__global__ __launch_bounds__(256) void k_zz(const float* __restrict__ z,
                                            float* __restrict__ zz) {
#pragma clang fp contract(off)
    int n = blockIdx.x * 256 + threadIdx.x;      // 128 blocks
    int b = n >> 10, hw = n & 1023;
    const float* a0 = z + (size_t)b * ZPLANE + hw;
    float s[2];
    for (int h = 0; h < 2; ++h) {
        const float* a = a0 + (size_t)h * 128 * 1024;
        float r[8];
        for (int j = 0; j < 8; ++j) { float v = a[(size_t)j * 1024]; r[j] = v * v; }
        for (int i = 8; i < 128; i += 8)
            for (int j = 0; j < 8; ++j) { float v = a[(size_t)(i + j) * 1024]; r[j] += v * v; }
        s[h] = ((r[0] + r[1]) + (r[2] + r[3])) + ((r[4] + r[5]) + (r[6] + r[7]));
    }
    zz[n] = s[0] + s[1];
}

// ======================================================================
// k_filter: bf16x3 MFMA approx scores, A read once per block (proven).
// ======================================================================
__global__ __launch_bounds__(256, 2) void k_filter(const u16* __restrict__ zh,
                                                   const u16* __restrict__ zl,
                                                   const u16* __restrict__ eh,
                                                   const u16* __restrict__ el,
                                                   const float* __restrict__ ee,
                                                   u8* __restrict__ candcnt,
                                                   int* __restrict__ candk,
                                                   float* __restrict__ cands,
                                                   int* __restrict__ ocnt,
                                                   int* __restrict__ olist) {
    __shared__ u16  Bh0[128 * 64];
    __shared__ u16  Bl0[128 * 64];
    __shared__ u16  Bh1[128 * 64];
    __shared__ u16  Bl1[128 * 64];
    __shared__ float eeL[256];
    __shared__ int  cntL[128];
    __shared__ int  ckL[128][3];
    __shared__ float csL[128][3];

    int t = threadIdx.x;
    int lane = t & 63, w = t >> 6;
    int g = blockIdx.x & 255;
    int q = blockIdx.x >> 8;
    int n0 = g * 128;
    int kqbase = q * 256;
    int prow = w * 32 + (lane & 15);
    const u16* zh0 = zh + (size_t)(n0 + prow) * 256;
    const u16* zl0 = zl + (size_t)(n0 + prow) * 256;
    const u16* zh1 = zh0 + 16 * 256;
    const u16* zl1 = zl0 + 16 * 256;
    int koff_lane = (lane >> 4) * 8;

    if (t < 128) cntL[t] = 0;
    eeL[t] = ee[kqbase + t];

    f32x4 acc[2][2][8];
#pragma unroll
    for (int nc = 0; nc < 2; ++nc)
#pragma unroll
        for (int gg = 0; gg < 2; ++gg)
#pragma unroll
            for (int nf = 0; nf < 8; ++nf)
                acc[nc][gg][nf] = (f32x4){0.f, 0.f, 0.f, 0.f};

    for (int kb = 0; kb < 4; ++kb) {
        __syncthreads();
#pragma unroll
        for (int nc = 0; nc < 2; ++nc) {
            int kcbase = kqbase + nc * 128;
            u16* BhX = nc ? Bh1 : Bh0;
            u16* BlX = nc ? Bl1 : Bl0;
#pragma unroll
            for (int i = 0; i < 8; ++i) {
                int f = i * 256 + t;
                int a = f >> 10, r = (f >> 3) & 127, seg = f & 7;
                const u16* src = (a ? el : eh) + (size_t)(kcbase + r) * 256 + kb * 64 + seg * 8;
                bf16x8 v = *(const bf16x8*)src;
                int bo = (r * 128 + seg * 16) ^ ((r & 7) << 4);
                *(bf16x8*)((char*)(a ? BlX : BhX) + bo) = v;
            }
        }
        __syncthreads();
#pragma unroll
        for (int ks2 = 0; ks2 < 2; ++ks2) {
            int ko = kb * 64 + ks2 * 32 + koff_lane;
            bf16x8 ah0 = *(const bf16x8*)(zh0 + ko);
            bf16x8 al0 = *(const bf16x8*)(zl0 + ko);
            bf16x8 ah1 = *(const bf16x8*)(zh1 + ko);
            bf16x8 al1 = *(const bf16x8*)(zl1 + ko);
#pragma unroll
            for (int nf = 0; nf < 8; ++nf) {
                int r = nf * 16 + (lane & 15);
                int bo = (r * 128 + ks2 * 64 + (lane >> 4) * 16) ^ ((r & 7) << 4);
                bf16x8 bh0v = *(const bf16x8*)((const char*)Bh0 + bo);
                bf16x8 bl0v = *(const bf16x8*)((const char*)Bl0 + bo);
                bf16x8 bh1v = *(const bf16x8*)((const char*)Bh1 + bo);
                bf16x8 bl1v = *(const bf16x8*)((const char*)Bl1 + bo);
                acc[0][0][nf] = __builtin_amdgcn_mfma_f32_16x16x32_bf16(ah0, bh0v, acc[0][0][nf], 0, 0, 0);
                acc[0][0][nf] = __builtin_amdgcn_mfma_f32_16x16x32_bf16(al0, bh0v, acc[0][0][nf], 0, 0, 0);
                acc[0][0][nf] = __builtin_amdgcn_mfma_f32_16x16x32_bf16(ah0, bl0v, acc[0][0][nf], 0, 0, 0);
                acc[0][1][nf] = __builtin_amdgcn_mfma_f32_16x16x32_bf16(ah1, bh0v, acc[0][1][nf], 0, 0, 0);
                acc[0][1][nf] = __builtin_amdgcn_mfma_f32_16x16x32_bf16(al1, bh0v, acc[0][1][nf], 0, 0, 0);
                acc[0][1][nf] = __builtin_amdgcn_mfma_f32_16x16x32_bf16(ah1, bl0v, acc[0][1][nf], 0, 0, 0);
                acc[1][0][nf] = __builtin_amdgcn_mfma_f32_16x16x32_bf16(ah0, bh1v, acc[1][0][nf], 0, 0, 0);
                acc[1][0][nf] = __builtin_amdgcn_mfma_f32_16x16x32_bf16(al0, bh1v, acc[1][0][nf], 0, 0, 0);
                acc[1][0][nf] = __builtin_amdgcn_mfma_f32_16x16x32_bf16(ah0, bl1v, acc[1][0][nf], 0, 0, 0);
                acc[1][1][nf] = __builtin_amdgcn_mfma_f32_16x16x32_bf16(ah1, bh1v, acc[1][1][nf], 0, 0, 0);
                acc[1][1][nf] = __builtin_amdgcn_mfma_f32_16x16x32_bf16(al1, bh1v, acc[1][1][nf], 0, 0, 0);
                acc[1][1][nf] = __builtin_amdgcn_mfma_f32_16x16x32_bf16(ah1, bl1v, acc[1][1][nf], 0, 0, 0);
            }
        }
    }
    __syncthreads();

    float runmin[2][4];
#pragma unroll
    for (int gg = 0; gg < 2; ++gg)
#pragma unroll
        for (int j = 0; j < 4; ++j) runmin[gg][j] = 3.4e38f;

#pragma unroll
    for (int nc = 0; nc < 2; ++nc) {
        int kcbase = kqbase + nc * 128;
#pragma unroll
        for (int gg = 0; gg < 2; ++gg) {
#pragma unroll
            for (int nf = 0; nf < 8; ++nf) {
                float eev = eeL[nc * 128 + nf * 16 + (lane & 15)];
                f32x4 d = acc[nc][gg][nf];
                f32x4 s;
#pragma unroll
                for (int j = 0; j < 4; ++j) s[j] = fmaf(-2.f, d[j], eev);
                acc[nc][gg][nf] = s;
            }
#pragma unroll
            for (int j = 0; j < 4; ++j) {
                float m = 3.4e38f;
#pragma unroll
                for (int nf = 0; nf < 8; ++nf) m = fminf(m, acc[nc][gg][nf][j]);
                m = fminf(m, __shfl_xor(m, 1, 64));
                m = fminf(m, __shfl_xor(m, 2, 64));
                m = fminf(m, __shfl_xor(m, 4, 64));
                m = fminf(m, __shfl_xor(m, 8, 64));
                runmin[gg][j] = fminf(runmin[gg][j], m);
                float th = runmin[gg][j] + MARGIN;
                int ml = w * 32 + gg * 16 + (lane >> 4) * 4 + j;
#pragma unroll
                for (int nf = 0; nf < 8; ++nf) {
                    float sv = acc[nc][gg][nf][j];
                    if (sv <= th) {
                        int pos = atomicAdd(&cntL[ml], 1);
                        if (pos < 3) { ckL[ml][pos] = kcbase + nf * 16 + (lane & 15);
                                       csL[ml][pos] = sv; }
                    }
                }
            }
        }
    }
    __syncthreads();
    if (t < 128) {
        int n = n0 + t;
        int cnt = cntL[t];
        candcnt[(size_t)n * 4 + q] = (u8)(cnt > 255 ? 255 : cnt);
        int* dk = candk + (size_t)n * 12 + q * 3;
        float* ds = cands + (size_t)n * 12 + q * 3;
#pragma unroll
        for (int i = 0; i < 3; ++i) {
            dk[i] = (i < cnt) ? ckL[t][i] : 0;
            ds[i] = (i < cnt) ? csL[t][i] : 3.4e38f;
        }
        if (cnt > 3) {
            int pos = atomicAdd(ocnt, 1);
            if (pos < OCAP) olist[pos] = n;
        }
    }
}

// ======================================================================
// k_score v2: phase 1 certification (t<128/point); ambiguous points go
// to an LDS worklist processed WAVE-COOPERATIVELY (64-lane parallel z
// column load + coalesced e row + shfl-tree dot). Phase 2: overflow
// exact scan (unchanged, proven).
// ======================================================================
__global__ __launch_bounds__(256) void k_score(const float* __restrict__ z,
                                               const float* __restrict__ cb,
                                               const float* __restrict__ ee,
                                               const float* __restrict__ zz,
                                               const u8* __restrict__ candcnt,
                                               const int* __restrict__ candk,
                                               const float* __restrict__ cands,
                                               const int* __restrict__ ocnt,
                                               const int* __restrict__ olist,
                                               int* __restrict__ idx_out) {
    __shared__ float zL[ED];
    __shared__ float rv[4];
    __shared__ int   ri[4];
    __shared__ int   ambN[128];
    __shared__ float ambTh[128];
    __shared__ int   ambCnt;
    int t = threadIdx.x;
    int w = t >> 6, lane = t & 63;
    if (t == 0) ambCnt = 0;
    __syncthreads();

    // ---------------- phase 1: certify / enqueue ambiguous -----------
    if (t < 128) {
        int n = blockIdx.x * 128 + t;                 // 256 blocks
        int packed = ((const int*)candcnt)[n];
        int c0 = packed & 255, c1 = (packed >> 8) & 255,
            c2 = (packed >> 16) & 255, c3 = (packed >> 24) & 255;
        if (!((c0 > 3) | (c1 > 3) | (c2 > 3) | (c3 > 3))) {
            int ks[12]; float ss[12];
            const int*   ck = candk + (size_t)n * 12;
            const float* cs = cands + (size_t)n * 12;
#pragma unroll
            for (int p = 0; p < 3; ++p) {
                *(int4*)&ks[p * 4]   = *(const int4*)(ck + p * 4);
                *(float4*)&ss[p * 4] = *(const float4*)(cs + p * 4);
            }
            float gmin = 3.4e38f;
#pragma unroll
            for (int j = 0; j < 12; ++j) gmin = fminf(gmin, ss[j]);
            float th = gmin + AMB;
            int nsurv = 0;
#pragma unroll
            for (int j = 0; j < 12; ++j) nsurv += (ss[j] <= th) ? 1 : 0;

            if (nsurv == 1) {
                int k = 0;
#pragma unroll
                for (int j = 0; j < 12; ++j) if (ss[j] <= th) k = ks[j];
                idx_out[n] = k;
            } else {
                int pos = atomicAdd(&ambCnt, 1);
                ambN[pos] = n; ambTh[pos] = th;
            }
        }
    }
    __syncthreads();

    // ---------------- phase 1b: cooperative ambiguous rescore --------
    int acount = ambCnt;
    for (int e = w; e < acount; e += 4) {
        int n = ambN[e]; float th = ambTh[e];
        int b = n >> 10, hw = n & 1023;
        const float* zp = z + (size_t)b * ZPLANE + hw;
        // 64-lane parallel z column load (4 values per lane, in flight)
        float z0 = zp[(size_t)(lane * 4 + 0) * 1024];
        float z1 = zp[(size_t)(lane * 4 + 1) * 1024];
        float z2 = zp[(size_t)(lane * 4 + 2) * 1024];
        float z3 = zp[(size_t)(lane * 4 + 3) * 1024];
        float zzv = zz[n];
        const int*   ck = candk + (size_t)n * 12;
        const float* cs = cands + (size_t)n * 12;
        float bd = 3.4e38f; int bk = 1 << 30;
#pragma unroll 1
        for (int j = 0; j < 12; ++j) {
            if (cs[j] > th) continue;
            int k = ck[j];
            float4 ev = *(const float4*)(cb + (size_t)k * ED + lane * 4);
            float p = z0 * ev.x;
            p = fmaf(z1, ev.y, p);
            p = fmaf(z2, ev.z, p);
            p = fmaf(z3, ev.w, p);
            // deterministic 64-lane tree sum
            p += __shfl_xor(p, 1);
            p += __shfl_xor(p, 2);
            p += __shfl_xor(p, 4);
            p += __shfl_xor(p, 8);
            p += __shfl_xor(p, 16);
            p += __shfl_xor(p, 32);
            float d = (zzv + ee[k]) - 2.f * p;
            if (d < bd || (d == bd && k < bk)) { bd = d; bk = k; }
        }
        if (lane == 0) idx_out[n] = bk;
    }
    __syncthreads();

    // ---------------- phase 2: overflow exact scan -------------------
    int cnt = *ocnt; if (cnt > OCAP) cnt = OCAP;
    for (int i = blockIdx.x; i < cnt; i += gridDim.x) {
        int n = olist[i];
        int b = n >> 10, hw = n & 1023;
        const float* zp = z + (size_t)b * ZPLANE + hw;
        __syncthreads();
        zL[t] = zp[(size_t)t * 1024];
        __syncthreads();
        float zzv = zz[n];
        int k0 = t, k1 = 256 + t, k2 = 512 + t, k3 = 768 + t;
        const float* e0 = cb + (size_t)k0 * ED;
        const float* e1 = cb + (size_t)k1 * ED;
        const float* e2 = cb + (size_t)k2 * ED;
        const float* e3 = cb + (size_t)k3 * ED;
        float a0 = 0.f, a1 = 0.f, a2 = 0.f, a3 = 0.f;
#pragma unroll 8
        for (int c = 0; c < ED; c += 4) {
            float4 z4 = *(const float4*)&zL[c];
            float4 v0 = *(const float4*)(e0 + c);
            float4 v1 = *(const float4*)(e1 + c);
            float4 v2 = *(const float4*)(e2 + c);
            float4 v3 = *(const float4*)(e3 + c);
            a0 = fmaf(z4.x, v0.x, a0); a0 = fmaf(z4.y, v0.y, a0);
            a0 = fmaf(z4.z, v0.z, a0); a0 = fmaf(z4.w, v0.w, a0);
            a1 = fmaf(z4.x, v1.x, a1); a1 = fmaf(z4.y, v1.y, a1);
            a1 = fmaf(z4.z, v1.z, a1); a1 = fmaf(z4.w, v1.w, a1);
            a2 = fmaf(z4.x, v2.x, a2); a2 = fmaf(z4.y, v2.y, a2);
            a2 = fmaf(z4.z, v2.z, a2); a2 = fmaf(z4.w, v2.w, a2);
            a3 = fmaf(z4.x, v3.x, a3); a3 = fmaf(z4.y, v3.y, a3);
            a3 = fmaf(z4.z, v3.z, a3); a3 = fmaf(z4.w, v3.w, a3);
        }
        float d0 = (zzv + ee[k0]) - 2.f * a0;
        float d1 = (zzv + ee[k1]) - 2.f * a1;
        float d2 = (zzv + ee[k2]) - 2.f * a2;
        float d3 = (zzv + ee[k3]) - 2.f * a3;
        float bd = d0; int bk = k0;
        if (d1 < bd) { bd = d1; bk = k1; }
        if (d2 < bd) { bd = d2; bk = k2; }
        if (d3 < bd) { bd = d3; bk = k3; }
        for (int off = 32; off; off >>= 1) {
            float ov = __shfl_down(bd, off);
            int   oi = __shfl_down(bk, off);
            if (ov < bd || (ov == bd && oi < bk)) { bd = ov; bk = oi; }
        }
        if ((t & 63) == 0) { rv[t >> 6] = bd; ri[t >> 6] = bk; }
        __syncthreads();
        if (t == 0) {
            for (int wv = 1; wv < 4; ++wv)
                if (rv[wv] < bd || (rv[wv] == bd && ri[wv] < bk)) { bd = rv[wv]; bk = ri[wv]; }
            idx_out[n] = bk;
        }
    }
}

// ======================================================================
// k_main (fallback path only): exact fp32 distances + argmin, proven.
// ======================================================================
#define TM 64
#define TK 128
#define CCH 64
__global__ __launch_bounds__(256) void k_main(const float* __restrict__ z,
                                              const float* __restrict__ eT,
                                              const float* __restrict__ ee,
                                              const float* __restrict__ zz,
                                              int* __restrict__ idx_out) {
    __shared__ float zt[CCH][TM];
    __shared__ float et[CCH][TK];
    __shared__ float redv[TM][16];
    __shared__ int   redi[TM][16];
    __shared__ float bestv[TM];
    __shared__ int   besti[TM];
    __shared__ float zzl[TM];
    int t = threadIdx.x;
    int n0 = blockIdx.x * TM;
    int b = n0 >> 10, hw0 = n0 & 1023;
    const float* zb = z + (size_t)b * ZPLANE + hw0;
    int trow = t >> 4, tcol = t & 15;
    if (t < TM) { bestv[t] = 3.4e38f; besti[t] = 0; zzl[t] = zz[n0 + t]; }
    for (int kt = 0; kt < NE / TK; ++kt) {
        int k0 = kt * TK;
        float acc[4][8];
        for (int i = 0; i < 4; ++i)
            for (int j = 0; j < 8; ++j) acc[i][j] = 0.f;
        for (int cc = 0; cc < ED / CCH; ++cc) {
            __syncthreads();
            {
                int m4 = (t & 15) * 4; int cb0 = t >> 4;
                for (int p = 0; p < 4; ++p) {
                    int cl = p * 16 + cb0;
                    float4 v = *(const float4*)(zb + (size_t)(cc * CCH + cl) * 1024 + m4);
                    *(float4*)&zt[cl][m4] = v;
                }
            }
            {
                int k4 = (t & 31) * 4; int cb0 = t >> 5;
                for (int p = 0; p < 8; ++p) {
                    int cl = p * 8 + cb0;
                    float4 v = *(const float4*)(eT + (size_t)(cc * CCH + cl) * 1024 + k0 + k4);
                    *(float4*)&et[cl][k4] = v;
                }
            }
            __syncthreads();
            for (int c = 0; c < CCH; ++c) {
                float4 zm = *(const float4*)&zt[c][trow * 4];
                float4 e0 = *(const float4*)&et[c][tcol * 8];
                float4 e1 = *(const float4*)&et[c][tcol * 8 + 4];
                float zv[4] = {zm.x, zm.y, zm.z, zm.w};
                float ev[8] = {e0.x, e0.y, e0.z, e0.w, e1.x, e1.y, e1.z, e1.w};
                for (int i = 0; i < 4; ++i)
                    for (int j = 0; j < 8; ++j)
                        acc[i][j] = fmaf(zv[i], ev[j], acc[i][j]);
            }
        }
        for (int i = 0; i < 4; ++i) {
            int m = trow * 4 + i;
            float zv = zzl[m];
            float bv = 3.4e38f; int bi = 0;
            for (int j = 0; j < 8; ++j) {
                int k = k0 + tcol * 8 + j;
                float t1 = zv + ee[k];
                float d  = t1 - 2.0f * acc[i][j];
                if (d < bv) { bv = d; bi = k; }
            }
            redv[m][tcol] = bv; redi[m][tcol] = bi;
        }
        __syncthreads();
        if (t < TM) {
            float bv = bestv[t]; int bi = besti[t];
            for (int tc = 0; tc < 16; ++tc) {
                float v = redv[t][tc]; int ix = redi[t][tc];
                if (v < bv || (v == bv && ix < bi)) { bv = v; bi = ix; }
            }
            bestv[t] = bv; besti[t] = bi;
        }
    }
    __syncthreads();
    if (t < TM) idx_out[n0 + t] = besti[t];
}

// ======================================================================
// k_out: fused out1 (blocks 0-1023: z_q + loss partials, float4) and
// out2 (blocks 1024-3071: one-hot float4 stores + indices + histogram).
// ======================================================================
__global__ __launch_bounds__(256) void k_out(const float* __restrict__ z,
                                             const float* __restrict__ cb,
                                             const int* __restrict__ idx,
                                             float* __restrict__ out,
                                             double* __restrict__ lossp,
                                             int* __restrict__ hist) {
#pragma clang fp contract(off)
    __shared__ float eL[32 * 257];     // 32.9 KB
    __shared__ int idxL[32];
    __shared__ double wsum[4];
    int t = threadIdx.x;
    int blk = blockIdx.x;

    if (blk < 1024) {
        // ---------------- out1: z_q + loss ----------------
        int b   = blk >> 5;
        int hw0 = (blk & 31) * 32;
        int n0  = (b << 10) + hw0;
        if (t < 32) idxL[t] = idx[n0 + t];
        __syncthreads();
        {
            int w = t >> 6, lane = t & 63;
            for (int rr = 0; rr < 8; ++rr) {
                int r = w * 8 + rr;
                int iv = idxL[r];
                float4 v = *(const float4*)(cb + (size_t)iv * ED + lane * 4);
                float* dst = &eL[r * 257 + lane * 4];
                dst[0] = v.x; dst[1] = v.y; dst[2] = v.z; dst[3] = v.w;
            }
        }
        __syncthreads();
        int p4 = (t & 7) * 4, cr = t >> 3;
        const float* zb = z + (size_t)b * ZPLANE + hw0;
        float* ob = out + OFF_ZQ + (size_t)b * ZPLANE + hw0;
        double lsum = 0.0;
#pragma unroll
        for (int i = 0; i < 8; ++i) {
            int c = i * 32 + cr;
            float4 zv4 = *(const float4*)(zb + (size_t)c * 1024 + p4);
            float4 o;
            float d0 = eL[(p4)     * 257 + c] - zv4.x; o.x = zv4.x + d0;
            float d1 = eL[(p4 + 1) * 257 + c] - zv4.y; o.y = zv4.y + d1;
            float d2 = eL[(p4 + 2) * 257 + c] - zv4.z; o.z = zv4.z + d2;
            float d3 = eL[(p4 + 3) * 257 + c] - zv4.w; o.w = zv4.w + d3;
            *(float4*)(ob + (size_t)c * 1024 + p4) = o;
            lsum += (double)(d0 * d0) + (double)(d1 * d1)
                  + (double)(d2 * d2) + (double)(d3 * d3);
        }
        for (int off = 32; off; off >>= 1) lsum += __shfl_down(lsum, off);
        if ((t & 63) == 0) wsum[t >> 6] = lsum;
        __syncthreads();
        if (t == 0) lossp[blk] = (wsum[0] + wsum[1]) + (wsum[2] + wsum[3]);
    } else {
        // ---------------- out2: one-hot + indices + histogram --------
        int blk2 = blk - 1024;
        if (t < 16) atomicAdd(&hist[idx[blk2 * 16 + t]], 1);
        for (int it = 0; it < 16; ++it) {
            int qq = (blk2 * 16 + it) * 256 + t;
            int row  = qq >> 8;
            int col4 = (qq & 255) * 4;
            int iv = idx[row];
            float4 v;
            v.x = (col4     == iv) ? 1.f : 0.f;
            v.y = (col4 + 1 == iv) ? 1.f : 0.f;
            v.z = (col4 + 2 == iv) ? 1.f : 0.f;
            v.w = (col4 + 3 == iv) ? 1.f : 0.f;
            *(float4*)(out + OFF_ENC + (size_t)qq * 4) = v;
            if ((qq & 255) == 0) out[OFF_IDX + row] = (float)iv;
        }
    }
}

// ======================================================================
// k_final2: perplexity from histogram + loss scalar. Deterministic.
// ======================================================================
__global__ __launch_bounds__(256) void k_final2(const int* __restrict__ hist,
                                                const double* __restrict__ lossp,
                                                float* __restrict__ out) {
    __shared__ double sh[4];
    int t = threadIdx.x;
    double psum = 0.0;
    for (int k = t; k < NE; k += 256) {
        float em = (float)hist[k] / 32768.0f;
        float term = em * logf(em + 1e-10f);
        psum += (double)term;
    }
    for (int off = 32; off; off >>= 1) psum += __shfl_down(psum, off);
    if ((t & 63) == 0) sh[t >> 6] = psum;
    __syncthreads();
    if (t == 0) {
        double tot = (sh[0] + sh[1]) + (sh[2] + sh[3]);
        out[OFF_PPL] = expf(-(float)tot);
    }
    __syncthreads();
    double ls = 0.0;
    for (int i = t; i < NLOSSP; i += 256) ls += lossp[i];
    for (int off = 32; off; off >>= 1) ls += __shfl_down(ls, off);
    __syncthreads();
    if ((t & 63) == 0) sh[t >> 6] = ls;
    __syncthreads();
    if (t == 0) {
        double m = ((sh[0] + sh[1]) + (sh[2] + sh[3])) / 8388608.0;
        float mf = (float)m;
        out[OFF_LOSS] = mf + 0.25f * mf;
    }
}

// ======================================================================
extern "C" void kernel_launch(void* const* d_in, const int* in_sizes, int n_in,
                              void* d_out, int out_size, void* d_ws, size_t ws_size,
                              hipStream_t stream) {
    const float* z  = (const float*)d_in[0];
    const float* cb = (const float*)d_in[1];
    float* out = (float*)d_out;
    char* ws = (char*)d_ws;

    int*    idx   = (int*)(ws + WS_IDX);
    float*  zz    = (float*)(ws + WS_ZZ);
    float*  ee    = (float*)(ws + WS_EE);
    double* lossp = (double*)(ws + WS_LOSSP);
    int*    hist  = (int*)(ws + WS_HIST);

    if (ws_size >= WS_NEED) {
        u16* eh = (u16*)(ws + WS_EH);
        u16* el = (u16*)(ws + WS_EL);
        u16* zh = (u16*)(ws + WS_ZH);
        u16* zl = (u16*)(ws + WS_ZL);
        u8*  ccnt  = (u8*)(ws + WS_CCNT);
        int* candk = (int*)(ws + WS_CANDK);
        float* cands = (float*)(ws + WS_CANDS);
        int* ocnt  = (int*)(ws + WS_OCNT);
        int* olist = (int*)(ws + WS_OLIST);

        k_prep0 <<<2048, 256, 0, stream>>>(z, cb, zz, zh, zl, ee, eh, el, ocnt, hist);
        k_filter<<<1024, 256, 0, stream>>>(zh, zl, eh, el, ee, ccnt, candk, cands, ocnt, olist);
        k_score <<<256,  256, 0, stream>>>(z, cb, ee, zz, ccnt, candk, cands, ocnt, olist, idx);
        k_out   <<<3072, 256, 0, stream>>>(z, cb, idx, out, lossp, hist);
    } else {
        float* eT = (float*)(ws + WS_ET_FB);
        k_prep_old<<<4,   256, 0, stream>>>(cb, ee, eT, hist);
        k_zz      <<<128, 256, 0, stream>>>(z, zz);
        k_main    <<<512, 256, 0, stream>>>(z, eT, ee, zz, idx);
        k_out     <<<3072,256, 0, stream>>>(z, cb, idx, out, lossp, hist);
    }
    k_final2<<<1, 256, 0, stream>>>(hist, lossp, out);
}

// Round 11
// 193.484 us; speedup vs baseline: 13.9246x; 1.1358x over previous
//
#include <hip/hip_runtime.h>
#include <hip/hip_bf16.h>
#include <cstdint>
#include <cstddef>

typedef unsigned short u16;
typedef unsigned char u8;
typedef __attribute__((ext_vector_type(8))) short bf16x8;
typedef __attribute__((ext_vector_type(4))) float f32x4;

// ---- problem sizes ----
#define NPTS 32768      // B*H*W = 32*32*32
#define NE   1024       // codes
#define ED   256        // embedding dim (= C)
#define ZPLANE 262144   // 256*1024 floats per batch image (C*H*W)

// ---- output layout (floats) ----
#define OFF_LOSS 0
#define OFF_ZQ   1
#define OFF_PPL  8388609
#define OFF_ENC  8388610
#define OFF_IDX  41943042

// ---- ws layout (bytes) ----
#define WS_IDX   0              // int[32768]
#define WS_ZZ    131072         // float[32768]
#define WS_EE    262144         // float[1024]
#define WS_LOSSP 266240         // double[1024]
#define NLOSSP   1024
#define WS_HIST  274432         // int[1024] (dead gap before ET_FB)
#define WS_ET_FB 331776         // float[256*1024] (FALLBACK ONLY, overlays EH/EL)
#define WS_EH    331776         // u16[1024*256]
#define WS_EL    856064
#define WS_ZH    1380352        // u16[32768*256]
#define WS_ZL    18157568
#define WS_CCNT  34934784       // u8[4*32768] packed counts
#define WS_CANDK 35065856       // int[12*32768]
#define WS_CANDS 36638720       // float[12*32768]
#define WS_OCNT  38211584       // int: overflow count
#define WS_OLIST 38211588       // int[4096]: overflow point list
#define WS_NEED  38227972ULL

#define MARGIN 3.0e-4f          // k_filter emission margin (capture bound)
#define AMB    2.0e-4f          // certification ambiguity window (>2E, <=MARGIN)
#define OCAP   4096

// ======================================================================
// k_prep0: fused zprep (blocks 0-1023) + eprep (blocks 1024-2047).
// ======================================================================
__global__ __launch_bounds__(256) void k_prep0(const float* __restrict__ z,
                                               const float* __restrict__ cb,
                                               float* __restrict__ zz,
                                               u16* __restrict__ zh,
                                               u16* __restrict__ zl,
                                               float* __restrict__ ee,
                                               u16* __restrict__ eh,
                                               u16* __restrict__ el,
                                               int* __restrict__ ocnt,
                                               int* __restrict__ hist) {
#pragma clang fp contract(off)
    __shared__ float tile[256 * 33];   // 33.8 KB (eprep uses first 256)
    int t = threadIdx.x;
    int blk = blockIdx.x;

    if (blk < 1024) {
        // ---------------- zprep ----------------
        int b   = blk >> 5;
        int hw0 = (blk & 31) * 32;
        const float* zb = z + (size_t)b * ZPLANE + hw0;
        int p4 = (t & 7) * 4, cr = t >> 3;
#pragma unroll
        for (int i = 0; i < 8; ++i) {
            int c = i * 32 + cr;
            float4 v = *(const float4*)(zb + (size_t)c * 1024 + p4);
            float* dst = &tile[c * 33 + p4];
            dst[0] = v.x; dst[1] = v.y; dst[2] = v.z; dst[3] = v.w;
        }
        __syncthreads();
        // zz for 32 points, exact numpy pairwise order
        if (t < 32) {
            int p = t;
            float s[2];
            for (int h = 0; h < 2; ++h) {
                float r[8];
                for (int j = 0; j < 8; ++j) { float v = tile[(h * 128 + j) * 33 + p]; r[j] = v * v; }
                for (int i = 8; i < 128; i += 8)
                    for (int j = 0; j < 8; ++j) { float v = tile[(h * 128 + i + j) * 33 + p]; r[j] += v * v; }
                s[h] = ((r[0] + r[1]) + (r[2] + r[3])) + ((r[4] + r[5]) + (r[6] + r[7]));
            }
            zz[(b << 10) + hw0 + p] = s[0] + s[1];
        }
        // bf16 hi/lo split
        int p = t >> 3, cq = t & 7;
        size_t n = (size_t)(b << 10) + hw0 + p;
        u16* dh = zh + n * 256 + cq * 32;
        u16* dl = zl + n * 256 + cq * 32;
#pragma unroll
        for (int g8 = 0; g8 < 4; ++g8) {
            u16 hbuf[8], lbuf[8];
#pragma unroll
            for (int kk = 0; kk < 8; ++kk) {
                float f = tile[(cq * 32 + g8 * 8 + kk) * 33 + p];
                __hip_bfloat16 h = __float2bfloat16(f);
                float hf = __bfloat162float(h);
                __hip_bfloat16 l = __float2bfloat16(f - hf);
                hbuf[kk] = *(u16*)&h; lbuf[kk] = *(u16*)&l;
            }
            *(bf16x8*)(dh + g8 * 8) = *(bf16x8*)&hbuf[0];
            *(bf16x8*)(dl + g8 * 8) = *(bf16x8*)&lbuf[0];
        }
    } else {
        // ---------------- eprep ----------------
        int k = blk - 1024;
        if (k == 0) {
            if (t == 0) *ocnt = 0;
            for (int i = t; i < NE; i += 256) hist[i] = 0;
        }
        float f = cb[(size_t)k * ED + t];
        tile[t] = f;
        __hip_bfloat16 h = __float2bfloat16(f);
        float hf = __bfloat162float(h);
        __hip_bfloat16 l = __float2bfloat16(f - hf);
        eh[(size_t)k * ED + t] = *(u16*)&h;
        el[(size_t)k * ED + t] = *(u16*)&l;
        __syncthreads();
        if (t == 0) {
            float s[2];
            for (int h2 = 0; h2 < 2; ++h2) {
                const float* a = &tile[h2 * 128];
                float r[8];
                for (int j = 0; j < 8; ++j) { float v = a[j]; r[j] = v * v; }
                for (int i = 8; i < 128; i += 8)
                    for (int j = 0; j < 8; ++j) { float v = a[i + j]; r[j] += v * v; }
                s[h2] = ((r[0] + r[1]) + (r[2] + r[3])) + ((r[4] + r[5]) + (r[6] + r[7]));
            }
            ee[k] = s[0] + s[1];
        }
    }
}

// k_prep_old: fallback (ee + eT + hist zero)
__global__ __launch_bounds__(256) void k_prep_old(const float* __restrict__ cb,
                                                  float* __restrict__ ee,
                                                  float* __restrict__ eT,
                                                  int* __restrict__ hist) {
#pragma clang fp contract(off)
    if (blockIdx.x == 0) for (int i = threadIdx.x; i < NE; i += 256) hist[i] = 0;
    int k = blockIdx.x * 256 + threadIdx.x;
    if (k >= NE) return;
    const float* row = cb + (size_t)k * ED;
    float s[2];
    for (int h = 0; h < 2; ++h) {
        const float* a = row + h * 128;
        float r[8];
        for (int j = 0; j < 8; ++j) { float v = a[j]; r[j] = v * v; }
        for (int i = 8; i < 128; i += 8)
            for (int j = 0; j < 8; ++j) { float v = a[i + j]; r[j] += v * v; }
        s[h] = ((r[0] + r[1]) + (r[2] + r[3])) + ((r[4] + r[5]) + (r[6] + r[7]));
    }
    ee[k] = s[0] + s[1];
    for (int c = 0; c < ED; ++c) eT[(size_t)c * NE + k] = row[c];
}

// ======================================================================
// k_zz: fallback-only per-point ||z||^2 (proven exact)
// ======================================================================
__global__ __launch_bounds__(256) void k_zz(const float* __restrict__ z,
                                            float* __restrict__ zz) {
#pragma clang fp contract(off)
    int n = blockIdx.x * 256 + threadIdx.x;      // 128 blocks
    int b = n >> 10, hw = n & 1023;
    const float* a0 = z + (size_t)b * ZPLANE + hw;
    float s[2];
    for (int h = 0; h < 2; ++h) {
        const float* a = a0 + (size_t)h * 128 * 1024;
        float r[8];
        for (int j = 0; j < 8; ++j) { float v = a[(size_t)j * 1024]; r[j] = v * v; }
        for (int i = 8; i < 128; i += 8)
            for (int j = 0; j < 8; ++j) { float v = a[(size_t)(i + j) * 1024]; r[j] += v * v; }
        s[h] = ((r[0] + r[1]) + (r[2] + r[3])) + ((r[4] + r[5]) + (r[6] + r[7]));
    }
    zz[n] = s[0] + s[1];
}

// ======================================================================
// k_filter v3: 8 K-slices of 32, double-buffered LDS (2x32KB), reg-staged
// prefetch (loads for slice ks+2 issued during MFMA of ks), A-operand
// prefetch, 2-way-free LDS swizzle. MFMA order per accumulator identical
// to proven v2 -> scores bit-identical.
// ======================================================================
#define LOAD_SLICE(KSV) { \
    _Pragma("unroll") \
    for (int i_ = 0; i_ < 8; ++i_) { \
        int f_ = i_ * 256 + t; \
        int arr_ = f_ >> 9, r_ = (f_ >> 2) & 127; \
        const u16* bp_ = (arr_ & 1) ? el : eh; \
        gbuf[i_] = *(const bf16x8*)(bp_ + (size_t)(kqbase + (arr_ >> 1) * 128 + r_) * 256 + (KSV) * 32 + (f_ & 3) * 8); \
    } }

#define WRITE_SLICE(BUFP) { \
    _Pragma("unroll") \
    for (int i_ = 0; i_ < 8; ++i_) { \
        int f_ = i_ * 256 + t; \
        int arr_ = f_ >> 9, r_ = (f_ >> 2) & 127, sl_ = f_ & 3; \
        *(bf16x8*)&(BUFP)[arr_ * 4096 + r_ * 32 + (sl_ ^ ((r_ >> 1) & 3)) * 8] = gbuf[i_]; \
    } }

#define MFMA_KS(BUFP) { \
    _Pragma("unroll") \
    for (int nf = 0; nf < 8; ++nf) { \
        int r = nf * 16 + (lane & 15); \
        int bo = r * 32 + (((lane >> 4) ^ ((r >> 1) & 3)) * 8); \
        bf16x8 bh0v = *(const bf16x8*)&(BUFP)[bo]; \
        bf16x8 bl0v = *(const bf16x8*)&(BUFP)[4096 + bo]; \
        bf16x8 bh1v = *(const bf16x8*)&(BUFP)[8192 + bo]; \
        bf16x8 bl1v = *(const bf16x8*)&(BUFP)[12288 + bo]; \
        acc[0][0][nf] = __builtin_amdgcn_mfma_f32_16x16x32_bf16(ah0c, bh0v, acc[0][0][nf], 0, 0, 0); \
        acc[0][0][nf] = __builtin_amdgcn_mfma_f32_16x16x32_bf16(al0c, bh0v, acc[0][0][nf], 0, 0, 0); \
        acc[0][0][nf] = __builtin_amdgcn_mfma_f32_16x16x32_bf16(ah0c, bl0v, acc[0][0][nf], 0, 0, 0); \
        acc[0][1][nf] = __builtin_amdgcn_mfma_f32_16x16x32_bf16(ah1c, bh0v, acc[0][1][nf], 0, 0, 0); \
        acc[0][1][nf] = __builtin_amdgcn_mfma_f32_16x16x32_bf16(al1c, bh0v, acc[0][1][nf], 0, 0, 0); \
        acc[0][1][nf] = __builtin_amdgcn_mfma_f32_16x16x32_bf16(ah1c, bl0v, acc[0][1][nf], 0, 0, 0); \
        acc[1][0][nf] = __builtin_amdgcn_mfma_f32_16x16x32_bf16(ah0c, bh1v, acc[1][0][nf], 0, 0, 0); \
        acc[1][0][nf] = __builtin_amdgcn_mfma_f32_16x16x32_bf16(al0c, bh1v, acc[1][0][nf], 0, 0, 0); \
        acc[1][0][nf] = __builtin_amdgcn_mfma_f32_16x16x32_bf16(ah0c, bl1v, acc[1][0][nf], 0, 0, 0); \
        acc[1][1][nf] = __builtin_amdgcn_mfma_f32_16x16x32_bf16(ah1c, bh1v, acc[1][1][nf], 0, 0, 0); \
        acc[1][1][nf] = __builtin_amdgcn_mfma_f32_16x16x32_bf16(al1c, bh1v, acc[1][1][nf], 0, 0, 0); \
        acc[1][1][nf] = __builtin_amdgcn_mfma_f32_16x16x32_bf16(ah1c, bl1v, acc[1][1][nf], 0, 0, 0); \
    } }

__global__ __launch_bounds__(256, 2) void k_filter(const u16* __restrict__ zh,
                                                   const u16* __restrict__ zl,
                                                   const u16* __restrict__ eh,
                                                   const u16* __restrict__ el,
                                                   const float* __restrict__ ee,
                                                   u8* __restrict__ candcnt,
                                                   int* __restrict__ candk,
                                                   float* __restrict__ cands,
                                                   int* __restrict__ ocnt,
                                                   int* __restrict__ olist) {
    __shared__ u16 Buf0[4 * 4096];    // 32 KB: [h0|l0|h1|l1], 128 rows x 64B, slot-XOR swizzle
    __shared__ u16 Buf1[4 * 4096];    // 32 KB
    __shared__ float eeL[256];
    __shared__ int  cntL[128];
    __shared__ int  ckL[128][3];
    __shared__ float csL[128][3];

    int t = threadIdx.x;
    int lane = t & 63, w = t >> 6;
    int pg = blockIdx.x & 255;
    int q  = blockIdx.x >> 8;
    int n0 = pg * 128;
    int kqbase = q * 256;
    int prow = w * 32 + (lane & 15);
    const u16* zh0 = zh + (size_t)(n0 + prow) * 256;
    const u16* zl0 = zl + (size_t)(n0 + prow) * 256;
    const u16* zh1 = zh0 + 16 * 256;
    const u16* zl1 = zl0 + 16 * 256;
    int koff_lane = (lane >> 4) * 8;

    if (t < 128) cntL[t] = 0;
    eeL[t] = ee[kqbase + t];

    f32x4 acc[2][2][8];
#pragma unroll
    for (int nc = 0; nc < 2; ++nc)
#pragma unroll
        for (int gg = 0; gg < 2; ++gg)
#pragma unroll
            for (int nf = 0; nf < 8; ++nf)
                acc[nc][gg][nf] = (f32x4){0.f, 0.f, 0.f, 0.f};

    bf16x8 gbuf[8];
    LOAD_SLICE(0);
    WRITE_SLICE(Buf0);
    LOAD_SLICE(1);
    bf16x8 ah0c = *(const bf16x8*)(zh0 + koff_lane);
    bf16x8 al0c = *(const bf16x8*)(zl0 + koff_lane);
    bf16x8 ah1c = *(const bf16x8*)(zh1 + koff_lane);
    bf16x8 al1c = *(const bf16x8*)(zl1 + koff_lane);
    __syncthreads();

    for (int ks = 0; ks < 8; ++ks) {
        u16* bufC = (ks & 1) ? Buf1 : Buf0;
        u16* bufN = (ks & 1) ? Buf0 : Buf1;
        if (ks < 7) WRITE_SLICE(bufN);       // gbuf holds slice ks+1; bufN free since iter ks-1's barrier
        if (ks < 6) LOAD_SLICE(ks + 2);      // async; lands during MFMA
        bf16x8 ah0n, al0n, ah1n, al1n;
        if (ks < 7) {
            int ko = (ks + 1) * 32 + koff_lane;
            ah0n = *(const bf16x8*)(zh0 + ko);
            al0n = *(const bf16x8*)(zl0 + ko);
            ah1n = *(const bf16x8*)(zh1 + ko);
            al1n = *(const bf16x8*)(zl1 + ko);
        }
        MFMA_KS(bufC);
        if (ks < 7) { ah0c = ah0n; al0c = al0n; ah1c = ah1n; al1c = al1n; }
        __syncthreads();
    }

    float runmin[2][4];
#pragma unroll
    for (int gg = 0; gg < 2; ++gg)
#pragma unroll
        for (int j = 0; j < 4; ++j) runmin[gg][j] = 3.4e38f;

#pragma unroll
    for (int nc = 0; nc < 2; ++nc) {
        int kcbase = kqbase + nc * 128;
#pragma unroll
        for (int gg = 0; gg < 2; ++gg) {
#pragma unroll
            for (int nf = 0; nf < 8; ++nf) {
                float eev = eeL[nc * 128 + nf * 16 + (lane & 15)];
                f32x4 d = acc[nc][gg][nf];
                f32x4 s;
#pragma unroll
                for (int j = 0; j < 4; ++j) s[j] = fmaf(-2.f, d[j], eev);
                acc[nc][gg][nf] = s;
            }
#pragma unroll
            for (int j = 0; j < 4; ++j) {
                float m = 3.4e38f;
#pragma unroll
                for (int nf = 0; nf < 8; ++nf) m = fminf(m, acc[nc][gg][nf][j]);
                m = fminf(m, __shfl_xor(m, 1, 64));
                m = fminf(m, __shfl_xor(m, 2, 64));
                m = fminf(m, __shfl_xor(m, 4, 64));
                m = fminf(m, __shfl_xor(m, 8, 64));
                runmin[gg][j] = fminf(runmin[gg][j], m);
                float th = runmin[gg][j] + MARGIN;
                int ml = w * 32 + gg * 16 + (lane >> 4) * 4 + j;
#pragma unroll
                for (int nf = 0; nf < 8; ++nf) {
                    float sv = acc[nc][gg][nf][j];
                    if (sv <= th) {
                        int pos = atomicAdd(&cntL[ml], 1);
                        if (pos < 3) { ckL[ml][pos] = kcbase + nf * 16 + (lane & 15);
                                       csL[ml][pos] = sv; }
                    }
                }
            }
        }
    }
    __syncthreads();
    if (t < 128) {
        int n = n0 + t;
        int cnt = cntL[t];
        candcnt[(size_t)n * 4 + q] = (u8)(cnt > 255 ? 255 : cnt);
        int* dk = candk + (size_t)n * 12 + q * 3;
        float* ds = cands + (size_t)n * 12 + q * 3;
#pragma unroll
        for (int i = 0; i < 3; ++i) {
            dk[i] = (i < cnt) ? ckL[t][i] : 0;
            ds[i] = (i < cnt) ? csL[t][i] : 3.4e38f;
        }
        if (cnt > 3) {
            int pos = atomicAdd(ocnt, 1);
            if (pos < OCAP) olist[pos] = n;
        }
    }
}

// ======================================================================
// k_score: phase 1 certification; ambiguous -> wave-cooperative rescore;
// phase 2 overflow exact scan. (proven, unchanged)
// ======================================================================
__global__ __launch_bounds__(256) void k_score(const float* __restrict__ z,
                                               const float* __restrict__ cb,
                                               const float* __restrict__ ee,
                                               const float* __restrict__ zz,
                                               const u8* __restrict__ candcnt,
                                               const int* __restrict__ candk,
                                               const float* __restrict__ cands,
                                               const int* __restrict__ ocnt,
                                               const int* __restrict__ olist,
                                               int* __restrict__ idx_out) {
    __shared__ float zL[ED];
    __shared__ float rv[4];
    __shared__ int   ri[4];
    __shared__ int   ambN[128];
    __shared__ float ambTh[128];
    __shared__ int   ambCnt;
    int t = threadIdx.x;
    int w = t >> 6, lane = t & 63;
    if (t == 0) ambCnt = 0;
    __syncthreads();

    if (t < 128) {
        int n = blockIdx.x * 128 + t;                 // 256 blocks
        int packed = ((const int*)candcnt)[n];
        int c0 = packed & 255, c1 = (packed >> 8) & 255,
            c2 = (packed >> 16) & 255, c3 = (packed >> 24) & 255;
        if (!((c0 > 3) | (c1 > 3) | (c2 > 3) | (c3 > 3))) {
            int ks[12]; float ss[12];
            const int*   ck = candk + (size_t)n * 12;
            const float* cs = cands + (size_t)n * 12;
#pragma unroll
            for (int p = 0; p < 3; ++p) {
                *(int4*)&ks[p * 4]   = *(const int4*)(ck + p * 4);
                *(float4*)&ss[p * 4] = *(const float4*)(cs + p * 4);
            }
            float gmin = 3.4e38f;
#pragma unroll
            for (int j = 0; j < 12; ++j) gmin = fminf(gmin, ss[j]);
            float th = gmin + AMB;
            int nsurv = 0;
#pragma unroll
            for (int j = 0; j < 12; ++j) nsurv += (ss[j] <= th) ? 1 : 0;

            if (nsurv == 1) {
                int k = 0;
#pragma unroll
                for (int j = 0; j < 12; ++j) if (ss[j] <= th) k = ks[j];
                idx_out[n] = k;
            } else {
                int pos = atomicAdd(&ambCnt, 1);
                ambN[pos] = n; ambTh[pos] = th;
            }
        }
    }
    __syncthreads();

    int acount = ambCnt;
    for (int e = w; e < acount; e += 4) {
        int n = ambN[e]; float th = ambTh[e];
        int b = n >> 10, hw = n & 1023;
        const float* zp = z + (size_t)b * ZPLANE + hw;
        float z0 = zp[(size_t)(lane * 4 + 0) * 1024];
        float z1 = zp[(size_t)(lane * 4 + 1) * 1024];
        float z2 = zp[(size_t)(lane * 4 + 2) * 1024];
        float z3 = zp[(size_t)(lane * 4 + 3) * 1024];
        float zzv = zz[n];
        const int*   ck = candk + (size_t)n * 12;
        const float* cs = cands + (size_t)n * 12;
        float bd = 3.4e38f; int bk = 1 << 30;
#pragma unroll 1
        for (int j = 0; j < 12; ++j) {
            if (cs[j] > th) continue;
            int k = ck[j];
            float4 ev = *(const float4*)(cb + (size_t)k * ED + lane * 4);
            float p = z0 * ev.x;
            p = fmaf(z1, ev.y, p);
            p = fmaf(z2, ev.z, p);
            p = fmaf(z3, ev.w, p);
            p += __shfl_xor(p, 1);
            p += __shfl_xor(p, 2);
            p += __shfl_xor(p, 4);
            p += __shfl_xor(p, 8);
            p += __shfl_xor(p, 16);
            p += __shfl_xor(p, 32);
            float d = (zzv + ee[k]) - 2.f * p;
            if (d < bd || (d == bd && k < bk)) { bd = d; bk = k; }
        }
        if (lane == 0) idx_out[n] = bk;
    }
    __syncthreads();

    int cnt = *ocnt; if (cnt > OCAP) cnt = OCAP;
    for (int i = blockIdx.x; i < cnt; i += gridDim.x) {
        int n = olist[i];
        int b = n >> 10, hw = n & 1023;
        const float* zp = z + (size_t)b * ZPLANE + hw;
        __syncthreads();
        zL[t] = zp[(size_t)t * 1024];
        __syncthreads();
        float zzv = zz[n];
        int k0 = t, k1 = 256 + t, k2 = 512 + t, k3 = 768 + t;
        const float* e0 = cb + (size_t)k0 * ED;
        const float* e1 = cb + (size_t)k1 * ED;
        const float* e2 = cb + (size_t)k2 * ED;
        const float* e3 = cb + (size_t)k3 * ED;
        float a0 = 0.f, a1 = 0.f, a2 = 0.f, a3 = 0.f;
#pragma unroll 8
        for (int c = 0; c < ED; c += 4) {
            float4 z4 = *(const float4*)&zL[c];
            float4 v0 = *(const float4*)(e0 + c);
            float4 v1 = *(const float4*)(e1 + c);
            float4 v2 = *(const float4*)(e2 + c);
            float4 v3 = *(const float4*)(e3 + c);
            a0 = fmaf(z4.x, v0.x, a0); a0 = fmaf(z4.y, v0.y, a0);
            a0 = fmaf(z4.z, v0.z, a0); a0 = fmaf(z4.w, v0.w, a0);
            a1 = fmaf(z4.x, v1.x, a1); a1 = fmaf(z4.y, v1.y, a1);
            a1 = fmaf(z4.z, v1.z, a1); a1 = fmaf(z4.w, v1.w, a1);
            a2 = fmaf(z4.x, v2.x, a2); a2 = fmaf(z4.y, v2.y, a2);
            a2 = fmaf(z4.z, v2.z, a2); a2 = fmaf(z4.w, v2.w, a2);
            a3 = fmaf(z4.x, v3.x, a3); a3 = fmaf(z4.y, v3.y, a3);
            a3 = fmaf(z4.z, v3.z, a3); a3 = fmaf(z4.w, v3.w, a3);
        }
        float d0 = (zzv + ee[k0]) - 2.f * a0;
        float d1 = (zzv + ee[k1]) - 2.f * a1;
        float d2 = (zzv + ee[k2]) - 2.f * a2;
        float d3 = (zzv + ee[k3]) - 2.f * a3;
        float bd = d0; int bk = k0;
        if (d1 < bd) { bd = d1; bk = k1; }
        if (d2 < bd) { bd = d2; bk = k2; }
        if (d3 < bd) { bd = d3; bk = k3; }
        for (int off = 32; off; off >>= 1) {
            float ov = __shfl_down(bd, off);
            int   oi = __shfl_down(bk, off);
            if (ov < bd || (ov == bd && oi < bk)) { bd = ov; bk = oi; }
        }
        if ((t & 63) == 0) { rv[t >> 6] = bd; ri[t >> 6] = bk; }
        __syncthreads();
        if (t == 0) {
            for (int wv = 1; wv < 4; ++wv)
                if (rv[wv] < bd || (rv[wv] == bd && ri[wv] < bk)) { bd = rv[wv]; bk = ri[wv]; }
            idx_out[n] = bk;
        }
    }
}

// ======================================================================
// k_main (fallback path only): exact fp32 distances + argmin, proven.
// ======================================================================
#define TM 64
#define TK 128
#define CCH 64
__global__ __launch_bounds__(256) void k_main(const float* __restrict__ z,
                                              const float* __restrict__ eT,
                                              const float* __restrict__ ee,
                                              const float* __restrict__ zz,
                                              int* __restrict__ idx_out) {
    __shared__ float zt[CCH][TM];
    __shared__ float et[CCH][TK];
    __shared__ float redv[TM][16];
    __shared__ int   redi[TM][16];
    __shared__ float bestv[TM];
    __shared__ int   besti[TM];
    __shared__ float zzl[TM];
    int t = threadIdx.x;
    int n0 = blockIdx.x * TM;
    int b = n0 >> 10, hw0 = n0 & 1023;
    const float* zb = z + (size_t)b * ZPLANE + hw0;
    int trow = t >> 4, tcol = t & 15;
    if (t < TM) { bestv[t] = 3.4e38f; besti[t] = 0; zzl[t] = zz[n0 + t]; }
    for (int kt = 0; kt < NE / TK; ++kt) {
        int k0 = kt * TK;
        float acc[4][8];
        for (int i = 0; i < 4; ++i)
            for (int j = 0; j < 8; ++j) acc[i][j] = 0.f;
        for (int cc = 0; cc < ED / CCH; ++cc) {
            __syncthreads();
            {
                int m4 = (t & 15) * 4; int cb0 = t >> 4;
                for (int p = 0; p < 4; ++p) {
                    int cl = p * 16 + cb0;
                    float4 v = *(const float4*)(zb + (size_t)(cc * CCH + cl) * 1024 + m4);
                    *(float4*)&zt[cl][m4] = v;
                }
            }
            {
                int k4 = (t & 31) * 4; int cb0 = t >> 5;
                for (int p = 0; p < 8; ++p) {
                    int cl = p * 8 + cb0;
                    float4 v = *(const float4*)(eT + (size_t)(cc * CCH + cl) * 1024 + k0 + k4);
                    *(float4*)&et[cl][k4] = v;
                }
            }
            __syncthreads();
            for (int c = 0; c < CCH; ++c) {
                float4 zm = *(const float4*)&zt[c][trow * 4];
                float4 e0 = *(const float4*)&et[c][tcol * 8];
                float4 e1 = *(const float4*)&et[c][tcol * 8 + 4];
                float zv[4] = {zm.x, zm.y, zm.z, zm.w};
                float ev[8] = {e0.x, e0.y, e0.z, e0.w, e1.x, e1.y, e1.z, e1.w};
                for (int i = 0; i < 4; ++i)
                    for (int j = 0; j < 8; ++j)
                        acc[i][j] = fmaf(zv[i], ev[j], acc[i][j]);
            }
        }
        for (int i = 0; i < 4; ++i) {
            int m = trow * 4 + i;
            float zv = zzl[m];
            float bv = 3.4e38f; int bi = 0;
            for (int j = 0; j < 8; ++j) {
                int k = k0 + tcol * 8 + j;
                float t1 = zv + ee[k];
                float d  = t1 - 2.0f * acc[i][j];
                if (d < bv) { bv = d; bi = k; }
            }
            redv[m][tcol] = bv; redi[m][tcol] = bi;
        }
        __syncthreads();
        if (t < TM) {
            float bv = bestv[t]; int bi = besti[t];
            for (int tc = 0; tc < 16; ++tc) {
                float v = redv[t][tc]; int ix = redi[t][tc];
                if (v < bv || (v == bv && ix < bi)) { bv = v; bi = ix; }
            }
            bestv[t] = bv; besti[t] = bi;
        }
    }
    __syncthreads();
    if (t < TM) idx_out[n0 + t] = besti[t];
}

// ======================================================================
// k_out: fused out1 (blocks 0-1023) + out2 (blocks 1024-3071). proven.
// ======================================================================
__global__ __launch_bounds__(256) void k_out(const float* __restrict__ z,
                                             const float* __restrict__ cb,
                                             const int* __restrict__ idx,
                                             float* __restrict__ out,
                                             double* __restrict__ lossp,
                                             int* __restrict__ hist) {
#pragma clang fp contract(off)
    __shared__ float eL[32 * 257];     // 32.9 KB
    __shared__ int idxL[32];
    __shared__ double wsum[4];
    int t = threadIdx.x;
    int blk = blockIdx.x;

    if (blk < 1024) {
        int b   = blk >> 5;
        int hw0 = (blk & 31) * 32;
        int n0  = (b << 10) + hw0;
        if (t < 32) idxL[t] = idx[n0 + t];
        __syncthreads();
        {
            int w = t >> 6, lane = t & 63;
            for (int rr = 0; rr < 8; ++rr) {
                int r = w * 8 + rr;
                int iv = idxL[r];
                float4 v = *(const float4*)(cb + (size_t)iv * ED + lane * 4);
                float* dst = &eL[r * 257 + lane * 4];
                dst[0] = v.x; dst[1] = v.y; dst[2] = v.z; dst[3] = v.w;
            }
        }
        __syncthreads();
        int p4 = (t & 7) * 4, cr = t >> 3;
        const float* zb = z + (size_t)b * ZPLANE + hw0;
        float* ob = out + OFF_ZQ + (size_t)b * ZPLANE + hw0;
        double lsum = 0.0;
#pragma unroll
        for (int i = 0; i < 8; ++i) {
            int c = i * 32 + cr;
            float4 zv4 = *(const float4*)(zb + (size_t)c * 1024 + p4);
            float4 o;
            float d0 = eL[(p4)     * 257 + c] - zv4.x; o.x = zv4.x + d0;
            float d1 = eL[(p4 + 1) * 257 + c] - zv4.y; o.y = zv4.y + d1;
            float d2 = eL[(p4 + 2) * 257 + c] - zv4.z; o.z = zv4.z + d2;
            float d3 = eL[(p4 + 3) * 257 + c] - zv4.w; o.w = zv4.w + d3;
            *(float4*)(ob + (size_t)c * 1024 + p4) = o;
            lsum += (double)(d0 * d0) + (double)(d1 * d1)
                  + (double)(d2 * d2) + (double)(d3 * d3);
        }
        for (int off = 32; off; off >>= 1) lsum += __shfl_down(lsum, off);
        if ((t & 63) == 0) wsum[t >> 6] = lsum;
        __syncthreads();
        if (t == 0) lossp[blk] = (wsum[0] + wsum[1]) + (wsum[2] + wsum[3]);
    } else {
        int blk2 = blk - 1024;
        if (t < 16) atomicAdd(&hist[idx[blk2 * 16 + t]], 1);
        for (int it = 0; it < 16; ++it) {
            int qq = (blk2 * 16 + it) * 256 + t;
            int row  = qq >> 8;
            int col4 = (qq & 255) * 4;
            int iv = idx[row];
            float4 v;
            v.x = (col4     == iv) ? 1.f : 0.f;
            v.y = (col4 + 1 == iv) ? 1.f : 0.f;
            v.z = (col4 + 2 == iv) ? 1.f : 0.f;
            v.w = (col4 + 3 == iv) ? 1.f : 0.f;
            *(float4*)(out + OFF_ENC + (size_t)qq * 4) = v;
            if ((qq & 255) == 0) out[OFF_IDX + row] = (float)iv;
        }
    }
}

// ======================================================================
// k_final2: perplexity from histogram + loss scalar. Deterministic.
// ======================================================================
__global__ __launch_bounds__(256) void k_final2(const int* __restrict__ hist,
                                                const double* __restrict__ lossp,
                                                float* __restrict__ out) {
    __shared__ double sh[4];
    int t = threadIdx.x;
    double psum = 0.0;
    for (int k = t; k < NE; k += 256) {
        float em = (float)hist[k] / 32768.0f;
        float term = em * logf(em + 1e-10f);
        psum += (double)term;
    }
    for (int off = 32; off; off >>= 1) psum += __shfl_down(psum, off);
    if ((t & 63) == 0) sh[t >> 6] = psum;
    __syncthreads();
    if (t == 0) {
        double tot = (sh[0] + sh[1]) + (sh[2] + sh[3]);
        out[OFF_PPL] = expf(-(float)tot);
    }
    __syncthreads();
    double ls = 0.0;
    for (int i = t; i < NLOSSP; i += 256) ls += lossp[i];
    for (int off = 32; off; off >>= 1) ls += __shfl_down(ls, off);
    __syncthreads();
    if ((t & 63) == 0) sh[t >> 6] = ls;
    __syncthreads();
    if (t == 0) {
        double m = ((sh[0] + sh[1]) + (sh[2] + sh[3])) / 8388608.0;
        float mf = (float)m;
        out[OFF_LOSS] = mf + 0.25f * mf;
    }
}

// ======================================================================
extern "C" void kernel_launch(void* const* d_in, const int* in_sizes, int n_in,
                              void* d_out, int out_size, void* d_ws, size_t ws_size,
                              hipStream_t stream) {
    const float* z  = (const float*)d_in[0];
    const float* cb = (const float*)d_in[1];
    float* out = (float*)d_out;
    char* ws = (char*)d_ws;

    int*    idx   = (int*)(ws + WS_IDX);
    float*  zz    = (float*)(ws + WS_ZZ);
    float*  ee    = (float*)(ws + WS_EE);
    double* lossp = (double*)(ws + WS_LOSSP);
    int*    hist  = (int*)(ws + WS_HIST);

    if (ws_size >= WS_NEED) {
        u16* eh = (u16*)(ws + WS_EH);
        u16* el = (u16*)(ws + WS_EL);
        u16* zh = (u16*)(ws + WS_ZH);
        u16* zl = (u16*)(ws + WS_ZL);
        u8*  ccnt  = (u8*)(ws + WS_CCNT);
        int* candk = (int*)(ws + WS_CANDK);
        float* cands = (float*)(ws + WS_CANDS);
        int* ocnt  = (int*)(ws + WS_OCNT);
        int* olist = (int*)(ws + WS_OLIST);

        k_prep0 <<<2048, 256, 0, stream>>>(z, cb, zz, zh, zl, ee, eh, el, ocnt, hist);
        k_filter<<<1024, 256, 0, stream>>>(zh, zl, eh, el, ee, ccnt, candk, cands, ocnt, olist);
        k_score <<<256,  256, 0, stream>>>(z, cb, ee, zz, ccnt, candk, cands, ocnt, olist, idx);
        k_out   <<<3072, 256, 0, stream>>>(z, cb, idx, out, lossp, hist);
    } else {
        float* eT = (float*)(ws + WS_ET_FB);
        k_prep_old<<<4,   256, 0, stream>>>(cb, ee, eT, hist);
        k_zz      <<<128, 256, 0, stream>>>(z, zz);
        k_main    <<<512, 256, 0, stream>>>(z, eT, ee, zz, idx);
        k_out     <<<3072,256, 0, stream>>>(z, cb, idx, out, lossp, hist);
    }
    k_final2<<<1, 256, 0, stream>>>(hist, lossp, out);
}